// Round 3
// baseline (5316.999 us; speedup 1.0000x reference)
//
#include <hip/hip_runtime.h>

#define N_NODES 100000
#define N_EDGES 3200000
#define N_GRAPHS 4096
#define IN_DIM 74
#define HID 64
#define MLP_HID 128

#define BKT_NODES 128                 // nodes per bucket
#define NBUCKET ((N_NODES + BKT_NODES - 1) / BKT_NODES)   // 782
#define BUCKET_CAP 8192               // edges capacity per bucket (mean ~4092)

// ---- projection: xw = x@W ; res = relu(x@R + rb). One thread per (node, f).
template<int IN>
__global__ void proj_kernel(const float* __restrict__ x,
                            const float* __restrict__ W,
                            const float* __restrict__ R,
                            const float* __restrict__ rb,
                            float* __restrict__ xw,
                            float* __restrict__ res,
                            int n_nodes) {
    int t = blockIdx.x * blockDim.x + threadIdx.x;
    int n = t >> 6;
    int f = t & 63;
    if (n >= n_nodes) return;
    const float* xr = x + (long)n * IN;
    float accW = 0.f, accR = 0.f;
    #pragma unroll 8
    for (int k = 0; k < IN; ++k) {
        float xv = xr[k];
        accW += xv * W[k * HID + f];
        accR += xv * R[k * HID + f];
    }
    xw[(long)n * HID + f] = accW;
    res[(long)n * HID + f] = fmaxf(accR + rb[f], 0.f);
}

// ---- cursor init: cursor[b] = b * BUCKET_CAP
__global__ void init_cursor_kernel(int* __restrict__ cursor) {
    int i = blockIdx.x * blockDim.x + threadIdx.x;
    if (i < NBUCKET) cursor[i] = i * BUCKET_CAP;
}

// ---- bucket append: pairs[pos] = src | (dst_local << 17); sequential within bucket
__global__ void bucket_fill_kernel(const int* __restrict__ src,
                                   const int* __restrict__ dst,
                                   int* __restrict__ cursor,
                                   unsigned* __restrict__ pairs,
                                   int n_edges) {
    int e = blockIdx.x * blockDim.x + threadIdx.x;
    if (e >= n_edges) return;
    int d = dst[e];
    int b = d >> 7;              // bucket of 128 nodes
    int pos = atomicAdd(&cursor[b], 1);
    pairs[pos] = (unsigned)src[e] | ((unsigned)(d & (BKT_NODES - 1)) << 17);
}

// ---- bucket aggregation + epilogue: one block per bucket, LDS accumulators.
// xout[n] = relu(sum_{s in in(n)} xw[s] + b) + res[n]
__launch_bounds__(256)
__global__ void agg_kernel(const float* __restrict__ xw,
                           const unsigned* __restrict__ pairs,
                           const int* __restrict__ cursor,
                           const float* __restrict__ bias,
                           const float* __restrict__ res,
                           float* __restrict__ xout) {
    __shared__ float acc[BKT_NODES * HID];   // 32 KB
    int bkt = blockIdx.x;
    int tid = threadIdx.x;
    #pragma unroll
    for (int i = tid; i < BKT_NODES * HID; i += 256) acc[i] = 0.f;
    __syncthreads();

    int base = bkt * BUCKET_CAP;
    int cnt = cursor[bkt] - base;
    int wid = tid >> 6, lane = tid & 63;
    const unsigned* pl = pairs + base;

    int e = wid;
    for (; e + 16 <= cnt; e += 16) {   // 4 waves * unroll 4
        unsigned p0 = pl[e];
        unsigned p1 = pl[e + 4];
        unsigned p2 = pl[e + 8];
        unsigned p3 = pl[e + 12];
        float v0 = xw[(long)(p0 & 0x1FFFF) * HID + lane];
        float v1 = xw[(long)(p1 & 0x1FFFF) * HID + lane];
        float v2 = xw[(long)(p2 & 0x1FFFF) * HID + lane];
        float v3 = xw[(long)(p3 & 0x1FFFF) * HID + lane];
        atomicAdd(&acc[(p0 >> 17) * HID + lane], v0);
        atomicAdd(&acc[(p1 >> 17) * HID + lane], v1);
        atomicAdd(&acc[(p2 >> 17) * HID + lane], v2);
        atomicAdd(&acc[(p3 >> 17) * HID + lane], v3);
    }
    for (; e < cnt; e += 4) {
        unsigned p = pl[e];
        float v = xw[(long)(p & 0x1FFFF) * HID + lane];
        atomicAdd(&acc[(p >> 17) * HID + lane], v);
    }
    __syncthreads();

    // epilogue
    int node0 = bkt * BKT_NODES;
    long obase = (long)node0 * HID;
    for (int i = tid; i < BKT_NODES * HID; i += 256) {
        int n = node0 + (i >> 6);
        if (n < N_NODES) {
            long o = obase + i;
            xout[o] = fmaxf(acc[i] + bias[i & 63], 0.f) + res[o];
        }
    }
}

// ---- pooling gather: graph_ids sorted -> binary search range, one wave/graph
__global__ void pool_gather_kernel(const float* __restrict__ x,
                                   const int* __restrict__ gid,
                                   float* __restrict__ g,
                                   int n_graphs) {
    int wid = (blockIdx.x * blockDim.x + threadIdx.x) >> 6;
    int lane = threadIdx.x & 63;
    if (wid >= n_graphs) return;
    int lo = 0, hi = N_NODES;
    while (lo < hi) { int mid = (lo + hi) >> 1; if (gid[mid] < wid) lo = mid + 1; else hi = mid; }
    int start = lo;
    hi = N_NODES;
    while (lo < hi) { int mid = (lo + hi) >> 1; if (gid[mid] < wid + 1) lo = mid + 1; else hi = mid; }
    int end = lo;
    float acc = 0.f;
    for (int n = start; n < end; ++n)
        acc += x[(long)n * HID + lane];
    g[(long)wid * HID + lane] = acc;
}

// ---- MLP: one wave per graph. out = relu(g@Wm1+bm1) @ Wm2 + bm2
__global__ void mlp_kernel(const float* __restrict__ g,
                           const float* __restrict__ Wm1,
                           const float* __restrict__ bm1,
                           const float* __restrict__ Wm2,
                           const float* __restrict__ bm2,
                           float* __restrict__ out,
                           int n_graphs) {
    int wid = (blockIdx.x * blockDim.x + threadIdx.x) >> 6;
    int lane = threadIdx.x & 63;
    if (wid >= n_graphs) return;
    const float* gr = g + (long)wid * HID;
    float h0 = bm1[lane];
    float h1 = bm1[lane + 64];
    for (int k = 0; k < HID; ++k) {
        float gv = gr[k];
        h0 += gv * Wm1[k * MLP_HID + lane];
        h1 += gv * Wm1[k * MLP_HID + lane + 64];
    }
    float part = fmaxf(h0, 0.f) * Wm2[lane] + fmaxf(h1, 0.f) * Wm2[lane + 64];
    #pragma unroll
    for (int off = 32; off > 0; off >>= 1)
        part += __shfl_down(part, off, 64);
    if (lane == 0) out[wid] = part + bm2[0];
}

extern "C" void kernel_launch(void* const* d_in, const int* in_sizes, int n_in,
                              void* d_out, int out_size, void* d_ws, size_t ws_size,
                              hipStream_t stream) {
    const float* feats = (const float*)d_in[0];
    const int*   src   = (const int*)d_in[1];
    const int*   dst   = (const int*)d_in[2];
    const int*   gid   = (const int*)d_in[3];
    const float* W[3]  = {(const float*)d_in[4],  (const float*)d_in[8],  (const float*)d_in[12]};
    const float* b[3]  = {(const float*)d_in[5],  (const float*)d_in[9],  (const float*)d_in[13]};
    const float* R[3]  = {(const float*)d_in[6],  (const float*)d_in[10], (const float*)d_in[14]};
    const float* rb[3] = {(const float*)d_in[7],  (const float*)d_in[11], (const float*)d_in[15]};
    const float* Wm1 = (const float*)d_in[16];
    const float* bm1 = (const float*)d_in[17];
    const float* Wm2 = (const float*)d_in[18];
    const float* bm2 = (const float*)d_in[19];
    float* out = (float*)d_out;

    // workspace carve
    char* ws = (char*)d_ws;
    const size_t node_buf = (size_t)N_NODES * HID * sizeof(float);   // 25.6 MB
    float*    xbuf   = (float*)(ws);    ws += node_buf;
    float*    xw     = (float*)(ws);    ws += node_buf;
    float*    res    = (float*)(ws);    ws += node_buf;
    float*    gbuf   = (float*)(ws);    ws += (size_t)N_GRAPHS * HID * sizeof(float);
    int*      cursor = (int*)(ws);      ws += (size_t)NBUCKET * sizeof(int);
    unsigned* pairs  = (unsigned*)(ws); ws += (size_t)NBUCKET * BUCKET_CAP * sizeof(unsigned); // 25.6 MB

    // ---- bucketize edges by dst (replaces CSR build)
    init_cursor_kernel<<<(NBUCKET + 255) / 256, 256, 0, stream>>>(cursor);
    bucket_fill_kernel<<<(N_EDGES + 255) / 256, 256, 0, stream>>>(src, dst, cursor, pairs, N_EDGES);

    const int total = N_NODES * HID;

    for (int l = 0; l < 3; ++l) {
        const float* xin = (l == 0) ? feats : xbuf;
        {
            int blocks = (total + 255) / 256;
            if (l == 0)
                proj_kernel<IN_DIM><<<blocks, 256, 0, stream>>>(xin, W[l], R[l], rb[l], xw, res, N_NODES);
            else
                proj_kernel<HID><<<blocks, 256, 0, stream>>>(xin, W[l], R[l], rb[l], xw, res, N_NODES);
        }
        agg_kernel<<<NBUCKET, 256, 0, stream>>>(xw, pairs, cursor, b[l], res, xbuf);
    }

    // pooling (gather over sorted graph_ids)
    {
        int threads = N_GRAPHS * 64;
        pool_gather_kernel<<<(threads + 255) / 256, 256, 0, stream>>>(xbuf, gid, gbuf, N_GRAPHS);
    }
    // MLP
    {
        int threads = N_GRAPHS * 64;
        mlp_kernel<<<(threads + 255) / 256, 256, 0, stream>>>(gbuf, Wm1, bm1, Wm2, bm2, out, N_GRAPHS);
    }
}

// Round 4
// 1631.736 us; speedup vs baseline: 3.2585x; 3.2585x over previous
//
#include <hip/hip_runtime.h>

#define N_NODES 100000
#define N_EDGES 3200000
#define N_GRAPHS 4096
#define IN_DIM 74
#define HID 64
#define MLP_HID 128

#define BKT_NODES 128                 // nodes per bucket
#define NBUCKET ((N_NODES + BKT_NODES - 1) / BKT_NODES)   // 782
#define BUCKET_CAP 8192               // edges capacity per bucket (mean ~4092, max ~4400)

// ---- projection: xw = x@W ; res = relu(x@R + rb). One thread per (node, f).
template<int IN>
__global__ void proj_kernel(const float* __restrict__ x,
                            const float* __restrict__ W,
                            const float* __restrict__ R,
                            const float* __restrict__ rb,
                            float* __restrict__ xw,
                            float* __restrict__ res,
                            int n_nodes) {
    int t = blockIdx.x * blockDim.x + threadIdx.x;
    int n = t >> 6;
    int f = t & 63;
    if (n >= n_nodes) return;
    const float* xr = x + (long)n * IN;
    float accW = 0.f, accR = 0.f;
    #pragma unroll 8
    for (int k = 0; k < IN; ++k) {
        float xv = xr[k];
        accW += xv * W[k * HID + f];
        accR += xv * R[k * HID + f];
    }
    xw[(long)n * HID + f] = accW;
    res[(long)n * HID + f] = fmaxf(accR + rb[f], 0.f);
}

// ---- cursor init: cursor[b] = b * BUCKET_CAP
__global__ void init_cursor_kernel(int* __restrict__ cursor) {
    int i = blockIdx.x * blockDim.x + threadIdx.x;
    if (i < NBUCKET) cursor[i] = i * BUCKET_CAP;
}

// ---- bucket append: pairs[pos] = src | (dst_local << 17); sequential within bucket
__global__ void bucket_fill_kernel(const int* __restrict__ src,
                                   const int* __restrict__ dst,
                                   int* __restrict__ cursor,
                                   unsigned* __restrict__ pairs,
                                   int n_edges) {
    int e = blockIdx.x * blockDim.x + threadIdx.x;
    if (e >= n_edges) return;
    int d = dst[e];
    int b = d >> 7;
    int pos = atomicAdd(&cursor[b], 1);
    pairs[pos] = (unsigned)src[e] | ((unsigned)(d & (BKT_NODES - 1)) << 17);
}

// ---- per-bucket LDS counting sort: pairs (bucketed) -> src sorted by dst_local,
// written back IN PLACE over the bucket's region; emits row_start/row_deg.
__launch_bounds__(256)
__global__ void bucket_sort_kernel(unsigned* __restrict__ pairs,
                                   const int* __restrict__ cursor,
                                   int* __restrict__ row_start,
                                   int* __restrict__ row_deg) {
    __shared__ unsigned stage[BUCKET_CAP];   // 32 KB
    __shared__ int hist[BKT_NODES];
    __shared__ int offs[BKT_NODES];
    __shared__ int cur[BKT_NODES];
    int bkt = blockIdx.x;
    int tid = threadIdx.x;
    int base = bkt * BUCKET_CAP;
    int cnt = cursor[bkt] - base;

    for (int i = tid; i < BKT_NODES; i += 256) hist[i] = 0;
    __syncthreads();
    for (int e = tid; e < cnt; e += 256) {
        unsigned p = pairs[base + e];
        stage[e] = p;
        atomicAdd(&hist[p >> 17], 1);
    }
    __syncthreads();
    // inclusive scan over 128 bins
    if (tid < BKT_NODES) offs[tid] = hist[tid];
    __syncthreads();
    for (int s = 1; s < BKT_NODES; s <<= 1) {
        int v = (tid < BKT_NODES && tid >= s) ? offs[tid - s] : 0;
        __syncthreads();
        if (tid < BKT_NODES) offs[tid] += v;
        __syncthreads();
    }
    if (tid < BKT_NODES) {
        int ex = offs[tid] - hist[tid];          // exclusive
        cur[tid] = ex;
        int node = bkt * BKT_NODES + tid;
        if (node < N_NODES) {
            row_start[node] = base + ex;
            row_deg[node] = hist[tid];
        }
    }
    __syncthreads();
    for (int e = tid; e < cnt; e += 256) {
        unsigned p = stage[e];
        int pos = atomicAdd(&cur[p >> 17], 1);
        pairs[base + pos] = p & 0x1FFFF;         // store src only
    }
}

// ---- gather aggregation + epilogue: one wave per node, lane = feature.
__global__ void gather_kernel(const float* __restrict__ xw,
                              const int* __restrict__ row_start,
                              const int* __restrict__ row_deg,
                              const unsigned* __restrict__ csr_src,
                              const float* __restrict__ b,
                              const float* __restrict__ res,
                              float* __restrict__ xout,
                              int n_nodes) {
    int wid = (blockIdx.x * blockDim.x + threadIdx.x) >> 6;
    int lane = threadIdx.x & 63;
    if (wid >= n_nodes) return;
    int start = row_start[wid];
    int end = start + row_deg[wid];
    float acc = 0.f;
    int e = start;
    for (; e + 4 <= end; e += 4) {
        unsigned s0 = csr_src[e];
        unsigned s1 = csr_src[e + 1];
        unsigned s2 = csr_src[e + 2];
        unsigned s3 = csr_src[e + 3];
        float v0 = xw[(long)s0 * HID + lane];
        float v1 = xw[(long)s1 * HID + lane];
        float v2 = xw[(long)s2 * HID + lane];
        float v3 = xw[(long)s3 * HID + lane];
        acc += (v0 + v1) + (v2 + v3);
    }
    for (; e < end; ++e)
        acc += xw[(long)csr_src[e] * HID + lane];
    long o = (long)wid * HID + lane;
    xout[o] = fmaxf(acc + b[lane], 0.f) + res[o];
}

// ---- pooling gather: graph_ids sorted -> binary search range, one wave/graph
__global__ void pool_gather_kernel(const float* __restrict__ x,
                                   const int* __restrict__ gid,
                                   float* __restrict__ g,
                                   int n_graphs) {
    int wid = (blockIdx.x * blockDim.x + threadIdx.x) >> 6;
    int lane = threadIdx.x & 63;
    if (wid >= n_graphs) return;
    int lo = 0, hi = N_NODES;
    while (lo < hi) { int mid = (lo + hi) >> 1; if (gid[mid] < wid) lo = mid + 1; else hi = mid; }
    int start = lo;
    hi = N_NODES;
    while (lo < hi) { int mid = (lo + hi) >> 1; if (gid[mid] < wid + 1) lo = mid + 1; else hi = mid; }
    int end = lo;
    float acc = 0.f;
    for (int n = start; n < end; ++n)
        acc += x[(long)n * HID + lane];
    g[(long)wid * HID + lane] = acc;
}

// ---- MLP: one wave per graph. out = relu(g@Wm1+bm1) @ Wm2 + bm2
__global__ void mlp_kernel(const float* __restrict__ g,
                           const float* __restrict__ Wm1,
                           const float* __restrict__ bm1,
                           const float* __restrict__ Wm2,
                           const float* __restrict__ bm2,
                           float* __restrict__ out,
                           int n_graphs) {
    int wid = (blockIdx.x * blockDim.x + threadIdx.x) >> 6;
    int lane = threadIdx.x & 63;
    if (wid >= n_graphs) return;
    const float* gr = g + (long)wid * HID;
    float h0 = bm1[lane];
    float h1 = bm1[lane + 64];
    for (int k = 0; k < HID; ++k) {
        float gv = gr[k];
        h0 += gv * Wm1[k * MLP_HID + lane];
        h1 += gv * Wm1[k * MLP_HID + lane + 64];
    }
    float part = fmaxf(h0, 0.f) * Wm2[lane] + fmaxf(h1, 0.f) * Wm2[lane + 64];
    #pragma unroll
    for (int off = 32; off > 0; off >>= 1)
        part += __shfl_down(part, off, 64);
    if (lane == 0) out[wid] = part + bm2[0];
}

extern "C" void kernel_launch(void* const* d_in, const int* in_sizes, int n_in,
                              void* d_out, int out_size, void* d_ws, size_t ws_size,
                              hipStream_t stream) {
    const float* feats = (const float*)d_in[0];
    const int*   src   = (const int*)d_in[1];
    const int*   dst   = (const int*)d_in[2];
    const int*   gid   = (const int*)d_in[3];
    const float* W[3]  = {(const float*)d_in[4],  (const float*)d_in[8],  (const float*)d_in[12]};
    const float* b[3]  = {(const float*)d_in[5],  (const float*)d_in[9],  (const float*)d_in[13]};
    const float* R[3]  = {(const float*)d_in[6],  (const float*)d_in[10], (const float*)d_in[14]};
    const float* rb[3] = {(const float*)d_in[7],  (const float*)d_in[11], (const float*)d_in[15]};
    const float* Wm1 = (const float*)d_in[16];
    const float* bm1 = (const float*)d_in[17];
    const float* Wm2 = (const float*)d_in[18];
    const float* bm2 = (const float*)d_in[19];
    float* out = (float*)d_out;

    // workspace carve
    char* ws = (char*)d_ws;
    const size_t node_buf = (size_t)N_NODES * HID * sizeof(float);   // 25.6 MB
    float*    xbuf      = (float*)(ws);    ws += node_buf;
    float*    xw        = (float*)(ws);    ws += node_buf;
    float*    res       = (float*)(ws);    ws += node_buf;
    float*    gbuf      = (float*)(ws);    ws += (size_t)N_GRAPHS * HID * sizeof(float);
    int*      cursor    = (int*)(ws);      ws += (size_t)NBUCKET * sizeof(int);
    int*      row_start = (int*)(ws);      ws += (size_t)N_NODES * sizeof(int);
    int*      row_deg   = (int*)(ws);      ws += (size_t)N_NODES * sizeof(int);
    unsigned* pairs     = (unsigned*)(ws); ws += (size_t)NBUCKET * BUCKET_CAP * sizeof(unsigned); // 25.6 MB

    // ---- build bucketed CSR (by dst)
    init_cursor_kernel<<<(NBUCKET + 255) / 256, 256, 0, stream>>>(cursor);
    bucket_fill_kernel<<<(N_EDGES + 255) / 256, 256, 0, stream>>>(src, dst, cursor, pairs, N_EDGES);
    bucket_sort_kernel<<<NBUCKET, 256, 0, stream>>>(pairs, cursor, row_start, row_deg);

    const int total = N_NODES * HID;

    for (int l = 0; l < 3; ++l) {
        const float* xin = (l == 0) ? feats : xbuf;
        {
            int blocks = (total + 255) / 256;
            if (l == 0)
                proj_kernel<IN_DIM><<<blocks, 256, 0, stream>>>(xin, W[l], R[l], rb[l], xw, res, N_NODES);
            else
                proj_kernel<HID><<<blocks, 256, 0, stream>>>(xin, W[l], R[l], rb[l], xw, res, N_NODES);
        }
        {
            int blocks = (total + 255) / 256;  // one wave per node
            gather_kernel<<<blocks, 256, 0, stream>>>(xw, row_start, row_deg, pairs, b[l], res, xbuf, N_NODES);
        }
    }

    // pooling
    {
        int threads = N_GRAPHS * 64;
        pool_gather_kernel<<<(threads + 255) / 256, 256, 0, stream>>>(xbuf, gid, gbuf, N_GRAPHS);
    }
    // MLP
    {
        int threads = N_GRAPHS * 64;
        mlp_kernel<<<(threads + 255) / 256, 256, 0, stream>>>(gbuf, Wm1, bm1, Wm2, bm2, out, N_GRAPHS);
    }
}

// Round 5
// 928.140 us; speedup vs baseline: 5.7287x; 1.7581x over previous
//
#include <hip/hip_runtime.h>

#define N_NODES 100000
#define N_EDGES 3200000
#define N_GRAPHS 4096
#define IN_DIM 74
#define HID 64
#define MLP_HID 128

#define BKT_NODES 128                 // nodes per bucket
#define NBUCKET ((N_NODES + BKT_NODES - 1) / BKT_NODES)   // 782
#define BUCKET_CAP 8192               // edges capacity per bucket (mean ~4096, 64-sigma safe)
#define NBLK 256                      // split blocks
#define CHUNK ((N_EDGES + NBLK - 1) / NBLK)               // 12500

// ---- projection: xw = x@W ; res = relu(x@R + rb). One thread per (node, f).
template<int IN>
__global__ void proj_kernel(const float* __restrict__ x,
                            const float* __restrict__ W,
                            const float* __restrict__ R,
                            const float* __restrict__ rb,
                            float* __restrict__ xw,
                            float* __restrict__ res,
                            int n_nodes) {
    int t = blockIdx.x * blockDim.x + threadIdx.x;
    int n = t >> 6;
    int f = t & 63;
    if (n >= n_nodes) return;
    const float* xr = x + (long)n * IN;
    float accW = 0.f, accR = 0.f;
    #pragma unroll 8
    for (int k = 0; k < IN; ++k) {
        float xv = xr[k];
        accW += xv * W[k * HID + f];
        accR += xv * R[k * HID + f];
    }
    xw[(long)n * HID + f] = accW;
    res[(long)n * HID + f] = fmaxf(accR + rb[f], 0.f);
}

// ---- split pass 1: per-block LDS histogram of dst buckets
__launch_bounds__(256)
__global__ void split_hist_kernel(const int* __restrict__ dst,
                                  int* __restrict__ blockHist /*[NBUCKET][NBLK]*/) {
    __shared__ int h[NBUCKET];
    int blk = blockIdx.x, tid = threadIdx.x;
    for (int i = tid; i < NBUCKET; i += 256) h[i] = 0;
    __syncthreads();
    int lo = blk * CHUNK;
    int hi = lo + CHUNK; if (hi > N_EDGES) hi = N_EDGES;
    for (int e = lo + tid; e < hi; e += 256)
        atomicAdd(&h[dst[e] >> 7], 1);
    __syncthreads();
    for (int i = tid; i < NBUCKET; i += 256)
        blockHist[i * NBLK + blk] = h[i];
}

// ---- split pass 2: per-bucket exclusive scan over the 256 block counts.
// blockHist[bkt][blk] := bkt*BUCKET_CAP + exclusive_prefix; cursor[bkt] := end.
__launch_bounds__(256)
__global__ void split_scan_kernel(int* __restrict__ blockHist,
                                  int* __restrict__ cursor) {
    __shared__ int s[NBLK];
    int bkt = blockIdx.x, tid = threadIdx.x;
    int v = blockHist[bkt * NBLK + tid];
    s[tid] = v;
    __syncthreads();
    for (int off = 1; off < NBLK; off <<= 1) {
        int t = (tid >= off) ? s[tid - off] : 0;
        __syncthreads();
        s[tid] += t;
        __syncthreads();
    }
    blockHist[bkt * NBLK + tid] = bkt * BUCKET_CAP + s[tid] - v;   // exclusive
    if (tid == NBLK - 1) cursor[bkt] = bkt * BUCKET_CAP + s[tid]; // total end
}

// ---- split pass 3: scatter to exact positions (LDS cursors, no global atomics)
__launch_bounds__(256)
__global__ void split_scatter_kernel(const int* __restrict__ src,
                                     const int* __restrict__ dst,
                                     const int* __restrict__ blockHist,
                                     unsigned* __restrict__ pairs) {
    __shared__ int cur[NBUCKET];
    int blk = blockIdx.x, tid = threadIdx.x;
    for (int i = tid; i < NBUCKET; i += 256)
        cur[i] = blockHist[i * NBLK + blk];
    __syncthreads();
    int lo = blk * CHUNK;
    int hi = lo + CHUNK; if (hi > N_EDGES) hi = N_EDGES;
    for (int e = lo + tid; e < hi; e += 256) {
        int d = dst[e];
        int b = d >> 7;
        int pos = atomicAdd(&cur[b], 1);
        pairs[pos] = (unsigned)src[e] | ((unsigned)(d & (BKT_NODES - 1)) << 17);
    }
}

// ---- per-bucket LDS counting sort: pairs -> src sorted by dst_local (in place);
// emits row_start/row_deg.
__launch_bounds__(256)
__global__ void bucket_sort_kernel(unsigned* __restrict__ pairs,
                                   const int* __restrict__ cursor,
                                   int* __restrict__ row_start,
                                   int* __restrict__ row_deg) {
    __shared__ unsigned stage[BUCKET_CAP];   // 32 KB
    __shared__ int hist[BKT_NODES];
    __shared__ int offs[BKT_NODES];
    __shared__ int cur[BKT_NODES];
    int bkt = blockIdx.x;
    int tid = threadIdx.x;
    int base = bkt * BUCKET_CAP;
    int cnt = cursor[bkt] - base;

    for (int i = tid; i < BKT_NODES; i += 256) hist[i] = 0;
    __syncthreads();
    for (int e = tid; e < cnt; e += 256) {
        unsigned p = pairs[base + e];
        stage[e] = p;
        atomicAdd(&hist[p >> 17], 1);
    }
    __syncthreads();
    if (tid < BKT_NODES) offs[tid] = hist[tid];
    __syncthreads();
    for (int s = 1; s < BKT_NODES; s <<= 1) {
        int v = (tid < BKT_NODES && tid >= s) ? offs[tid - s] : 0;
        __syncthreads();
        if (tid < BKT_NODES) offs[tid] += v;
        __syncthreads();
    }
    if (tid < BKT_NODES) {
        int ex = offs[tid] - hist[tid];
        cur[tid] = ex;
        int node = bkt * BKT_NODES + tid;
        if (node < N_NODES) {
            row_start[node] = base + ex;
            row_deg[node] = hist[tid];
        }
    }
    __syncthreads();
    for (int e = tid; e < cnt; e += 256) {
        unsigned p = stage[e];
        int pos = atomicAdd(&cur[p >> 17], 1);
        pairs[base + pos] = p & 0x1FFFF;   // store src only
    }
}

// ---- gather aggregation + epilogue: one wave per node, lane = feature.
__global__ void gather_kernel(const float* __restrict__ xw,
                              const int* __restrict__ row_start,
                              const int* __restrict__ row_deg,
                              const unsigned* __restrict__ csr_src,
                              const float* __restrict__ b,
                              const float* __restrict__ res,
                              float* __restrict__ xout,
                              int n_nodes) {
    int wid = (blockIdx.x * blockDim.x + threadIdx.x) >> 6;
    int lane = threadIdx.x & 63;
    if (wid >= n_nodes) return;
    int start = row_start[wid];
    int end = start + row_deg[wid];
    float acc = 0.f;
    int e = start;
    for (; e + 4 <= end; e += 4) {
        unsigned s0 = csr_src[e];
        unsigned s1 = csr_src[e + 1];
        unsigned s2 = csr_src[e + 2];
        unsigned s3 = csr_src[e + 3];
        float v0 = xw[(long)s0 * HID + lane];
        float v1 = xw[(long)s1 * HID + lane];
        float v2 = xw[(long)s2 * HID + lane];
        float v3 = xw[(long)s3 * HID + lane];
        acc += (v0 + v1) + (v2 + v3);
    }
    for (; e < end; ++e)
        acc += xw[(long)csr_src[e] * HID + lane];
    long o = (long)wid * HID + lane;
    xout[o] = fmaxf(acc + b[lane], 0.f) + res[o];
}

// ---- pooling gather: graph_ids sorted -> binary search range, one wave/graph
__global__ void pool_gather_kernel(const float* __restrict__ x,
                                   const int* __restrict__ gid,
                                   float* __restrict__ g,
                                   int n_graphs) {
    int wid = (blockIdx.x * blockDim.x + threadIdx.x) >> 6;
    int lane = threadIdx.x & 63;
    if (wid >= n_graphs) return;
    int lo = 0, hi = N_NODES;
    while (lo < hi) { int mid = (lo + hi) >> 1; if (gid[mid] < wid) lo = mid + 1; else hi = mid; }
    int start = lo;
    hi = N_NODES;
    while (lo < hi) { int mid = (lo + hi) >> 1; if (gid[mid] < wid + 1) lo = mid + 1; else hi = mid; }
    int end = lo;
    float acc = 0.f;
    for (int n = start; n < end; ++n)
        acc += x[(long)n * HID + lane];
    g[(long)wid * HID + lane] = acc;
}

// ---- MLP: one wave per graph. out = relu(g@Wm1+bm1) @ Wm2 + bm2
__global__ void mlp_kernel(const float* __restrict__ g,
                           const float* __restrict__ Wm1,
                           const float* __restrict__ bm1,
                           const float* __restrict__ Wm2,
                           const float* __restrict__ bm2,
                           float* __restrict__ out,
                           int n_graphs) {
    int wid = (blockIdx.x * blockDim.x + threadIdx.x) >> 6;
    int lane = threadIdx.x & 63;
    if (wid >= n_graphs) return;
    const float* gr = g + (long)wid * HID;
    float h0 = bm1[lane];
    float h1 = bm1[lane + 64];
    for (int k = 0; k < HID; ++k) {
        float gv = gr[k];
        h0 += gv * Wm1[k * MLP_HID + lane];
        h1 += gv * Wm1[k * MLP_HID + lane + 64];
    }
    float part = fmaxf(h0, 0.f) * Wm2[lane] + fmaxf(h1, 0.f) * Wm2[lane + 64];
    #pragma unroll
    for (int off = 32; off > 0; off >>= 1)
        part += __shfl_down(part, off, 64);
    if (lane == 0) out[wid] = part + bm2[0];
}

extern "C" void kernel_launch(void* const* d_in, const int* in_sizes, int n_in,
                              void* d_out, int out_size, void* d_ws, size_t ws_size,
                              hipStream_t stream) {
    const float* feats = (const float*)d_in[0];
    const int*   src   = (const int*)d_in[1];
    const int*   dst   = (const int*)d_in[2];
    const int*   gid   = (const int*)d_in[3];
    const float* W[3]  = {(const float*)d_in[4],  (const float*)d_in[8],  (const float*)d_in[12]};
    const float* b[3]  = {(const float*)d_in[5],  (const float*)d_in[9],  (const float*)d_in[13]};
    const float* R[3]  = {(const float*)d_in[6],  (const float*)d_in[10], (const float*)d_in[14]};
    const float* rb[3] = {(const float*)d_in[7],  (const float*)d_in[11], (const float*)d_in[15]};
    const float* Wm1 = (const float*)d_in[16];
    const float* bm1 = (const float*)d_in[17];
    const float* Wm2 = (const float*)d_in[18];
    const float* bm2 = (const float*)d_in[19];
    float* out = (float*)d_out;

    // workspace carve
    char* ws = (char*)d_ws;
    const size_t node_buf = (size_t)N_NODES * HID * sizeof(float);   // 25.6 MB
    float*    xbuf      = (float*)(ws);    ws += node_buf;
    float*    xw        = (float*)(ws);    ws += node_buf;
    float*    res       = (float*)(ws);    ws += node_buf;
    float*    gbuf      = (float*)(ws);    ws += (size_t)N_GRAPHS * HID * sizeof(float);
    int*      cursor    = (int*)(ws);      ws += (size_t)NBUCKET * sizeof(int);
    int*      row_start = (int*)(ws);      ws += (size_t)N_NODES * sizeof(int);
    int*      row_deg   = (int*)(ws);      ws += (size_t)N_NODES * sizeof(int);
    int*      blockHist = (int*)(ws);      ws += (size_t)NBUCKET * NBLK * sizeof(int);  // 800 KB
    unsigned* pairs     = (unsigned*)(ws); ws += (size_t)NBUCKET * BUCKET_CAP * sizeof(unsigned); // 25.6 MB

    // ---- build bucketed CSR (by dst): deterministic two-pass multisplit
    split_hist_kernel<<<NBLK, 256, 0, stream>>>(dst, blockHist);
    split_scan_kernel<<<NBUCKET, NBLK, 0, stream>>>(blockHist, cursor);
    split_scatter_kernel<<<NBLK, 256, 0, stream>>>(src, dst, blockHist, pairs);
    bucket_sort_kernel<<<NBUCKET, 256, 0, stream>>>(pairs, cursor, row_start, row_deg);

    const int total = N_NODES * HID;

    for (int l = 0; l < 3; ++l) {
        const float* xin = (l == 0) ? feats : xbuf;
        {
            int blocks = (total + 255) / 256;
            if (l == 0)
                proj_kernel<IN_DIM><<<blocks, 256, 0, stream>>>(xin, W[l], R[l], rb[l], xw, res, N_NODES);
            else
                proj_kernel<HID><<<blocks, 256, 0, stream>>>(xin, W[l], R[l], rb[l], xw, res, N_NODES);
        }
        {
            int blocks = (total + 255) / 256;  // one wave per node
            gather_kernel<<<blocks, 256, 0, stream>>>(xw, row_start, row_deg, pairs, b[l], res, xbuf, N_NODES);
        }
    }

    // pooling
    {
        int threads = N_GRAPHS * 64;
        pool_gather_kernel<<<(threads + 255) / 256, 256, 0, stream>>>(xbuf, gid, gbuf, N_GRAPHS);
    }
    // MLP
    {
        int threads = N_GRAPHS * 64;
        mlp_kernel<<<(threads + 255) / 256, 256, 0, stream>>>(gbuf, Wm1, bm1, Wm2, bm2, out, N_GRAPHS);
    }
}

// Round 6
// 815.018 us; speedup vs baseline: 6.5238x; 1.1388x over previous
//
#include <hip/hip_runtime.h>

#define N_NODES 100000
#define N_EDGES 3200000
#define N_GRAPHS 4096
#define IN_DIM 74
#define HID 64
#define MLP_HID 128

#define BKT_NODES 128                 // nodes per bucket
#define NBUCKET ((N_NODES + BKT_NODES - 1) / BKT_NODES)   // 782
#define BUCKET_CAP 8192               // edges capacity per bucket (mean ~4096)
#define NBLK 256                      // split blocks
#define CHUNK ((N_EDGES + NBLK - 1) / NBLK)               // 12500

// ---- projection: xw = x@W ; res = relu(x@R + rb).
// 8 threads per node, 8 output features per thread, float4 weight loads.
template<int IN>
__launch_bounds__(256)
__global__ void proj_kernel(const float* __restrict__ x,
                            const float* __restrict__ W,
                            const float* __restrict__ R,
                            const float* __restrict__ rb,
                            float* __restrict__ xw,
                            float* __restrict__ res,
                            int n_nodes) {
    int t = blockIdx.x * blockDim.x + threadIdx.x;
    int n = t >> 3;
    int fb = (t & 7) << 3;            // feature base: 0,8,...,56
    if (n >= n_nodes) return;
    const float* xr = x + (long)n * IN;
    float accW[8] = {0.f, 0.f, 0.f, 0.f, 0.f, 0.f, 0.f, 0.f};
    float accR[8] = {0.f, 0.f, 0.f, 0.f, 0.f, 0.f, 0.f, 0.f};
    #pragma unroll 2
    for (int k = 0; k < IN; ++k) {
        float xv = xr[k];
        const float4 w0 = *reinterpret_cast<const float4*>(&W[k * HID + fb]);
        const float4 w1 = *reinterpret_cast<const float4*>(&W[k * HID + fb + 4]);
        const float4 r0 = *reinterpret_cast<const float4*>(&R[k * HID + fb]);
        const float4 r1 = *reinterpret_cast<const float4*>(&R[k * HID + fb + 4]);
        accW[0] += xv * w0.x; accW[1] += xv * w0.y; accW[2] += xv * w0.z; accW[3] += xv * w0.w;
        accW[4] += xv * w1.x; accW[5] += xv * w1.y; accW[6] += xv * w1.z; accW[7] += xv * w1.w;
        accR[0] += xv * r0.x; accR[1] += xv * r0.y; accR[2] += xv * r0.z; accR[3] += xv * r0.w;
        accR[4] += xv * r1.x; accR[5] += xv * r1.y; accR[6] += xv * r1.z; accR[7] += xv * r1.w;
    }
    long o = (long)n * HID + fb;
    float4 s0 = make_float4(accW[0], accW[1], accW[2], accW[3]);
    float4 s1 = make_float4(accW[4], accW[5], accW[6], accW[7]);
    *reinterpret_cast<float4*>(&xw[o])     = s0;
    *reinterpret_cast<float4*>(&xw[o + 4]) = s1;
    float4 q0, q1;
    q0.x = fmaxf(accR[0] + rb[fb + 0], 0.f);
    q0.y = fmaxf(accR[1] + rb[fb + 1], 0.f);
    q0.z = fmaxf(accR[2] + rb[fb + 2], 0.f);
    q0.w = fmaxf(accR[3] + rb[fb + 3], 0.f);
    q1.x = fmaxf(accR[4] + rb[fb + 4], 0.f);
    q1.y = fmaxf(accR[5] + rb[fb + 5], 0.f);
    q1.z = fmaxf(accR[6] + rb[fb + 6], 0.f);
    q1.w = fmaxf(accR[7] + rb[fb + 7], 0.f);
    *reinterpret_cast<float4*>(&res[o])     = q0;
    *reinterpret_cast<float4*>(&res[o + 4]) = q1;
}

// ---- split pass 1: per-block LDS histogram of dst buckets
__launch_bounds__(256)
__global__ void split_hist_kernel(const int* __restrict__ dst,
                                  int* __restrict__ blockHist /*[NBUCKET][NBLK]*/) {
    __shared__ int h[NBUCKET];
    int blk = blockIdx.x, tid = threadIdx.x;
    for (int i = tid; i < NBUCKET; i += 256) h[i] = 0;
    __syncthreads();
    int lo = blk * CHUNK;
    int hi = lo + CHUNK; if (hi > N_EDGES) hi = N_EDGES;
    for (int e = lo + tid; e < hi; e += 256)
        atomicAdd(&h[dst[e] >> 7], 1);
    __syncthreads();
    for (int i = tid; i < NBUCKET; i += 256)
        blockHist[i * NBLK + blk] = h[i];
}

// ---- split pass 2: per-bucket exclusive scan over the 256 block counts.
__launch_bounds__(256)
__global__ void split_scan_kernel(int* __restrict__ blockHist,
                                  int* __restrict__ cursor) {
    __shared__ int s[NBLK];
    int bkt = blockIdx.x, tid = threadIdx.x;
    int v = blockHist[bkt * NBLK + tid];
    s[tid] = v;
    __syncthreads();
    for (int off = 1; off < NBLK; off <<= 1) {
        int t = (tid >= off) ? s[tid - off] : 0;
        __syncthreads();
        s[tid] += t;
        __syncthreads();
    }
    blockHist[bkt * NBLK + tid] = bkt * BUCKET_CAP + s[tid] - v;   // exclusive
    if (tid == NBLK - 1) cursor[bkt] = bkt * BUCKET_CAP + s[tid]; // total end
}

// ---- split pass 3: scatter to exact positions (LDS cursors, no global atomics)
__launch_bounds__(256)
__global__ void split_scatter_kernel(const int* __restrict__ src,
                                     const int* __restrict__ dst,
                                     const int* __restrict__ blockHist,
                                     unsigned* __restrict__ pairs) {
    __shared__ int cur[NBUCKET];
    int blk = blockIdx.x, tid = threadIdx.x;
    for (int i = tid; i < NBUCKET; i += 256)
        cur[i] = blockHist[i * NBLK + blk];
    __syncthreads();
    int lo = blk * CHUNK;
    int hi = lo + CHUNK; if (hi > N_EDGES) hi = N_EDGES;
    for (int e = lo + tid; e < hi; e += 256) {
        int d = dst[e];
        int b = d >> 7;
        int pos = atomicAdd(&cur[b], 1);
        pairs[pos] = (unsigned)src[e] | ((unsigned)(d & (BKT_NODES - 1)) << 17);
    }
}

// ---- per-bucket LDS counting sort -> src sorted by dst_local; row_start/row_deg
__launch_bounds__(256)
__global__ void bucket_sort_kernel(unsigned* __restrict__ pairs,
                                   const int* __restrict__ cursor,
                                   int* __restrict__ row_start,
                                   int* __restrict__ row_deg) {
    __shared__ unsigned stage[BUCKET_CAP];   // 32 KB
    __shared__ int hist[BKT_NODES];
    __shared__ int offs[BKT_NODES];
    __shared__ int cur[BKT_NODES];
    int bkt = blockIdx.x;
    int tid = threadIdx.x;
    int base = bkt * BUCKET_CAP;
    int cnt = cursor[bkt] - base;

    for (int i = tid; i < BKT_NODES; i += 256) hist[i] = 0;
    __syncthreads();
    for (int e = tid; e < cnt; e += 256) {
        unsigned p = pairs[base + e];
        stage[e] = p;
        atomicAdd(&hist[p >> 17], 1);
    }
    __syncthreads();
    if (tid < BKT_NODES) offs[tid] = hist[tid];
    __syncthreads();
    for (int s = 1; s < BKT_NODES; s <<= 1) {
        int v = (tid < BKT_NODES && tid >= s) ? offs[tid - s] : 0;
        __syncthreads();
        if (tid < BKT_NODES) offs[tid] += v;
        __syncthreads();
    }
    if (tid < BKT_NODES) {
        int ex = offs[tid] - hist[tid];
        cur[tid] = ex;
        int node = bkt * BKT_NODES + tid;
        if (node < N_NODES) {
            row_start[node] = base + ex;
            row_deg[node] = hist[tid];
        }
    }
    __syncthreads();
    for (int e = tid; e < cnt; e += 256) {
        unsigned p = stage[e];
        int pos = atomicAdd(&cur[p >> 17], 1);
        pairs[base + pos] = p & 0x1FFFF;   // store src only
    }
}

// ---- gather aggregation + epilogue: one wave per node, lane = feature.
__global__ void gather_kernel(const float* __restrict__ xw,
                              const int* __restrict__ row_start,
                              const int* __restrict__ row_deg,
                              const unsigned* __restrict__ csr_src,
                              const float* __restrict__ b,
                              const float* __restrict__ res,
                              float* __restrict__ xout,
                              int n_nodes) {
    int wid = (blockIdx.x * blockDim.x + threadIdx.x) >> 6;
    int lane = threadIdx.x & 63;
    if (wid >= n_nodes) return;
    int start = row_start[wid];
    int end = start + row_deg[wid];
    float acc = 0.f;
    int e = start;
    for (; e + 4 <= end; e += 4) {
        unsigned s0 = csr_src[e];
        unsigned s1 = csr_src[e + 1];
        unsigned s2 = csr_src[e + 2];
        unsigned s3 = csr_src[e + 3];
        float v0 = xw[(long)s0 * HID + lane];
        float v1 = xw[(long)s1 * HID + lane];
        float v2 = xw[(long)s2 * HID + lane];
        float v3 = xw[(long)s3 * HID + lane];
        acc += (v0 + v1) + (v2 + v3);
    }
    for (; e < end; ++e)
        acc += xw[(long)csr_src[e] * HID + lane];
    long o = (long)wid * HID + lane;
    xout[o] = fmaxf(acc + b[lane], 0.f) + res[o];
}

// ---- pooling gather: graph_ids sorted -> binary search range, one wave/graph
__global__ void pool_gather_kernel(const float* __restrict__ x,
                                   const int* __restrict__ gid,
                                   float* __restrict__ g,
                                   int n_graphs) {
    int wid = (blockIdx.x * blockDim.x + threadIdx.x) >> 6;
    int lane = threadIdx.x & 63;
    if (wid >= n_graphs) return;
    int lo = 0, hi = N_NODES;
    while (lo < hi) { int mid = (lo + hi) >> 1; if (gid[mid] < wid) lo = mid + 1; else hi = mid; }
    int start = lo;
    hi = N_NODES;
    while (lo < hi) { int mid = (lo + hi) >> 1; if (gid[mid] < wid + 1) lo = mid + 1; else hi = mid; }
    int end = lo;
    float acc = 0.f;
    for (int n = start; n < end; ++n)
        acc += x[(long)n * HID + lane];
    g[(long)wid * HID + lane] = acc;
}

// ---- MLP: one wave per graph. out = relu(g@Wm1+bm1) @ Wm2 + bm2
__global__ void mlp_kernel(const float* __restrict__ g,
                           const float* __restrict__ Wm1,
                           const float* __restrict__ bm1,
                           const float* __restrict__ Wm2,
                           const float* __restrict__ bm2,
                           float* __restrict__ out,
                           int n_graphs) {
    int wid = (blockIdx.x * blockDim.x + threadIdx.x) >> 6;
    int lane = threadIdx.x & 63;
    if (wid >= n_graphs) return;
    const float* gr = g + (long)wid * HID;
    float h0 = bm1[lane];
    float h1 = bm1[lane + 64];
    for (int k = 0; k < HID; ++k) {
        float gv = gr[k];
        h0 += gv * Wm1[k * MLP_HID + lane];
        h1 += gv * Wm1[k * MLP_HID + lane + 64];
    }
    float part = fmaxf(h0, 0.f) * Wm2[lane] + fmaxf(h1, 0.f) * Wm2[lane + 64];
    #pragma unroll
    for (int off = 32; off > 0; off >>= 1)
        part += __shfl_down(part, off, 64);
    if (lane == 0) out[wid] = part + bm2[0];
}

extern "C" void kernel_launch(void* const* d_in, const int* in_sizes, int n_in,
                              void* d_out, int out_size, void* d_ws, size_t ws_size,
                              hipStream_t stream) {
    const float* feats = (const float*)d_in[0];
    const int*   src   = (const int*)d_in[1];
    const int*   dst   = (const int*)d_in[2];
    const int*   gid   = (const int*)d_in[3];
    const float* W[3]  = {(const float*)d_in[4],  (const float*)d_in[8],  (const float*)d_in[12]};
    const float* b[3]  = {(const float*)d_in[5],  (const float*)d_in[9],  (const float*)d_in[13]};
    const float* R[3]  = {(const float*)d_in[6],  (const float*)d_in[10], (const float*)d_in[14]};
    const float* rb[3] = {(const float*)d_in[7],  (const float*)d_in[11], (const float*)d_in[15]};
    const float* Wm1 = (const float*)d_in[16];
    const float* bm1 = (const float*)d_in[17];
    const float* Wm2 = (const float*)d_in[18];
    const float* bm2 = (const float*)d_in[19];
    float* out = (float*)d_out;

    // workspace carve
    char* ws = (char*)d_ws;
    const size_t node_buf = (size_t)N_NODES * HID * sizeof(float);   // 25.6 MB
    float*    xbuf      = (float*)(ws);    ws += node_buf;
    float*    xw        = (float*)(ws);    ws += node_buf;
    float*    res       = (float*)(ws);    ws += node_buf;
    float*    gbuf      = (float*)(ws);    ws += (size_t)N_GRAPHS * HID * sizeof(float);
    int*      cursor    = (int*)(ws);      ws += (size_t)NBUCKET * sizeof(int);
    int*      row_start = (int*)(ws);      ws += (size_t)N_NODES * sizeof(int);
    int*      row_deg   = (int*)(ws);      ws += (size_t)N_NODES * sizeof(int);
    int*      blockHist = (int*)(ws);      ws += (size_t)NBUCKET * NBLK * sizeof(int);  // 800 KB
    unsigned* pairs     = (unsigned*)(ws); ws += (size_t)NBUCKET * BUCKET_CAP * sizeof(unsigned); // 25.6 MB

    // ---- build bucketed CSR (by dst): deterministic two-pass multisplit
    split_hist_kernel<<<NBLK, 256, 0, stream>>>(dst, blockHist);
    split_scan_kernel<<<NBUCKET, NBLK, 0, stream>>>(blockHist, cursor);
    split_scatter_kernel<<<NBLK, 256, 0, stream>>>(src, dst, blockHist, pairs);
    bucket_sort_kernel<<<NBUCKET, 256, 0, stream>>>(pairs, cursor, row_start, row_deg);

    for (int l = 0; l < 3; ++l) {
        const float* xin = (l == 0) ? feats : xbuf;
        {
            int threads = N_NODES * 8;            // 8 threads per node
            int blocks = (threads + 255) / 256;
            if (l == 0)
                proj_kernel<IN_DIM><<<blocks, 256, 0, stream>>>(xin, W[l], R[l], rb[l], xw, res, N_NODES);
            else
                proj_kernel<HID><<<blocks, 256, 0, stream>>>(xin, W[l], R[l], rb[l], xw, res, N_NODES);
        }
        {
            int blocks = (N_NODES * 64 + 255) / 256;  // one wave per node
            gather_kernel<<<blocks, 256, 0, stream>>>(xw, row_start, row_deg, pairs, b[l], res, xbuf, N_NODES);
        }
    }

    // pooling
    {
        int threads = N_GRAPHS * 64;
        pool_gather_kernel<<<(threads + 255) / 256, 256, 0, stream>>>(xbuf, gid, gbuf, N_GRAPHS);
    }
    // MLP
    {
        int threads = N_GRAPHS * 64;
        mlp_kernel<<<(threads + 255) / 256, 256, 0, stream>>>(gbuf, Wm1, bm1, Wm2, bm2, out, N_GRAPHS);
    }
}

// Round 7
// 688.879 us; speedup vs baseline: 7.7183x; 1.1831x over previous
//
#include <hip/hip_runtime.h>

#define N_NODES 100000
#define N_EDGES 3200000
#define N_GRAPHS 4096
#define IN_DIM 74
#define HID 64
#define MLP_HID 128

#define BKT_NODES 128                 // nodes per bucket
#define NBUCKET ((N_NODES + BKT_NODES - 1) / BKT_NODES)   // 782
#define BUCKET_CAP 8192               // edges capacity per bucket (mean ~4096)
#define NBLK 256                      // split blocks
#define CHUNK ((N_EDGES + NBLK - 1) / NBLK)               // 12500

// ---- projection: xw = x@W ; res = relu(x@R + rb).
// Block: 256 thr stages 64 node-rows of x into LDS; each wave register-blocks
// 16 nodes, lane = feature. Per k: 2 coalesced W/R loads + 16 LDS broadcasts
// + 32 FMAs -> FMA:VMEM = 16:1.
template<int IN>
__launch_bounds__(256)
__global__ void proj_kernel(const float* __restrict__ x,
                            const float* __restrict__ W,
                            const float* __restrict__ R,
                            const float* __restrict__ rb,
                            float* __restrict__ xw,
                            float* __restrict__ res,
                            int n_nodes) {
    __shared__ float xs[64 * IN];
    int n0 = blockIdx.x * 64;
    int tid = threadIdx.x;
    const float* gsrc = x + (long)n0 * IN;
    const int total = 64 * IN;
    int limit = (n_nodes - n0) * IN;
    if (limit >= total) {
        const float4* g4 = reinterpret_cast<const float4*>(gsrc);
        float4* s4 = reinterpret_cast<float4*>(xs);
        #pragma unroll 4
        for (int i = tid; i < total / 4; i += 256) s4[i] = g4[i];
    } else {
        for (int i = tid; i < total; i += 256) xs[i] = (i < limit) ? gsrc[i] : 0.f;
    }
    __syncthreads();

    int w = tid >> 6, f = tid & 63;
    int nb = w * 16;                  // wave's node base within the block
    float accW[16], accR[16];
    #pragma unroll
    for (int j = 0; j < 16; ++j) { accW[j] = 0.f; accR[j] = 0.f; }

    #pragma unroll 2
    for (int k = 0; k < IN; ++k) {
        float wv = W[k * HID + f];
        float rv = R[k * HID + f];
        #pragma unroll
        for (int j = 0; j < 16; ++j) {
            float xv = xs[(nb + j) * IN + k];   // wave-uniform -> LDS broadcast
            accW[j] = fmaf(xv, wv, accW[j]);
            accR[j] = fmaf(xv, rv, accR[j]);
        }
    }
    float rbv = rb[f];
    #pragma unroll
    for (int j = 0; j < 16; ++j) {
        int n = n0 + nb + j;
        if (n < n_nodes) {
            long o = (long)n * HID + f;
            xw[o]  = accW[j];
            res[o] = fmaxf(accR[j] + rbv, 0.f);
        }
    }
}

// ---- split pass 1: per-block LDS histogram of dst buckets
__launch_bounds__(256)
__global__ void split_hist_kernel(const int* __restrict__ dst,
                                  int* __restrict__ blockHist /*[NBUCKET][NBLK]*/) {
    __shared__ int h[NBUCKET];
    int blk = blockIdx.x, tid = threadIdx.x;
    for (int i = tid; i < NBUCKET; i += 256) h[i] = 0;
    __syncthreads();
    int lo = blk * CHUNK;
    int hi = lo + CHUNK; if (hi > N_EDGES) hi = N_EDGES;
    for (int e = lo + tid; e < hi; e += 256)
        atomicAdd(&h[dst[e] >> 7], 1);
    __syncthreads();
    for (int i = tid; i < NBUCKET; i += 256)
        blockHist[i * NBLK + blk] = h[i];
}

// ---- split pass 2: per-bucket exclusive scan over the 256 block counts.
__launch_bounds__(256)
__global__ void split_scan_kernel(int* __restrict__ blockHist,
                                  int* __restrict__ cursor) {
    __shared__ int s[NBLK];
    int bkt = blockIdx.x, tid = threadIdx.x;
    int v = blockHist[bkt * NBLK + tid];
    s[tid] = v;
    __syncthreads();
    for (int off = 1; off < NBLK; off <<= 1) {
        int t = (tid >= off) ? s[tid - off] : 0;
        __syncthreads();
        s[tid] += t;
        __syncthreads();
    }
    blockHist[bkt * NBLK + tid] = bkt * BUCKET_CAP + s[tid] - v;   // exclusive
    if (tid == NBLK - 1) cursor[bkt] = bkt * BUCKET_CAP + s[tid]; // total end
}

// ---- split pass 3: scatter to exact positions (LDS cursors, no global atomics)
__launch_bounds__(256)
__global__ void split_scatter_kernel(const int* __restrict__ src,
                                     const int* __restrict__ dst,
                                     const int* __restrict__ blockHist,
                                     unsigned* __restrict__ pairs) {
    __shared__ int cur[NBUCKET];
    int blk = blockIdx.x, tid = threadIdx.x;
    for (int i = tid; i < NBUCKET; i += 256)
        cur[i] = blockHist[i * NBLK + blk];
    __syncthreads();
    int lo = blk * CHUNK;
    int hi = lo + CHUNK; if (hi > N_EDGES) hi = N_EDGES;
    for (int e = lo + tid; e < hi; e += 256) {
        int d = dst[e];
        int b = d >> 7;
        int pos = atomicAdd(&cur[b], 1);
        pairs[pos] = (unsigned)src[e] | ((unsigned)(d & (BKT_NODES - 1)) << 17);
    }
}

// ---- per-bucket LDS counting sort -> src sorted by dst_local; row_start/row_deg
__launch_bounds__(256)
__global__ void bucket_sort_kernel(unsigned* __restrict__ pairs,
                                   const int* __restrict__ cursor,
                                   int* __restrict__ row_start,
                                   int* __restrict__ row_deg) {
    __shared__ unsigned stage[BUCKET_CAP];   // 32 KB
    __shared__ int hist[BKT_NODES];
    __shared__ int offs[BKT_NODES];
    __shared__ int cur[BKT_NODES];
    int bkt = blockIdx.x;
    int tid = threadIdx.x;
    int base = bkt * BUCKET_CAP;
    int cnt = cursor[bkt] - base;

    for (int i = tid; i < BKT_NODES; i += 256) hist[i] = 0;
    __syncthreads();
    for (int e = tid; e < cnt; e += 256) {
        unsigned p = pairs[base + e];
        stage[e] = p;
        atomicAdd(&hist[p >> 17], 1);
    }
    __syncthreads();
    if (tid < BKT_NODES) offs[tid] = hist[tid];
    __syncthreads();
    for (int s = 1; s < BKT_NODES; s <<= 1) {
        int v = (tid < BKT_NODES && tid >= s) ? offs[tid - s] : 0;
        __syncthreads();
        if (tid < BKT_NODES) offs[tid] += v;
        __syncthreads();
    }
    if (tid < BKT_NODES) {
        int ex = offs[tid] - hist[tid];
        cur[tid] = ex;
        int node = bkt * BKT_NODES + tid;
        if (node < N_NODES) {
            row_start[node] = base + ex;
            row_deg[node] = hist[tid];
        }
    }
    __syncthreads();
    for (int e = tid; e < cnt; e += 256) {
        unsigned p = stage[e];
        int pos = atomicAdd(&cur[p >> 17], 1);
        pairs[base + pos] = p & 0x1FFFF;   // store src only
    }
}

// ---- gather aggregation + epilogue: one wave per node, lane = feature.
__global__ void gather_kernel(const float* __restrict__ xw,
                              const int* __restrict__ row_start,
                              const int* __restrict__ row_deg,
                              const unsigned* __restrict__ csr_src,
                              const float* __restrict__ b,
                              const float* __restrict__ res,
                              float* __restrict__ xout,
                              int n_nodes) {
    int wid = (blockIdx.x * blockDim.x + threadIdx.x) >> 6;
    int lane = threadIdx.x & 63;
    if (wid >= n_nodes) return;
    int start = row_start[wid];
    int end = start + row_deg[wid];
    float acc = 0.f;
    int e = start;
    for (; e + 4 <= end; e += 4) {
        unsigned s0 = csr_src[e];
        unsigned s1 = csr_src[e + 1];
        unsigned s2 = csr_src[e + 2];
        unsigned s3 = csr_src[e + 3];
        float v0 = xw[(long)s0 * HID + lane];
        float v1 = xw[(long)s1 * HID + lane];
        float v2 = xw[(long)s2 * HID + lane];
        float v3 = xw[(long)s3 * HID + lane];
        acc += (v0 + v1) + (v2 + v3);
    }
    for (; e < end; ++e)
        acc += xw[(long)csr_src[e] * HID + lane];
    long o = (long)wid * HID + lane;
    xout[o] = fmaxf(acc + b[lane], 0.f) + res[o];
}

// ---- pooling gather: graph_ids sorted -> binary search range, one wave/graph
__global__ void pool_gather_kernel(const float* __restrict__ x,
                                   const int* __restrict__ gid,
                                   float* __restrict__ g,
                                   int n_graphs) {
    int wid = (blockIdx.x * blockDim.x + threadIdx.x) >> 6;
    int lane = threadIdx.x & 63;
    if (wid >= n_graphs) return;
    int lo = 0, hi = N_NODES;
    while (lo < hi) { int mid = (lo + hi) >> 1; if (gid[mid] < wid) lo = mid + 1; else hi = mid; }
    int start = lo;
    hi = N_NODES;
    while (lo < hi) { int mid = (lo + hi) >> 1; if (gid[mid] < wid + 1) lo = mid + 1; else hi = mid; }
    int end = lo;
    float acc = 0.f;
    for (int n = start; n < end; ++n)
        acc += x[(long)n * HID + lane];
    g[(long)wid * HID + lane] = acc;
}

// ---- MLP: one wave per graph. out = relu(g@Wm1+bm1) @ Wm2 + bm2
__global__ void mlp_kernel(const float* __restrict__ g,
                           const float* __restrict__ Wm1,
                           const float* __restrict__ bm1,
                           const float* __restrict__ Wm2,
                           const float* __restrict__ bm2,
                           float* __restrict__ out,
                           int n_graphs) {
    int wid = (blockIdx.x * blockDim.x + threadIdx.x) >> 6;
    int lane = threadIdx.x & 63;
    if (wid >= n_graphs) return;
    const float* gr = g + (long)wid * HID;
    float h0 = bm1[lane];
    float h1 = bm1[lane + 64];
    for (int k = 0; k < HID; ++k) {
        float gv = gr[k];
        h0 += gv * Wm1[k * MLP_HID + lane];
        h1 += gv * Wm1[k * MLP_HID + lane + 64];
    }
    float part = fmaxf(h0, 0.f) * Wm2[lane] + fmaxf(h1, 0.f) * Wm2[lane + 64];
    #pragma unroll
    for (int off = 32; off > 0; off >>= 1)
        part += __shfl_down(part, off, 64);
    if (lane == 0) out[wid] = part + bm2[0];
}

extern "C" void kernel_launch(void* const* d_in, const int* in_sizes, int n_in,
                              void* d_out, int out_size, void* d_ws, size_t ws_size,
                              hipStream_t stream) {
    const float* feats = (const float*)d_in[0];
    const int*   src   = (const int*)d_in[1];
    const int*   dst   = (const int*)d_in[2];
    const int*   gid   = (const int*)d_in[3];
    const float* W[3]  = {(const float*)d_in[4],  (const float*)d_in[8],  (const float*)d_in[12]};
    const float* b[3]  = {(const float*)d_in[5],  (const float*)d_in[9],  (const float*)d_in[13]};
    const float* R[3]  = {(const float*)d_in[6],  (const float*)d_in[10], (const float*)d_in[14]};
    const float* rb[3] = {(const float*)d_in[7],  (const float*)d_in[11], (const float*)d_in[15]};
    const float* Wm1 = (const float*)d_in[16];
    const float* bm1 = (const float*)d_in[17];
    const float* Wm2 = (const float*)d_in[18];
    const float* bm2 = (const float*)d_in[19];
    float* out = (float*)d_out;

    // workspace carve
    char* ws = (char*)d_ws;
    const size_t node_buf = (size_t)N_NODES * HID * sizeof(float);   // 25.6 MB
    float*    xbuf      = (float*)(ws);    ws += node_buf;
    float*    xw        = (float*)(ws);    ws += node_buf;
    float*    res       = (float*)(ws);    ws += node_buf;
    float*    gbuf      = (float*)(ws);    ws += (size_t)N_GRAPHS * HID * sizeof(float);
    int*      cursor    = (int*)(ws);      ws += (size_t)NBUCKET * sizeof(int);
    int*      row_start = (int*)(ws);      ws += (size_t)N_NODES * sizeof(int);
    int*      row_deg   = (int*)(ws);      ws += (size_t)N_NODES * sizeof(int);
    int*      blockHist = (int*)(ws);      ws += (size_t)NBUCKET * NBLK * sizeof(int);  // 800 KB
    unsigned* pairs     = (unsigned*)(ws); ws += (size_t)NBUCKET * BUCKET_CAP * sizeof(unsigned); // 25.6 MB

    // ---- build bucketed CSR (by dst): deterministic two-pass multisplit
    split_hist_kernel<<<NBLK, 256, 0, stream>>>(dst, blockHist);
    split_scan_kernel<<<NBUCKET, NBLK, 0, stream>>>(blockHist, cursor);
    split_scatter_kernel<<<NBLK, 256, 0, stream>>>(src, dst, blockHist, pairs);
    bucket_sort_kernel<<<NBUCKET, 256, 0, stream>>>(pairs, cursor, row_start, row_deg);

    for (int l = 0; l < 3; ++l) {
        const float* xin = (l == 0) ? feats : xbuf;
        {
            int blocks = (N_NODES + 63) / 64;     // 64 nodes per block
            if (l == 0)
                proj_kernel<IN_DIM><<<blocks, 256, 0, stream>>>(xin, W[l], R[l], rb[l], xw, res, N_NODES);
            else
                proj_kernel<HID><<<blocks, 256, 0, stream>>>(xin, W[l], R[l], rb[l], xw, res, N_NODES);
        }
        {
            int blocks = (N_NODES * 64 + 255) / 256;  // one wave per node
            gather_kernel<<<blocks, 256, 0, stream>>>(xw, row_start, row_deg, pairs, b[l], res, xbuf, N_NODES);
        }
    }

    // pooling
    {
        int threads = N_GRAPHS * 64;
        pool_gather_kernel<<<(threads + 255) / 256, 256, 0, stream>>>(xbuf, gid, gbuf, N_GRAPHS);
    }
    // MLP
    {
        int threads = N_GRAPHS * 64;
        mlp_kernel<<<(threads + 255) / 256, 256, 0, stream>>>(gbuf, Wm1, bm1, Wm2, bm2, out, N_GRAPHS);
    }
}

// Round 8
// 555.213 us; speedup vs baseline: 9.5765x; 1.2407x over previous
//
#include <hip/hip_runtime.h>

#define N_NODES 100000
#define N_EDGES 3200000
#define N_GRAPHS 4096
#define IN_DIM 74
#define HID 64
#define MLP_HID 128

#define BKT_NODES 128                 // nodes per bucket
#define NBUCKET ((N_NODES + BKT_NODES - 1) / BKT_NODES)   // 782
#define BUCKET_CAP 8192               // edges capacity per bucket (mean ~4096)
#define NBLK 256                      // split blocks
#define CHUNK ((N_EDGES + NBLK - 1) / NBLK)               // 12500

__device__ __forceinline__ unsigned short f32_to_bf16_rne(float f) {
    unsigned u = __float_as_uint(f);
    unsigned r = (u + 0x7FFFu + ((u >> 16) & 1u)) >> 16;
    return (unsigned short)r;
}

// ---- projection: xw(bf16) = x@W ; res(f32) = relu(x@R + rb).
// Block stages 64 node-rows of x into LDS; each wave register-blocks 16 nodes,
// lane = feature.
template<int IN>
__launch_bounds__(256)
__global__ void proj_kernel(const float* __restrict__ x,
                            const float* __restrict__ W,
                            const float* __restrict__ R,
                            const float* __restrict__ rb,
                            unsigned short* __restrict__ xwb,
                            float* __restrict__ res,
                            int n_nodes) {
    __shared__ float xs[64 * IN];
    int n0 = blockIdx.x * 64;
    int tid = threadIdx.x;
    const float* gsrc = x + (long)n0 * IN;
    const int total = 64 * IN;
    int limit = (n_nodes - n0) * IN;
    if (limit >= total) {
        const float4* g4 = reinterpret_cast<const float4*>(gsrc);
        float4* s4 = reinterpret_cast<float4*>(xs);
        #pragma unroll 4
        for (int i = tid; i < total / 4; i += 256) s4[i] = g4[i];
    } else {
        for (int i = tid; i < total; i += 256) xs[i] = (i < limit) ? gsrc[i] : 0.f;
    }
    __syncthreads();

    int w = tid >> 6, f = tid & 63;
    int nb = w * 16;
    float accW[16], accR[16];
    #pragma unroll
    for (int j = 0; j < 16; ++j) { accW[j] = 0.f; accR[j] = 0.f; }

    #pragma unroll 2
    for (int k = 0; k < IN; ++k) {
        float wv = W[k * HID + f];
        float rv = R[k * HID + f];
        #pragma unroll
        for (int j = 0; j < 16; ++j) {
            float xv = xs[(nb + j) * IN + k];   // wave-uniform -> LDS broadcast
            accW[j] = fmaf(xv, wv, accW[j]);
            accR[j] = fmaf(xv, rv, accR[j]);
        }
    }
    float rbv = rb[f];
    #pragma unroll
    for (int j = 0; j < 16; ++j) {
        int n = n0 + nb + j;
        if (n < n_nodes) {
            long o = (long)n * HID + f;
            xwb[o] = f32_to_bf16_rne(accW[j]);
            res[o] = fmaxf(accR[j] + rbv, 0.f);
        }
    }
}

// ---- split pass 1: per-block LDS histogram of dst buckets
__launch_bounds__(256)
__global__ void split_hist_kernel(const int* __restrict__ dst,
                                  int* __restrict__ blockHist /*[NBUCKET][NBLK]*/) {
    __shared__ int h[NBUCKET];
    int blk = blockIdx.x, tid = threadIdx.x;
    for (int i = tid; i < NBUCKET; i += 256) h[i] = 0;
    __syncthreads();
    int lo = blk * CHUNK;
    int hi = lo + CHUNK; if (hi > N_EDGES) hi = N_EDGES;
    for (int e = lo + tid; e < hi; e += 256)
        atomicAdd(&h[dst[e] >> 7], 1);
    __syncthreads();
    for (int i = tid; i < NBUCKET; i += 256)
        blockHist[i * NBLK + blk] = h[i];
}

// ---- split pass 2: per-bucket exclusive scan over the 256 block counts.
__launch_bounds__(256)
__global__ void split_scan_kernel(int* __restrict__ blockHist,
                                  int* __restrict__ cursor) {
    __shared__ int s[NBLK];
    int bkt = blockIdx.x, tid = threadIdx.x;
    int v = blockHist[bkt * NBLK + tid];
    s[tid] = v;
    __syncthreads();
    for (int off = 1; off < NBLK; off <<= 1) {
        int t = (tid >= off) ? s[tid - off] : 0;
        __syncthreads();
        s[tid] += t;
        __syncthreads();
    }
    blockHist[bkt * NBLK + tid] = bkt * BUCKET_CAP + s[tid] - v;   // exclusive
    if (tid == NBLK - 1) cursor[bkt] = bkt * BUCKET_CAP + s[tid]; // total end
}

// ---- split pass 3: scatter to exact positions (LDS cursors, no global atomics)
__launch_bounds__(256)
__global__ void split_scatter_kernel(const int* __restrict__ src,
                                     const int* __restrict__ dst,
                                     const int* __restrict__ blockHist,
                                     unsigned* __restrict__ pairs) {
    __shared__ int cur[NBUCKET];
    int blk = blockIdx.x, tid = threadIdx.x;
    for (int i = tid; i < NBUCKET; i += 256)
        cur[i] = blockHist[i * NBLK + blk];
    __syncthreads();
    int lo = blk * CHUNK;
    int hi = lo + CHUNK; if (hi > N_EDGES) hi = N_EDGES;
    for (int e = lo + tid; e < hi; e += 256) {
        int d = dst[e];
        int b = d >> 7;
        int pos = atomicAdd(&cur[b], 1);
        pairs[pos] = (unsigned)src[e] | ((unsigned)(d & (BKT_NODES - 1)) << 17);
    }
}

// ---- per-bucket LDS counting sort -> src sorted by dst_local; row_start/row_deg
__launch_bounds__(256)
__global__ void bucket_sort_kernel(unsigned* __restrict__ pairs,
                                   const int* __restrict__ cursor,
                                   int* __restrict__ row_start,
                                   int* __restrict__ row_deg) {
    __shared__ unsigned stage[BUCKET_CAP];   // 32 KB
    __shared__ int hist[BKT_NODES];
    __shared__ int offs[BKT_NODES];
    __shared__ int cur[BKT_NODES];
    int bkt = blockIdx.x;
    int tid = threadIdx.x;
    int base = bkt * BUCKET_CAP;
    int cnt = cursor[bkt] - base;

    for (int i = tid; i < BKT_NODES; i += 256) hist[i] = 0;
    __syncthreads();
    for (int e = tid; e < cnt; e += 256) {
        unsigned p = pairs[base + e];
        stage[e] = p;
        atomicAdd(&hist[p >> 17], 1);
    }
    __syncthreads();
    if (tid < BKT_NODES) offs[tid] = hist[tid];
    __syncthreads();
    for (int s = 1; s < BKT_NODES; s <<= 1) {
        int v = (tid < BKT_NODES && tid >= s) ? offs[tid - s] : 0;
        __syncthreads();
        if (tid < BKT_NODES) offs[tid] += v;
        __syncthreads();
    }
    if (tid < BKT_NODES) {
        int ex = offs[tid] - hist[tid];
        cur[tid] = ex;
        int node = bkt * BKT_NODES + tid;
        if (node < N_NODES) {
            row_start[node] = base + ex;
            row_deg[node] = hist[tid];
        }
    }
    __syncthreads();
    for (int e = tid; e < cnt; e += 256) {
        unsigned p = stage[e];
        int pos = atomicAdd(&cur[p >> 17], 1);
        pairs[base + pos] = p & 0x1FFFF;   // store src only
    }
}

// ---- gather aggregation + epilogue over bf16 xw.
// One wave per node; 2 edges per step (half-wave each); lane reads one
// bf16x2 dword = 2 features; f32 accumulate; shfl_xor(32) merges halves.
__global__ void gather_kernel(const unsigned* __restrict__ xwq,   // 32 dwords/node
                              const int* __restrict__ row_start,
                              const int* __restrict__ row_deg,
                              const unsigned* __restrict__ csr_src,
                              const float* __restrict__ b,
                              const float* __restrict__ res,
                              float* __restrict__ xout,
                              int n_nodes) {
    int wid = (blockIdx.x * blockDim.x + threadIdx.x) >> 6;
    int lane = threadIdx.x & 63;
    if (wid >= n_nodes) return;
    int c = lane & 31;
    int half = lane >> 5;
    int start = row_start[wid];
    int end = start + row_deg[wid];
    float acc0 = 0.f, acc1 = 0.f;
    int e = start;
    for (; e + 8 <= end; e += 8) {
        unsigned s0 = csr_src[e + half];
        unsigned s1 = csr_src[e + 2 + half];
        unsigned s2 = csr_src[e + 4 + half];
        unsigned s3 = csr_src[e + 6 + half];
        unsigned v0 = xwq[s0 * 32 + c];
        unsigned v1 = xwq[s1 * 32 + c];
        unsigned v2 = xwq[s2 * 32 + c];
        unsigned v3 = xwq[s3 * 32 + c];
        acc0 += (__uint_as_float(v0 << 16) + __uint_as_float(v1 << 16))
              + (__uint_as_float(v2 << 16) + __uint_as_float(v3 << 16));
        acc1 += (__uint_as_float(v0 & 0xFFFF0000u) + __uint_as_float(v1 & 0xFFFF0000u))
              + (__uint_as_float(v2 & 0xFFFF0000u) + __uint_as_float(v3 & 0xFFFF0000u));
    }
    for (; e + 2 <= end; e += 2) {
        unsigned s = csr_src[e + half];
        unsigned v = xwq[s * 32 + c];
        acc0 += __uint_as_float(v << 16);
        acc1 += __uint_as_float(v & 0xFFFF0000u);
    }
    if (e < end && half == 0) {
        unsigned s = csr_src[e];
        unsigned v = xwq[s * 32 + c];
        acc0 += __uint_as_float(v << 16);
        acc1 += __uint_as_float(v & 0xFFFF0000u);
    }
    acc0 += __shfl_xor(acc0, 32, 64);
    acc1 += __shfl_xor(acc1, 32, 64);
    if (half == 0) {
        int f = c * 2;
        long o = (long)wid * HID + f;
        float2 r = *reinterpret_cast<const float2*>(&res[o]);
        float2 wv;
        wv.x = fmaxf(acc0 + b[f],     0.f) + r.x;
        wv.y = fmaxf(acc1 + b[f + 1], 0.f) + r.y;
        *reinterpret_cast<float2*>(&xout[o]) = wv;
    }
}

// ---- pooling gather: graph_ids sorted -> binary search range, one wave/graph
__global__ void pool_gather_kernel(const float* __restrict__ x,
                                   const int* __restrict__ gid,
                                   float* __restrict__ g,
                                   int n_graphs) {
    int wid = (blockIdx.x * blockDim.x + threadIdx.x) >> 6;
    int lane = threadIdx.x & 63;
    if (wid >= n_graphs) return;
    int lo = 0, hi = N_NODES;
    while (lo < hi) { int mid = (lo + hi) >> 1; if (gid[mid] < wid) lo = mid + 1; else hi = mid; }
    int start = lo;
    hi = N_NODES;
    while (lo < hi) { int mid = (lo + hi) >> 1; if (gid[mid] < wid + 1) lo = mid + 1; else hi = mid; }
    int end = lo;
    float acc = 0.f;
    for (int n = start; n < end; ++n)
        acc += x[(long)n * HID + lane];
    g[(long)wid * HID + lane] = acc;
}

// ---- MLP: one wave per graph. out = relu(g@Wm1+bm1) @ Wm2 + bm2
__global__ void mlp_kernel(const float* __restrict__ g,
                           const float* __restrict__ Wm1,
                           const float* __restrict__ bm1,
                           const float* __restrict__ Wm2,
                           const float* __restrict__ bm2,
                           float* __restrict__ out,
                           int n_graphs) {
    int wid = (blockIdx.x * blockDim.x + threadIdx.x) >> 6;
    int lane = threadIdx.x & 63;
    if (wid >= n_graphs) return;
    const float* gr = g + (long)wid * HID;
    float h0 = bm1[lane];
    float h1 = bm1[lane + 64];
    for (int k = 0; k < HID; ++k) {
        float gv = gr[k];
        h0 += gv * Wm1[k * MLP_HID + lane];
        h1 += gv * Wm1[k * MLP_HID + lane + 64];
    }
    float part = fmaxf(h0, 0.f) * Wm2[lane] + fmaxf(h1, 0.f) * Wm2[lane + 64];
    #pragma unroll
    for (int off = 32; off > 0; off >>= 1)
        part += __shfl_down(part, off, 64);
    if (lane == 0) out[wid] = part + bm2[0];
}

extern "C" void kernel_launch(void* const* d_in, const int* in_sizes, int n_in,
                              void* d_out, int out_size, void* d_ws, size_t ws_size,
                              hipStream_t stream) {
    const float* feats = (const float*)d_in[0];
    const int*   src   = (const int*)d_in[1];
    const int*   dst   = (const int*)d_in[2];
    const int*   gid   = (const int*)d_in[3];
    const float* W[3]  = {(const float*)d_in[4],  (const float*)d_in[8],  (const float*)d_in[12]};
    const float* b[3]  = {(const float*)d_in[5],  (const float*)d_in[9],  (const float*)d_in[13]};
    const float* R[3]  = {(const float*)d_in[6],  (const float*)d_in[10], (const float*)d_in[14]};
    const float* rb[3] = {(const float*)d_in[7],  (const float*)d_in[11], (const float*)d_in[15]};
    const float* Wm1 = (const float*)d_in[16];
    const float* bm1 = (const float*)d_in[17];
    const float* Wm2 = (const float*)d_in[18];
    const float* bm2 = (const float*)d_in[19];
    float* out = (float*)d_out;

    // workspace carve
    char* ws = (char*)d_ws;
    const size_t node_buf = (size_t)N_NODES * HID * sizeof(float);   // 25.6 MB
    float*          xbuf      = (float*)(ws);          ws += node_buf;
    unsigned short* xwb       = (unsigned short*)(ws); ws += (size_t)N_NODES * HID * sizeof(unsigned short); // 12.8 MB
    float*          res       = (float*)(ws);          ws += node_buf;
    float*          gbuf      = (float*)(ws);          ws += (size_t)N_GRAPHS * HID * sizeof(float);
    int*            cursor    = (int*)(ws);            ws += (size_t)NBUCKET * sizeof(int);
    int*            row_start = (int*)(ws);            ws += (size_t)N_NODES * sizeof(int);
    int*            row_deg   = (int*)(ws);            ws += (size_t)N_NODES * sizeof(int);
    int*            blockHist = (int*)(ws);            ws += (size_t)NBUCKET * NBLK * sizeof(int);  // 800 KB
    unsigned*       pairs     = (unsigned*)(ws);       ws += (size_t)NBUCKET * BUCKET_CAP * sizeof(unsigned); // 25.6 MB

    // ---- build bucketed CSR (by dst): deterministic two-pass multisplit
    split_hist_kernel<<<NBLK, 256, 0, stream>>>(dst, blockHist);
    split_scan_kernel<<<NBUCKET, NBLK, 0, stream>>>(blockHist, cursor);
    split_scatter_kernel<<<NBLK, 256, 0, stream>>>(src, dst, blockHist, pairs);
    bucket_sort_kernel<<<NBUCKET, 256, 0, stream>>>(pairs, cursor, row_start, row_deg);

    for (int l = 0; l < 3; ++l) {
        const float* xin = (l == 0) ? feats : xbuf;
        {
            int blocks = (N_NODES + 63) / 64;     // 64 nodes per block
            if (l == 0)
                proj_kernel<IN_DIM><<<blocks, 256, 0, stream>>>(xin, W[l], R[l], rb[l], xwb, res, N_NODES);
            else
                proj_kernel<HID><<<blocks, 256, 0, stream>>>(xin, W[l], R[l], rb[l], xwb, res, N_NODES);
        }
        {
            int blocks = (N_NODES * 64 + 255) / 256;  // one wave per node
            gather_kernel<<<blocks, 256, 0, stream>>>((const unsigned*)xwb, row_start, row_deg,
                                                      pairs, b[l], res, xbuf, N_NODES);
        }
    }

    // pooling
    {
        int threads = N_GRAPHS * 64;
        pool_gather_kernel<<<(threads + 255) / 256, 256, 0, stream>>>(xbuf, gid, gbuf, N_GRAPHS);
    }
    // MLP
    {
        int threads = N_GRAPHS * 64;
        mlp_kernel<<<(threads + 255) / 256, 256, 0, stream>>>(gbuf, Wm1, bm1, Wm2, bm2, out, N_GRAPHS);
    }
}

// Round 9
// 453.006 us; speedup vs baseline: 11.7372x; 1.2256x over previous
//
#include <hip/hip_runtime.h>

#define N_NODES 100000
#define N_EDGES 3200000
#define N_GRAPHS 4096
#define IN_DIM 74
#define HID 64
#define MLP_HID 128

#define BKT_NODES 128                 // nodes per bucket
#define NBUCKET ((N_NODES + BKT_NODES - 1) / BKT_NODES)   // 782
#define BUCKET_CAP 8192               // edges capacity per bucket (mean ~4096)
#define NBLK 256                      // split blocks
#define CHUNK ((N_EDGES + NBLK - 1) / NBLK)               // 12500

__device__ __forceinline__ unsigned short f32_to_bf16_rne(float f) {
    unsigned u = __float_as_uint(f);
    unsigned r = (u + 0x7FFFu + ((u >> 16) & 1u)) >> 16;
    return (unsigned short)r;
}

// ---- projection: xw(bf16) = x@W ; res(f32) = relu(x@R + rb).
// Block stages 64 node-rows of x into LDS (row stride padded to 16B multiple);
// each wave register-blocks 16 nodes, lane = feature. Inner loop k-blocked by
// 4: per group 16x ds_read_b128 (broadcast) + 8 L1 dwords + 128 FMAs.
template<int IN, int STRIDE>
__launch_bounds__(256)
__global__ void proj_kernel(const float* __restrict__ x,
                            const float* __restrict__ W,
                            const float* __restrict__ R,
                            const float* __restrict__ rb,
                            unsigned short* __restrict__ xwb,
                            float* __restrict__ res,
                            int n_nodes) {
    __shared__ float xs[64 * STRIDE];
    int n0 = blockIdx.x * 64;
    int tid = threadIdx.x;
    if (IN == STRIDE) {
        const float* gsrc = x + (long)n0 * IN;
        const int total = 64 * IN;
        int limit = (n_nodes - n0) * IN;
        if (limit >= total) {
            const float4* g4 = reinterpret_cast<const float4*>(gsrc);
            float4* s4 = reinterpret_cast<float4*>(xs);
            #pragma unroll 4
            for (int i = tid; i < total / 4; i += 256) s4[i] = g4[i];
        } else {
            for (int i = tid; i < total; i += 256) xs[i] = (i < limit) ? gsrc[i] : 0.f;
        }
    } else {
        // padded staging: col >= IN and OOB rows -> 0
        for (int i = tid; i < 64 * STRIDE; i += 256) {
            int row = i / STRIDE, col = i - row * STRIDE;
            int n = n0 + row;
            xs[i] = (col < IN && n < n_nodes) ? x[(long)n * IN + col] : 0.f;
        }
    }
    __syncthreads();

    int w = tid >> 6, f = tid & 63;
    int nb = w * 16;
    float accW[16], accR[16];
    #pragma unroll
    for (int j = 0; j < 16; ++j) { accW[j] = 0.f; accR[j] = 0.f; }

    constexpr int K4 = IN & ~3;       // 72 or 64
    #pragma unroll 2
    for (int g = 0; g < K4 / 4; ++g) {
        int k = g * 4;
        float wv0 = W[(k + 0) * HID + f], wv1 = W[(k + 1) * HID + f];
        float wv2 = W[(k + 2) * HID + f], wv3 = W[(k + 3) * HID + f];
        float rv0 = R[(k + 0) * HID + f], rv1 = R[(k + 1) * HID + f];
        float rv2 = R[(k + 2) * HID + f], rv3 = R[(k + 3) * HID + f];
        #pragma unroll
        for (int j = 0; j < 16; ++j) {
            const float4 xv = *reinterpret_cast<const float4*>(&xs[(nb + j) * STRIDE + k]);
            accW[j] = fmaf(xv.x, wv0, accW[j]);
            accW[j] = fmaf(xv.y, wv1, accW[j]);
            accW[j] = fmaf(xv.z, wv2, accW[j]);
            accW[j] = fmaf(xv.w, wv3, accW[j]);
            accR[j] = fmaf(xv.x, rv0, accR[j]);
            accR[j] = fmaf(xv.y, rv1, accR[j]);
            accR[j] = fmaf(xv.z, rv2, accR[j]);
            accR[j] = fmaf(xv.w, rv3, accR[j]);
        }
    }
    #pragma unroll
    for (int k = K4; k < IN; ++k) {    // tail (2 iters for IN=74, 0 for 64)
        float wv = W[k * HID + f];
        float rv = R[k * HID + f];
        #pragma unroll
        for (int j = 0; j < 16; ++j) {
            float xv = xs[(nb + j) * STRIDE + k];
            accW[j] = fmaf(xv, wv, accW[j]);
            accR[j] = fmaf(xv, rv, accR[j]);
        }
    }

    float rbv = rb[f];
    #pragma unroll
    for (int j = 0; j < 16; ++j) {
        int n = n0 + nb + j;
        if (n < n_nodes) {
            long o = (long)n * HID + f;
            xwb[o] = f32_to_bf16_rne(accW[j]);
            res[o] = fmaxf(accR[j] + rbv, 0.f);
        }
    }
}

// ---- split pass 1: per-block LDS histogram of dst buckets
__launch_bounds__(256)
__global__ void split_hist_kernel(const int* __restrict__ dst,
                                  int* __restrict__ blockHist /*[NBUCKET][NBLK]*/) {
    __shared__ int h[NBUCKET];
    int blk = blockIdx.x, tid = threadIdx.x;
    for (int i = tid; i < NBUCKET; i += 256) h[i] = 0;
    __syncthreads();
    int lo = blk * CHUNK;
    int hi = lo + CHUNK; if (hi > N_EDGES) hi = N_EDGES;
    for (int e = lo + tid; e < hi; e += 256)
        atomicAdd(&h[dst[e] >> 7], 1);
    __syncthreads();
    for (int i = tid; i < NBUCKET; i += 256)
        blockHist[i * NBLK + blk] = h[i];
}

// ---- split pass 2: per-bucket exclusive scan over the 256 block counts.
__launch_bounds__(256)
__global__ void split_scan_kernel(int* __restrict__ blockHist,
                                  int* __restrict__ cursor) {
    __shared__ int s[NBLK];
    int bkt = blockIdx.x, tid = threadIdx.x;
    int v = blockHist[bkt * NBLK + tid];
    s[tid] = v;
    __syncthreads();
    for (int off = 1; off < NBLK; off <<= 1) {
        int t = (tid >= off) ? s[tid - off] : 0;
        __syncthreads();
        s[tid] += t;
        __syncthreads();
    }
    blockHist[bkt * NBLK + tid] = bkt * BUCKET_CAP + s[tid] - v;   // exclusive
    if (tid == NBLK - 1) cursor[bkt] = bkt * BUCKET_CAP + s[tid]; // total end
}

// ---- split pass 3: scatter to exact positions (LDS cursors, no global atomics)
__launch_bounds__(256)
__global__ void split_scatter_kernel(const int* __restrict__ src,
                                     const int* __restrict__ dst,
                                     const int* __restrict__ blockHist,
                                     unsigned* __restrict__ pairs) {
    __shared__ int cur[NBUCKET];
    int blk = blockIdx.x, tid = threadIdx.x;
    for (int i = tid; i < NBUCKET; i += 256)
        cur[i] = blockHist[i * NBLK + blk];
    __syncthreads();
    int lo = blk * CHUNK;
    int hi = lo + CHUNK; if (hi > N_EDGES) hi = N_EDGES;
    for (int e = lo + tid; e < hi; e += 256) {
        int d = dst[e];
        int b = d >> 7;
        int pos = atomicAdd(&cur[b], 1);
        pairs[pos] = (unsigned)src[e] | ((unsigned)(d & (BKT_NODES - 1)) << 17);
    }
}

// ---- per-bucket LDS counting sort -> src sorted by dst_local; row_start/row_deg
__launch_bounds__(256)
__global__ void bucket_sort_kernel(unsigned* __restrict__ pairs,
                                   const int* __restrict__ cursor,
                                   int* __restrict__ row_start,
                                   int* __restrict__ row_deg) {
    __shared__ unsigned stage[BUCKET_CAP];   // 32 KB
    __shared__ int hist[BKT_NODES];
    __shared__ int offs[BKT_NODES];
    __shared__ int cur[BKT_NODES];
    int bkt = blockIdx.x;
    int tid = threadIdx.x;
    int base = bkt * BUCKET_CAP;
    int cnt = cursor[bkt] - base;

    for (int i = tid; i < BKT_NODES; i += 256) hist[i] = 0;
    __syncthreads();
    for (int e = tid; e < cnt; e += 256) {
        unsigned p = pairs[base + e];
        stage[e] = p;
        atomicAdd(&hist[p >> 17], 1);
    }
    __syncthreads();
    if (tid < BKT_NODES) offs[tid] = hist[tid];
    __syncthreads();
    for (int s = 1; s < BKT_NODES; s <<= 1) {
        int v = (tid < BKT_NODES && tid >= s) ? offs[tid - s] : 0;
        __syncthreads();
        if (tid < BKT_NODES) offs[tid] += v;
        __syncthreads();
    }
    if (tid < BKT_NODES) {
        int ex = offs[tid] - hist[tid];
        cur[tid] = ex;
        int node = bkt * BKT_NODES + tid;
        if (node < N_NODES) {
            row_start[node] = base + ex;
            row_deg[node] = hist[tid];
        }
    }
    __syncthreads();
    for (int e = tid; e < cnt; e += 256) {
        unsigned p = stage[e];
        int pos = atomicAdd(&cur[p >> 17], 1);
        pairs[base + pos] = p & 0x1FFFF;   // store src only
    }
}

// ---- gather aggregation + epilogue over bf16 xw.
__global__ void gather_kernel(const unsigned* __restrict__ xwq,   // 32 dwords/node
                              const int* __restrict__ row_start,
                              const int* __restrict__ row_deg,
                              const unsigned* __restrict__ csr_src,
                              const float* __restrict__ b,
                              const float* __restrict__ res,
                              float* __restrict__ xout,
                              int n_nodes) {
    int wid = (blockIdx.x * blockDim.x + threadIdx.x) >> 6;
    int lane = threadIdx.x & 63;
    if (wid >= n_nodes) return;
    int c = lane & 31;
    int half = lane >> 5;
    int start = row_start[wid];
    int end = start + row_deg[wid];
    float acc0 = 0.f, acc1 = 0.f;
    int e = start;
    for (; e + 8 <= end; e += 8) {
        unsigned s0 = csr_src[e + half];
        unsigned s1 = csr_src[e + 2 + half];
        unsigned s2 = csr_src[e + 4 + half];
        unsigned s3 = csr_src[e + 6 + half];
        unsigned v0 = xwq[s0 * 32 + c];
        unsigned v1 = xwq[s1 * 32 + c];
        unsigned v2 = xwq[s2 * 32 + c];
        unsigned v3 = xwq[s3 * 32 + c];
        acc0 += (__uint_as_float(v0 << 16) + __uint_as_float(v1 << 16))
              + (__uint_as_float(v2 << 16) + __uint_as_float(v3 << 16));
        acc1 += (__uint_as_float(v0 & 0xFFFF0000u) + __uint_as_float(v1 & 0xFFFF0000u))
              + (__uint_as_float(v2 & 0xFFFF0000u) + __uint_as_float(v3 & 0xFFFF0000u));
    }
    for (; e + 2 <= end; e += 2) {
        unsigned s = csr_src[e + half];
        unsigned v = xwq[s * 32 + c];
        acc0 += __uint_as_float(v << 16);
        acc1 += __uint_as_float(v & 0xFFFF0000u);
    }
    if (e < end && half == 0) {
        unsigned s = csr_src[e];
        unsigned v = xwq[s * 32 + c];
        acc0 += __uint_as_float(v << 16);
        acc1 += __uint_as_float(v & 0xFFFF0000u);
    }
    acc0 += __shfl_xor(acc0, 32, 64);
    acc1 += __shfl_xor(acc1, 32, 64);
    if (half == 0) {
        int f = c * 2;
        long o = (long)wid * HID + f;
        float2 r = *reinterpret_cast<const float2*>(&res[o]);
        float2 wv;
        wv.x = fmaxf(acc0 + b[f],     0.f) + r.x;
        wv.y = fmaxf(acc1 + b[f + 1], 0.f) + r.y;
        *reinterpret_cast<float2*>(&xout[o]) = wv;
    }
}

// ---- pooling gather: graph_ids sorted -> binary search range, one wave/graph
__global__ void pool_gather_kernel(const float* __restrict__ x,
                                   const int* __restrict__ gid,
                                   float* __restrict__ g,
                                   int n_graphs) {
    int wid = (blockIdx.x * blockDim.x + threadIdx.x) >> 6;
    int lane = threadIdx.x & 63;
    if (wid >= n_graphs) return;
    int lo = 0, hi = N_NODES;
    while (lo < hi) { int mid = (lo + hi) >> 1; if (gid[mid] < wid) lo = mid + 1; else hi = mid; }
    int start = lo;
    hi = N_NODES;
    while (lo < hi) { int mid = (lo + hi) >> 1; if (gid[mid] < wid + 1) lo = mid + 1; else hi = mid; }
    int end = lo;
    float acc = 0.f;
    for (int n = start; n < end; ++n)
        acc += x[(long)n * HID + lane];
    g[(long)wid * HID + lane] = acc;
}

// ---- MLP: one wave per graph. out = relu(g@Wm1+bm1) @ Wm2 + bm2
__global__ void mlp_kernel(const float* __restrict__ g,
                           const float* __restrict__ Wm1,
                           const float* __restrict__ bm1,
                           const float* __restrict__ Wm2,
                           const float* __restrict__ bm2,
                           float* __restrict__ out,
                           int n_graphs) {
    int wid = (blockIdx.x * blockDim.x + threadIdx.x) >> 6;
    int lane = threadIdx.x & 63;
    if (wid >= n_graphs) return;
    const float* gr = g + (long)wid * HID;
    float h0 = bm1[lane];
    float h1 = bm1[lane + 64];
    for (int k = 0; k < HID; ++k) {
        float gv = gr[k];
        h0 += gv * Wm1[k * MLP_HID + lane];
        h1 += gv * Wm1[k * MLP_HID + lane + 64];
    }
    float part = fmaxf(h0, 0.f) * Wm2[lane] + fmaxf(h1, 0.f) * Wm2[lane + 64];
    #pragma unroll
    for (int off = 32; off > 0; off >>= 1)
        part += __shfl_down(part, off, 64);
    if (lane == 0) out[wid] = part + bm2[0];
}

extern "C" void kernel_launch(void* const* d_in, const int* in_sizes, int n_in,
                              void* d_out, int out_size, void* d_ws, size_t ws_size,
                              hipStream_t stream) {
    const float* feats = (const float*)d_in[0];
    const int*   src   = (const int*)d_in[1];
    const int*   dst   = (const int*)d_in[2];
    const int*   gid   = (const int*)d_in[3];
    const float* W[3]  = {(const float*)d_in[4],  (const float*)d_in[8],  (const float*)d_in[12]};
    const float* b[3]  = {(const float*)d_in[5],  (const float*)d_in[9],  (const float*)d_in[13]};
    const float* R[3]  = {(const float*)d_in[6],  (const float*)d_in[10], (const float*)d_in[14]};
    const float* rb[3] = {(const float*)d_in[7],  (const float*)d_in[11], (const float*)d_in[15]};
    const float* Wm1 = (const float*)d_in[16];
    const float* bm1 = (const float*)d_in[17];
    const float* Wm2 = (const float*)d_in[18];
    const float* bm2 = (const float*)d_in[19];
    float* out = (float*)d_out;

    // workspace carve
    char* ws = (char*)d_ws;
    const size_t node_buf = (size_t)N_NODES * HID * sizeof(float);   // 25.6 MB
    float*          xbuf      = (float*)(ws);          ws += node_buf;
    unsigned short* xwb       = (unsigned short*)(ws); ws += (size_t)N_NODES * HID * sizeof(unsigned short); // 12.8 MB
    float*          res       = (float*)(ws);          ws += node_buf;
    float*          gbuf      = (float*)(ws);          ws += (size_t)N_GRAPHS * HID * sizeof(float);
    int*            cursor    = (int*)(ws);            ws += (size_t)NBUCKET * sizeof(int);
    int*            row_start = (int*)(ws);            ws += (size_t)N_NODES * sizeof(int);
    int*            row_deg   = (int*)(ws);            ws += (size_t)N_NODES * sizeof(int);
    int*            blockHist = (int*)(ws);            ws += (size_t)NBUCKET * NBLK * sizeof(int);  // 800 KB
    unsigned*       pairs     = (unsigned*)(ws);       ws += (size_t)NBUCKET * BUCKET_CAP * sizeof(unsigned); // 25.6 MB

    // ---- build bucketed CSR (by dst): deterministic two-pass multisplit
    split_hist_kernel<<<NBLK, 256, 0, stream>>>(dst, blockHist);
    split_scan_kernel<<<NBUCKET, NBLK, 0, stream>>>(blockHist, cursor);
    split_scatter_kernel<<<NBLK, 256, 0, stream>>>(src, dst, blockHist, pairs);
    bucket_sort_kernel<<<NBUCKET, 256, 0, stream>>>(pairs, cursor, row_start, row_deg);

    for (int l = 0; l < 3; ++l) {
        const float* xin = (l == 0) ? feats : xbuf;
        {
            int blocks = (N_NODES + 63) / 64;     // 64 nodes per block
            if (l == 0)
                proj_kernel<IN_DIM, 76><<<blocks, 256, 0, stream>>>(xin, W[l], R[l], rb[l], xwb, res, N_NODES);
            else
                proj_kernel<HID, HID><<<blocks, 256, 0, stream>>>(xin, W[l], R[l], rb[l], xwb, res, N_NODES);
        }
        {
            int blocks = (N_NODES * 64 + 255) / 256;  // one wave per node
            gather_kernel<<<blocks, 256, 0, stream>>>((const unsigned*)xwb, row_start, row_deg,
                                                      pairs, b[l], res, xbuf, N_NODES);
        }
    }

    // pooling
    {
        int threads = N_GRAPHS * 64;
        pool_gather_kernel<<<(threads + 255) / 256, 256, 0, stream>>>(xbuf, gid, gbuf, N_GRAPHS);
    }
    // MLP
    {
        int threads = N_GRAPHS * 64;
        mlp_kernel<<<(threads + 255) / 256, 256, 0, stream>>>(gbuf, Wm1, bm1, Wm2, bm2, out, N_GRAPHS);
    }
}

// Round 10
// 388.633 us; speedup vs baseline: 13.6813x; 1.1656x over previous
//
#include <hip/hip_runtime.h>

#define N_NODES 100000
#define N_EDGES 3200000
#define N_GRAPHS 4096
#define IN_DIM 74
#define HID 64
#define MLP_HID 128

#define BKT_NODES 128                 // nodes per bucket
#define NBUCKET ((N_NODES + BKT_NODES - 1) / BKT_NODES)   // 782
#define BUCKET_CAP 8192               // edges capacity per bucket (mean ~4096)
#define NBLK 256                      // split blocks
#define CHUNK ((N_EDGES + NBLK - 1) / NBLK)               // 12500

// prep'd weight layout sizes (bf16, transposed [feat][k], padded stride)
#define STRIDE0 104                   // layer0: KPAD=96, stride 104 (16B mult, conflict-free)
#define STRIDE12 72                   // layers 1,2: KPAD=64, stride 72
#define SZ0 (64 * STRIDE0)            // shorts per matrix, layer0
#define SZ12 (64 * STRIDE12)

typedef __attribute__((ext_vector_type(8))) short bf16x8;
typedef __attribute__((ext_vector_type(4))) float f32x4;

__device__ __forceinline__ unsigned short f32_to_bf16_rne(float f) {
    unsigned u = __float_as_uint(f);
    unsigned r = (u + 0x7FFFu + ((u >> 16) & 1u)) >> 16;
    return (unsigned short)r;
}

// ---- one-time weight prep: Wt[l][feat][k] = bf16(W_l[k][feat]), zero-padded.
// 6 blocks: blockIdx.x = l*2 + isR.
__global__ void prep_wt_kernel(const float* __restrict__ W0, const float* __restrict__ R0,
                               const float* __restrict__ W1, const float* __restrict__ R1,
                               const float* __restrict__ W2, const float* __restrict__ R2,
                               unsigned short* __restrict__ wtbuf) {
    const float* srcs[6] = {W0, R0, W1, R1, W2, R2};
    int id = blockIdx.x;
    int l = id >> 1, isR = id & 1;
    const float* src = srcs[id];
    int IN = (l == 0) ? IN_DIM : HID;
    int STRIDE = (l == 0) ? STRIDE0 : STRIDE12;
    int base = (l == 0 ? 0 : 2 * SZ0 + (l - 1) * 2 * SZ12) + isR * (l == 0 ? SZ0 : SZ12);
    int total = 64 * STRIDE;
    for (int i = threadIdx.x; i < total; i += 256) {
        int n = i / STRIDE, k = i - n * STRIDE;
        wtbuf[base + i] = (k < IN) ? f32_to_bf16_rne(src[k * HID + n]) : 0;
    }
}

// ---- projection via MFMA: xw(bf16) = x@W ; res(f32) = relu(x@R + rb).
// Block = 4 waves = 64 nodes. LDS: x tile bf16 [64][STRIDE], Wt/Rt copies.
// Wave: 16 nodes x 64 feats, 8 mfma per 32-k step.
template<int IN, int KPAD, int STRIDE>
__launch_bounds__(256)
__global__ void proj_mfma_kernel(const float* __restrict__ x,
                                 const unsigned short* __restrict__ wt_layer, // W then R
                                 const float* __restrict__ rb,
                                 unsigned short* __restrict__ xwb,
                                 float* __restrict__ res,
                                 int n_nodes) {
    __shared__ __align__(16) unsigned short xs[64 * STRIDE];
    __shared__ __align__(16) unsigned short wt[64 * STRIDE];
    __shared__ __align__(16) unsigned short rt[64 * STRIDE];
    int n0 = blockIdx.x * 64;
    int tid = threadIdx.x;

    // copy prepped weights (bf16, already padded layout) via 16B chunks
    {
        const uint4* gw = reinterpret_cast<const uint4*>(wt_layer);
        const uint4* gr = reinterpret_cast<const uint4*>(wt_layer + 64 * STRIDE);
        uint4* sw = reinterpret_cast<uint4*>(wt);
        uint4* sr = reinterpret_cast<uint4*>(rt);
        const int cnt = 64 * STRIDE / 8;   // uint4 = 8 shorts
        for (int i = tid; i < cnt; i += 256) { sw[i] = gw[i]; sr[i] = gr[i]; }
    }
    // stage x tile as bf16, zero-padded cols/rows
    for (int i = tid; i < 64 * STRIDE; i += 256) {
        int row = i / STRIDE, col = i - row * STRIDE;
        int n = n0 + row;
        float v = (col < IN && n < n_nodes) ? x[(long)n * IN + col] : 0.f;
        xs[i] = f32_to_bf16_rne(v);
    }
    __syncthreads();

    int w = tid >> 6, lane = tid & 63;
    int nb = w * 16;
    int rc = lane & 15;        // A row / B col / D col
    int kg = lane >> 4;        // k-chunk of 8

    f32x4 accW[4], accR[4];
    #pragma unroll
    for (int fg = 0; fg < 4; ++fg) { accW[fg] = {0.f, 0.f, 0.f, 0.f}; accR[fg] = {0.f, 0.f, 0.f, 0.f}; }

    #pragma unroll
    for (int ks = 0; ks < KPAD / 32; ++ks) {
        int k0 = ks * 32 + kg * 8;
        bf16x8 a = *reinterpret_cast<const bf16x8*>(&xs[(nb + rc) * STRIDE + k0]);
        #pragma unroll
        for (int fg = 0; fg < 4; ++fg) {
            bf16x8 bw = *reinterpret_cast<const bf16x8*>(&wt[(fg * 16 + rc) * STRIDE + k0]);
            accW[fg] = __builtin_amdgcn_mfma_f32_16x16x32_bf16(a, bw, accW[fg], 0, 0, 0);
            bf16x8 br = *reinterpret_cast<const bf16x8*>(&rt[(fg * 16 + rc) * STRIDE + k0]);
            accR[fg] = __builtin_amdgcn_mfma_f32_16x16x32_bf16(a, br, accR[fg], 0, 0, 0);
        }
    }

    // D: col = lane&15, row = (lane>>4)*4 + reg
    #pragma unroll
    for (int fg = 0; fg < 4; ++fg) {
        int feat = fg * 16 + rc;
        float rbv = rb[feat];
        #pragma unroll
        for (int r = 0; r < 4; ++r) {
            int node = n0 + nb + kg * 4 + r;
            if (node < n_nodes) {
                long o = (long)node * HID + feat;
                xwb[o] = f32_to_bf16_rne(accW[fg][r]);
                res[o] = fmaxf(accR[fg][r] + rbv, 0.f);
            }
        }
    }
}

// ---- split pass 1: per-block LDS histogram of dst buckets
__launch_bounds__(256)
__global__ void split_hist_kernel(const int* __restrict__ dst,
                                  int* __restrict__ blockHist /*[NBUCKET][NBLK]*/) {
    __shared__ int h[NBUCKET];
    int blk = blockIdx.x, tid = threadIdx.x;
    for (int i = tid; i < NBUCKET; i += 256) h[i] = 0;
    __syncthreads();
    int lo = blk * CHUNK;
    int hi = lo + CHUNK; if (hi > N_EDGES) hi = N_EDGES;
    for (int e = lo + tid; e < hi; e += 256)
        atomicAdd(&h[dst[e] >> 7], 1);
    __syncthreads();
    for (int i = tid; i < NBUCKET; i += 256)
        blockHist[i * NBLK + blk] = h[i];
}

// ---- split pass 2: per-bucket exclusive scan over the 256 block counts.
__launch_bounds__(256)
__global__ void split_scan_kernel(int* __restrict__ blockHist,
                                  int* __restrict__ cursor) {
    __shared__ int s[NBLK];
    int bkt = blockIdx.x, tid = threadIdx.x;
    int v = blockHist[bkt * NBLK + tid];
    s[tid] = v;
    __syncthreads();
    for (int off = 1; off < NBLK; off <<= 1) {
        int t = (tid >= off) ? s[tid - off] : 0;
        __syncthreads();
        s[tid] += t;
        __syncthreads();
    }
    blockHist[bkt * NBLK + tid] = bkt * BUCKET_CAP + s[tid] - v;   // exclusive
    if (tid == NBLK - 1) cursor[bkt] = bkt * BUCKET_CAP + s[tid]; // total end
}

// ---- split pass 3: scatter to exact positions (LDS cursors, no global atomics)
__launch_bounds__(256)
__global__ void split_scatter_kernel(const int* __restrict__ src,
                                     const int* __restrict__ dst,
                                     const int* __restrict__ blockHist,
                                     unsigned* __restrict__ pairs) {
    __shared__ int cur[NBUCKET];
    int blk = blockIdx.x, tid = threadIdx.x;
    for (int i = tid; i < NBUCKET; i += 256)
        cur[i] = blockHist[i * NBLK + blk];
    __syncthreads();
    int lo = blk * CHUNK;
    int hi = lo + CHUNK; if (hi > N_EDGES) hi = N_EDGES;
    for (int e = lo + tid; e < hi; e += 256) {
        int d = dst[e];
        int b = d >> 7;
        int pos = atomicAdd(&cur[b], 1);
        pairs[pos] = (unsigned)src[e] | ((unsigned)(d & (BKT_NODES - 1)) << 17);
    }
}

// ---- per-bucket LDS counting sort -> src sorted by dst_local; row_start/row_deg
__launch_bounds__(256)
__global__ void bucket_sort_kernel(unsigned* __restrict__ pairs,
                                   const int* __restrict__ cursor,
                                   int* __restrict__ row_start,
                                   int* __restrict__ row_deg) {
    __shared__ unsigned stage[BUCKET_CAP];   // 32 KB
    __shared__ int hist[BKT_NODES];
    __shared__ int offs[BKT_NODES];
    __shared__ int cur[BKT_NODES];
    int bkt = blockIdx.x;
    int tid = threadIdx.x;
    int base = bkt * BUCKET_CAP;
    int cnt = cursor[bkt] - base;

    for (int i = tid; i < BKT_NODES; i += 256) hist[i] = 0;
    __syncthreads();
    for (int e = tid; e < cnt; e += 256) {
        unsigned p = pairs[base + e];
        stage[e] = p;
        atomicAdd(&hist[p >> 17], 1);
    }
    __syncthreads();
    if (tid < BKT_NODES) offs[tid] = hist[tid];
    __syncthreads();
    for (int s = 1; s < BKT_NODES; s <<= 1) {
        int v = (tid < BKT_NODES && tid >= s) ? offs[tid - s] : 0;
        __syncthreads();
        if (tid < BKT_NODES) offs[tid] += v;
        __syncthreads();
    }
    if (tid < BKT_NODES) {
        int ex = offs[tid] - hist[tid];
        cur[tid] = ex;
        int node = bkt * BKT_NODES + tid;
        if (node < N_NODES) {
            row_start[node] = base + ex;
            row_deg[node] = hist[tid];
        }
    }
    __syncthreads();
    for (int e = tid; e < cnt; e += 256) {
        unsigned p = stage[e];
        int pos = atomicAdd(&cur[p >> 17], 1);
        pairs[base + pos] = p & 0x1FFFF;   // store src only
    }
}

// ---- gather aggregation + epilogue over bf16 xw.
// One wave per node; 4 edges per step (quarter-wave each); lane reads uint2
// (4 bf16 feats); f32 accumulate; shfl_xor(16,32) merges quarters.
__global__ void gather_kernel(const uint2* __restrict__ xwq,   // 16 uint2 per node
                              const int* __restrict__ row_start,
                              const int* __restrict__ row_deg,
                              const unsigned* __restrict__ csr_src,
                              const float* __restrict__ b,
                              const float* __restrict__ res,
                              float* __restrict__ xout,
                              int n_nodes) {
    int wid = (blockIdx.x * blockDim.x + threadIdx.x) >> 6;
    int lane = threadIdx.x & 63;
    if (wid >= n_nodes) return;
    int c = lane & 15;
    int q = lane >> 4;
    int start = row_start[wid];
    int end = start + row_deg[wid];
    float a0 = 0.f, a1 = 0.f, a2 = 0.f, a3 = 0.f;
    int e = start;
    for (; e + 16 <= end; e += 16) {
        unsigned s0 = csr_src[e + q];
        unsigned s1 = csr_src[e + q + 4];
        unsigned s2 = csr_src[e + q + 8];
        unsigned s3 = csr_src[e + q + 12];
        uint2 v0 = xwq[s0 * 16 + c];
        uint2 v1 = xwq[s1 * 16 + c];
        uint2 v2 = xwq[s2 * 16 + c];
        uint2 v3 = xwq[s3 * 16 + c];
        a0 += (__uint_as_float(v0.x << 16) + __uint_as_float(v1.x << 16))
            + (__uint_as_float(v2.x << 16) + __uint_as_float(v3.x << 16));
        a1 += (__uint_as_float(v0.x & 0xFFFF0000u) + __uint_as_float(v1.x & 0xFFFF0000u))
            + (__uint_as_float(v2.x & 0xFFFF0000u) + __uint_as_float(v3.x & 0xFFFF0000u));
        a2 += (__uint_as_float(v0.y << 16) + __uint_as_float(v1.y << 16))
            + (__uint_as_float(v2.y << 16) + __uint_as_float(v3.y << 16));
        a3 += (__uint_as_float(v0.y & 0xFFFF0000u) + __uint_as_float(v1.y & 0xFFFF0000u))
            + (__uint_as_float(v2.y & 0xFFFF0000u) + __uint_as_float(v3.y & 0xFFFF0000u));
    }
    for (; e + 4 <= end; e += 4) {
        unsigned s = csr_src[e + q];
        uint2 v = xwq[s * 16 + c];
        a0 += __uint_as_float(v.x << 16);
        a1 += __uint_as_float(v.x & 0xFFFF0000u);
        a2 += __uint_as_float(v.y << 16);
        a3 += __uint_as_float(v.y & 0xFFFF0000u);
    }
    if (e < end && q < end - e) {
        unsigned s = csr_src[e + q];
        uint2 v = xwq[s * 16 + c];
        a0 += __uint_as_float(v.x << 16);
        a1 += __uint_as_float(v.x & 0xFFFF0000u);
        a2 += __uint_as_float(v.y << 16);
        a3 += __uint_as_float(v.y & 0xFFFF0000u);
    }
    a0 += __shfl_xor(a0, 16, 64); a0 += __shfl_xor(a0, 32, 64);
    a1 += __shfl_xor(a1, 16, 64); a1 += __shfl_xor(a1, 32, 64);
    a2 += __shfl_xor(a2, 16, 64); a2 += __shfl_xor(a2, 32, 64);
    a3 += __shfl_xor(a3, 16, 64); a3 += __shfl_xor(a3, 32, 64);
    if (q == 0) {
        int f = c * 4;
        long o = (long)wid * HID + f;
        const float4 bv = *reinterpret_cast<const float4*>(&b[f]);
        const float4 rv = *reinterpret_cast<const float4*>(&res[o]);
        float4 wv;
        wv.x = fmaxf(a0 + bv.x, 0.f) + rv.x;
        wv.y = fmaxf(a1 + bv.y, 0.f) + rv.y;
        wv.z = fmaxf(a2 + bv.z, 0.f) + rv.z;
        wv.w = fmaxf(a3 + bv.w, 0.f) + rv.w;
        *reinterpret_cast<float4*>(&xout[o]) = wv;
    }
}

// ---- pooling gather: graph_ids sorted -> binary search range, one wave/graph
__global__ void pool_gather_kernel(const float* __restrict__ x,
                                   const int* __restrict__ gid,
                                   float* __restrict__ g,
                                   int n_graphs) {
    int wid = (blockIdx.x * blockDim.x + threadIdx.x) >> 6;
    int lane = threadIdx.x & 63;
    if (wid >= n_graphs) return;
    int lo = 0, hi = N_NODES;
    while (lo < hi) { int mid = (lo + hi) >> 1; if (gid[mid] < wid) lo = mid + 1; else hi = mid; }
    int start = lo;
    hi = N_NODES;
    while (lo < hi) { int mid = (lo + hi) >> 1; if (gid[mid] < wid + 1) lo = mid + 1; else hi = mid; }
    int end = lo;
    float acc = 0.f;
    for (int n = start; n < end; ++n)
        acc += x[(long)n * HID + lane];
    g[(long)wid * HID + lane] = acc;
}

// ---- MLP: one wave per graph. out = relu(g@Wm1+bm1) @ Wm2 + bm2
__global__ void mlp_kernel(const float* __restrict__ g,
                           const float* __restrict__ Wm1,
                           const float* __restrict__ bm1,
                           const float* __restrict__ Wm2,
                           const float* __restrict__ bm2,
                           float* __restrict__ out,
                           int n_graphs) {
    int wid = (blockIdx.x * blockDim.x + threadIdx.x) >> 6;
    int lane = threadIdx.x & 63;
    if (wid >= n_graphs) return;
    const float* gr = g + (long)wid * HID;
    float h0 = bm1[lane];
    float h1 = bm1[lane + 64];
    for (int k = 0; k < HID; ++k) {
        float gv = gr[k];
        h0 += gv * Wm1[k * MLP_HID + lane];
        h1 += gv * Wm1[k * MLP_HID + lane + 64];
    }
    float part = fmaxf(h0, 0.f) * Wm2[lane] + fmaxf(h1, 0.f) * Wm2[lane + 64];
    #pragma unroll
    for (int off = 32; off > 0; off >>= 1)
        part += __shfl_down(part, off, 64);
    if (lane == 0) out[wid] = part + bm2[0];
}

extern "C" void kernel_launch(void* const* d_in, const int* in_sizes, int n_in,
                              void* d_out, int out_size, void* d_ws, size_t ws_size,
                              hipStream_t stream) {
    const float* feats = (const float*)d_in[0];
    const int*   src   = (const int*)d_in[1];
    const int*   dst   = (const int*)d_in[2];
    const int*   gid   = (const int*)d_in[3];
    const float* W[3]  = {(const float*)d_in[4],  (const float*)d_in[8],  (const float*)d_in[12]};
    const float* b[3]  = {(const float*)d_in[5],  (const float*)d_in[9],  (const float*)d_in[13]};
    const float* R[3]  = {(const float*)d_in[6],  (const float*)d_in[10], (const float*)d_in[14]};
    const float* rb[3] = {(const float*)d_in[7],  (const float*)d_in[11], (const float*)d_in[15]};
    const float* Wm1 = (const float*)d_in[16];
    const float* bm1 = (const float*)d_in[17];
    const float* Wm2 = (const float*)d_in[18];
    const float* bm2 = (const float*)d_in[19];
    float* out = (float*)d_out;

    // workspace carve
    char* ws = (char*)d_ws;
    const size_t node_buf = (size_t)N_NODES * HID * sizeof(float);   // 25.6 MB
    float*          xbuf      = (float*)(ws);          ws += node_buf;
    unsigned short* xwb       = (unsigned short*)(ws); ws += (size_t)N_NODES * HID * sizeof(unsigned short); // 12.8 MB
    float*          res       = (float*)(ws);          ws += node_buf;
    float*          gbuf      = (float*)(ws);          ws += (size_t)N_GRAPHS * HID * sizeof(float);
    int*            cursor    = (int*)(ws);            ws += (size_t)NBUCKET * sizeof(int);
    int*            row_start = (int*)(ws);            ws += (size_t)N_NODES * sizeof(int);
    int*            row_deg   = (int*)(ws);            ws += (size_t)N_NODES * sizeof(int);
    int*            blockHist = (int*)(ws);            ws += (size_t)NBUCKET * NBLK * sizeof(int);  // 800 KB
    unsigned short* wtbuf     = (unsigned short*)(ws); ws += (size_t)(2 * SZ0 + 4 * SZ12) * sizeof(unsigned short);
    ws = (char*)(((size_t)ws + 255) & ~(size_t)255);
    unsigned*       pairs     = (unsigned*)(ws);       ws += (size_t)NBUCKET * BUCKET_CAP * sizeof(unsigned); // 25.6 MB

    // ---- one-time weight transpose/quantize + bucketed CSR build
    prep_wt_kernel<<<6, 256, 0, stream>>>(W[0], R[0], W[1], R[1], W[2], R[2], wtbuf);
    split_hist_kernel<<<NBLK, 256, 0, stream>>>(dst, blockHist);
    split_scan_kernel<<<NBUCKET, NBLK, 0, stream>>>(blockHist, cursor);
    split_scatter_kernel<<<NBLK, 256, 0, stream>>>(src, dst, blockHist, pairs);
    bucket_sort_kernel<<<NBUCKET, 256, 0, stream>>>(pairs, cursor, row_start, row_deg);

    const unsigned short* wt_l[3] = {wtbuf, wtbuf + 2 * SZ0, wtbuf + 2 * SZ0 + 2 * SZ12};

    for (int l = 0; l < 3; ++l) {
        const float* xin = (l == 0) ? feats : xbuf;
        {
            int blocks = (N_NODES + 63) / 64;     // 64 nodes per block
            if (l == 0)
                proj_mfma_kernel<IN_DIM, 96, STRIDE0><<<blocks, 256, 0, stream>>>(
                    xin, wt_l[l], rb[l], xwb, res, N_NODES);
            else
                proj_mfma_kernel<HID, 64, STRIDE12><<<blocks, 256, 0, stream>>>(
                    xin, wt_l[l], rb[l], xwb, res, N_NODES);
        }
        {
            int blocks = (N_NODES * 64 + 255) / 256;  // one wave per node
            gather_kernel<<<blocks, 256, 0, stream>>>((const uint2*)xwb, row_start, row_deg,
                                                      pairs, b[l], res, xbuf, N_NODES);
        }
    }

    // pooling
    {
        int threads = N_GRAPHS * 64;
        pool_gather_kernel<<<(threads + 255) / 256, 256, 0, stream>>>(xbuf, gid, gbuf, N_GRAPHS);
    }
    // MLP
    {
        int threads = N_GRAPHS * 64;
        mlp_kernel<<<(threads + 255) / 256, 256, 0, stream>>>(gbuf, Wm1, bm1, Wm2, bm2, out, N_GRAPHS);
    }
}

// Round 11
// 376.441 us; speedup vs baseline: 14.1244x; 1.0324x over previous
//
#include <hip/hip_runtime.h>

#define N_NODES 100000
#define N_EDGES 3200000
#define N_GRAPHS 4096
#define IN_DIM 74
#define HID 64
#define MLP_HID 128

#define BKT_NODES 128                 // nodes per bucket
#define NBUCKET ((N_NODES + BKT_NODES - 1) / BKT_NODES)   // 782
#define BUCKET_CAP 8192               // edges capacity per bucket (mean ~4096)
#define NBLK 1024                     // split blocks (4 blocks/CU for latency hiding)
#define CHUNK ((N_EDGES + NBLK - 1) / NBLK)               // 3125

// prep'd weight layout sizes (bf16, transposed [feat][k], padded stride)
#define STRIDE0 104                   // layer0: KPAD=96, stride 104
#define STRIDE12 72                   // layers 1,2: KPAD=64, stride 72
#define SZ0 (64 * STRIDE0)
#define SZ12 (64 * STRIDE12)

typedef __attribute__((ext_vector_type(8))) short bf16x8;
typedef __attribute__((ext_vector_type(4))) float f32x4;

__device__ __forceinline__ unsigned short f32_to_bf16_rne(float f) {
    unsigned u = __float_as_uint(f);
    unsigned r = (u + 0x7FFFu + ((u >> 16) & 1u)) >> 16;
    return (unsigned short)r;
}
__device__ __forceinline__ float bf16lo_f(unsigned v) { return __uint_as_float(v << 16); }
__device__ __forceinline__ float bf16hi_f(unsigned v) { return __uint_as_float(v & 0xFFFF0000u); }

// ---- one-time weight prep: Wt[l][feat][k] = bf16(W_l[k][feat]), zero-padded.
__global__ void prep_wt_kernel(const float* __restrict__ W0, const float* __restrict__ R0,
                               const float* __restrict__ W1, const float* __restrict__ R1,
                               const float* __restrict__ W2, const float* __restrict__ R2,
                               unsigned short* __restrict__ wtbuf) {
    const float* srcs[6] = {W0, R0, W1, R1, W2, R2};
    int id = blockIdx.x;
    int l = id >> 1, isR = id & 1;
    const float* src = srcs[id];
    int IN = (l == 0) ? IN_DIM : HID;
    int STRIDE = (l == 0) ? STRIDE0 : STRIDE12;
    int base = (l == 0 ? 0 : 2 * SZ0 + (l - 1) * 2 * SZ12) + isR * (l == 0 ? SZ0 : SZ12);
    int total = 64 * STRIDE;
    for (int i = threadIdx.x; i < total; i += 256) {
        int n = i / STRIDE, k = i - n * STRIDE;
        wtbuf[base + i] = (k < IN) ? f32_to_bf16_rne(src[k * HID + n]) : 0;
    }
}

// ---- projection via MFMA: xw(bf16) = x@W ; res(bf16) = relu(x@R + rb).
// Block = 4 waves = 64 nodes. LDS: x tile bf16 [64][STRIDE], Wt/Rt copies.
template<int IN, int KPAD, int STRIDE, bool BF16IN>
__launch_bounds__(256)
__global__ void proj_mfma_kernel(const void* __restrict__ x,
                                 const unsigned short* __restrict__ wt_layer, // W then R
                                 const float* __restrict__ rb,
                                 unsigned short* __restrict__ xwb,
                                 unsigned short* __restrict__ resb,
                                 int n_nodes) {
    __shared__ __align__(16) unsigned short xs[64 * STRIDE];
    __shared__ __align__(16) unsigned short wt[64 * STRIDE];
    __shared__ __align__(16) unsigned short rt[64 * STRIDE];
    int n0 = blockIdx.x * 64;
    int tid = threadIdx.x;

    // copy prepped weights (bf16, padded layout) via 16B chunks
    {
        const uint4* gw = reinterpret_cast<const uint4*>(wt_layer);
        const uint4* gr = reinterpret_cast<const uint4*>(wt_layer + 64 * STRIDE);
        uint4* sw = reinterpret_cast<uint4*>(wt);
        uint4* sr = reinterpret_cast<uint4*>(rt);
        const int cnt = 64 * STRIDE / 8;
        for (int i = tid; i < cnt; i += 256) { sw[i] = gw[i]; sr[i] = gr[i]; }
    }
    if (!BF16IN) {
        const float* xf = (const float*)x;
        for (int i = tid; i < 64 * STRIDE; i += 256) {
            int row = i / STRIDE, col = i - row * STRIDE;
            int n = n0 + row;
            float v = (col < IN && n < n_nodes) ? xf[(long)n * IN + col] : 0.f;
            xs[i] = f32_to_bf16_rne(v);
        }
    } else {
        // IN==64 bf16 rows: straight uint4 copy into padded stride
        const uint4* xb = (const uint4*)x;
        for (int i = tid; i < 64 * 8; i += 256) {
            int row = i >> 3, c8 = (i & 7) << 3;
            int n = n0 + row;
            uint4 v = make_uint4(0, 0, 0, 0);
            if (n < n_nodes) v = xb[(long)n * 8 + (i & 7)];
            *reinterpret_cast<uint4*>(&xs[row * STRIDE + c8]) = v;
        }
    }
    __syncthreads();

    int w = tid >> 6, lane = tid & 63;
    int nb = w * 16;
    int rc = lane & 15;        // A row / B col / D col
    int kg = lane >> 4;        // k-chunk of 8

    f32x4 accW[4], accR[4];
    #pragma unroll
    for (int fg = 0; fg < 4; ++fg) { accW[fg] = {0.f, 0.f, 0.f, 0.f}; accR[fg] = {0.f, 0.f, 0.f, 0.f}; }

    #pragma unroll
    for (int ks = 0; ks < KPAD / 32; ++ks) {
        int k0 = ks * 32 + kg * 8;
        bf16x8 a = *reinterpret_cast<const bf16x8*>(&xs[(nb + rc) * STRIDE + k0]);
        #pragma unroll
        for (int fg = 0; fg < 4; ++fg) {
            bf16x8 bw = *reinterpret_cast<const bf16x8*>(&wt[(fg * 16 + rc) * STRIDE + k0]);
            accW[fg] = __builtin_amdgcn_mfma_f32_16x16x32_bf16(a, bw, accW[fg], 0, 0, 0);
            bf16x8 br = *reinterpret_cast<const bf16x8*>(&rt[(fg * 16 + rc) * STRIDE + k0]);
            accR[fg] = __builtin_amdgcn_mfma_f32_16x16x32_bf16(a, br, accR[fg], 0, 0, 0);
        }
    }

    // D: col = lane&15, row = (lane>>4)*4 + reg
    #pragma unroll
    for (int fg = 0; fg < 4; ++fg) {
        int feat = fg * 16 + rc;
        float rbv = rb[feat];
        #pragma unroll
        for (int r = 0; r < 4; ++r) {
            int node = n0 + nb + kg * 4 + r;
            if (node < n_nodes) {
                long o = (long)node * HID + feat;
                xwb[o]  = f32_to_bf16_rne(accW[fg][r]);
                resb[o] = f32_to_bf16_rne(fmaxf(accR[fg][r] + rbv, 0.f));
            }
        }
    }
}

// ---- split pass 1: per-block LDS histogram of dst buckets
__launch_bounds__(256)
__global__ void split_hist_kernel(const int* __restrict__ dst,
                                  int* __restrict__ blockHist /*[NBUCKET][NBLK]*/) {
    __shared__ int h[NBUCKET];
    int blk = blockIdx.x, tid = threadIdx.x;
    for (int i = tid; i < NBUCKET; i += 256) h[i] = 0;
    __syncthreads();
    int lo = blk * CHUNK;
    int hi = lo + CHUNK; if (hi > N_EDGES) hi = N_EDGES;
    for (int e = lo + tid; e < hi; e += 256)
        atomicAdd(&h[dst[e] >> 7], 1);
    __syncthreads();
    for (int i = tid; i < NBUCKET; i += 256)
        blockHist[i * NBLK + blk] = h[i];
}

// ---- split pass 2: per-bucket exclusive scan over the NBLK block counts.
__launch_bounds__(NBLK)
__global__ void split_scan_kernel(int* __restrict__ blockHist,
                                  int* __restrict__ cursor) {
    __shared__ int s[NBLK];
    int bkt = blockIdx.x, tid = threadIdx.x;
    int v = blockHist[bkt * NBLK + tid];
    s[tid] = v;
    __syncthreads();
    for (int off = 1; off < NBLK; off <<= 1) {
        int t = (tid >= off) ? s[tid - off] : 0;
        __syncthreads();
        s[tid] += t;
        __syncthreads();
    }
    blockHist[bkt * NBLK + tid] = bkt * BUCKET_CAP + s[tid] - v;   // exclusive
    if (tid == NBLK - 1) cursor[bkt] = bkt * BUCKET_CAP + s[tid]; // total end
}

// ---- split pass 3: scatter to exact positions (LDS cursors, no global atomics)
__launch_bounds__(256)
__global__ void split_scatter_kernel(const int* __restrict__ src,
                                     const int* __restrict__ dst,
                                     const int* __restrict__ blockHist,
                                     unsigned* __restrict__ pairs) {
    __shared__ int cur[NBUCKET];
    int blk = blockIdx.x, tid = threadIdx.x;
    for (int i = tid; i < NBUCKET; i += 256)
        cur[i] = blockHist[i * NBLK + blk];
    __syncthreads();
    int lo = blk * CHUNK;
    int hi = lo + CHUNK; if (hi > N_EDGES) hi = N_EDGES;
    for (int e = lo + tid; e < hi; e += 256) {
        int d = dst[e];
        int b = d >> 7;
        int pos = atomicAdd(&cur[b], 1);
        pairs[pos] = (unsigned)src[e] | ((unsigned)(d & (BKT_NODES - 1)) << 17);
    }
}

// ---- per-bucket LDS counting sort -> src sorted by dst_local; row_start/row_deg
__launch_bounds__(256)
__global__ void bucket_sort_kernel(unsigned* __restrict__ pairs,
                                   const int* __restrict__ cursor,
                                   int* __restrict__ row_start,
                                   int* __restrict__ row_deg) {
    __shared__ unsigned stage[BUCKET_CAP];   // 32 KB
    __shared__ int hist[BKT_NODES];
    __shared__ int offs[BKT_NODES];
    __shared__ int cur[BKT_NODES];
    int bkt = blockIdx.x;
    int tid = threadIdx.x;
    int base = bkt * BUCKET_CAP;
    int cnt = cursor[bkt] - base;

    for (int i = tid; i < BKT_NODES; i += 256) hist[i] = 0;
    __syncthreads();
    for (int e = tid; e < cnt; e += 256) {
        unsigned p = pairs[base + e];
        stage[e] = p;
        atomicAdd(&hist[p >> 17], 1);
    }
    __syncthreads();
    if (tid < BKT_NODES) offs[tid] = hist[tid];
    __syncthreads();
    for (int s = 1; s < BKT_NODES; s <<= 1) {
        int v = (tid < BKT_NODES && tid >= s) ? offs[tid - s] : 0;
        __syncthreads();
        if (tid < BKT_NODES) offs[tid] += v;
        __syncthreads();
    }
    if (tid < BKT_NODES) {
        int ex = offs[tid] - hist[tid];
        cur[tid] = ex;
        int node = bkt * BKT_NODES + tid;
        if (node < N_NODES) {
            row_start[node] = base + ex;
            row_deg[node] = hist[tid];
        }
    }
    __syncthreads();
    for (int e = tid; e < cnt; e += 256) {
        unsigned p = stage[e];
        int pos = atomicAdd(&cur[p >> 17], 1);
        pairs[base + pos] = p & 0x1FFFF;   // store src only
    }
}

// ---- gather aggregation + epilogue over bf16 xw; res/xout bf16.
// One wave per node; 4 edges per step (quarter-wave each); lane reads uint2.
__global__ void gather_kernel(const uint2* __restrict__ xwq,   // 16 uint2 per node
                              const int* __restrict__ row_start,
                              const int* __restrict__ row_deg,
                              const unsigned* __restrict__ csr_src,
                              const float* __restrict__ b,
                              const unsigned short* __restrict__ resb,
                              unsigned short* __restrict__ xoutb,
                              int n_nodes) {
    int wid = (blockIdx.x * blockDim.x + threadIdx.x) >> 6;
    int lane = threadIdx.x & 63;
    if (wid >= n_nodes) return;
    int c = lane & 15;
    int q = lane >> 4;
    int start = row_start[wid];
    int end = start + row_deg[wid];
    float a0 = 0.f, a1 = 0.f, a2 = 0.f, a3 = 0.f;
    int e = start;
    for (; e + 16 <= end; e += 16) {
        unsigned s0 = csr_src[e + q];
        unsigned s1 = csr_src[e + q + 4];
        unsigned s2 = csr_src[e + q + 8];
        unsigned s3 = csr_src[e + q + 12];
        uint2 v0 = xwq[s0 * 16 + c];
        uint2 v1 = xwq[s1 * 16 + c];
        uint2 v2 = xwq[s2 * 16 + c];
        uint2 v3 = xwq[s3 * 16 + c];
        a0 += (bf16lo_f(v0.x) + bf16lo_f(v1.x)) + (bf16lo_f(v2.x) + bf16lo_f(v3.x));
        a1 += (bf16hi_f(v0.x) + bf16hi_f(v1.x)) + (bf16hi_f(v2.x) + bf16hi_f(v3.x));
        a2 += (bf16lo_f(v0.y) + bf16lo_f(v1.y)) + (bf16lo_f(v2.y) + bf16lo_f(v3.y));
        a3 += (bf16hi_f(v0.y) + bf16hi_f(v1.y)) + (bf16hi_f(v2.y) + bf16hi_f(v3.y));
    }
    for (; e + 4 <= end; e += 4) {
        unsigned s = csr_src[e + q];
        uint2 v = xwq[s * 16 + c];
        a0 += bf16lo_f(v.x); a1 += bf16hi_f(v.x);
        a2 += bf16lo_f(v.y); a3 += bf16hi_f(v.y);
    }
    if (e < end && q < end - e) {
        unsigned s = csr_src[e + q];
        uint2 v = xwq[s * 16 + c];
        a0 += bf16lo_f(v.x); a1 += bf16hi_f(v.x);
        a2 += bf16lo_f(v.y); a3 += bf16hi_f(v.y);
    }
    a0 += __shfl_xor(a0, 16, 64); a0 += __shfl_xor(a0, 32, 64);
    a1 += __shfl_xor(a1, 16, 64); a1 += __shfl_xor(a1, 32, 64);
    a2 += __shfl_xor(a2, 16, 64); a2 += __shfl_xor(a2, 32, 64);
    a3 += __shfl_xor(a3, 16, 64); a3 += __shfl_xor(a3, 32, 64);
    if (q == 0) {
        int f = c * 4;
        long o = (long)wid * HID + f;
        const float4 bv = *reinterpret_cast<const float4*>(&b[f]);
        uint2 rv = *reinterpret_cast<const uint2*>(&resb[o]);
        float w0 = fmaxf(a0 + bv.x, 0.f) + bf16lo_f(rv.x);
        float w1 = fmaxf(a1 + bv.y, 0.f) + bf16hi_f(rv.x);
        float w2 = fmaxf(a2 + bv.z, 0.f) + bf16lo_f(rv.y);
        float w3 = fmaxf(a3 + bv.w, 0.f) + bf16hi_f(rv.y);
        uint2 ov;
        ov.x = (unsigned)f32_to_bf16_rne(w0) | ((unsigned)f32_to_bf16_rne(w1) << 16);
        ov.y = (unsigned)f32_to_bf16_rne(w2) | ((unsigned)f32_to_bf16_rne(w3) << 16);
        *reinterpret_cast<uint2*>(&xoutb[o]) = ov;
    }
}

// ---- pooling gather over bf16 x: one wave/graph, binary search range
__global__ void pool_gather_kernel(const unsigned short* __restrict__ x,
                                   const int* __restrict__ gid,
                                   float* __restrict__ g,
                                   int n_graphs) {
    int wid = (blockIdx.x * blockDim.x + threadIdx.x) >> 6;
    int lane = threadIdx.x & 63;
    if (wid >= n_graphs) return;
    int lo = 0, hi = N_NODES;
    while (lo < hi) { int mid = (lo + hi) >> 1; if (gid[mid] < wid) lo = mid + 1; else hi = mid; }
    int start = lo;
    hi = N_NODES;
    while (lo < hi) { int mid = (lo + hi) >> 1; if (gid[mid] < wid + 1) lo = mid + 1; else hi = mid; }
    int end = lo;
    float acc = 0.f;
    for (int n = start; n < end; ++n)
        acc += __uint_as_float((unsigned)x[(long)n * HID + lane] << 16);
    g[(long)wid * HID + lane] = acc;
}

// ---- MLP: one wave per graph. out = relu(g@Wm1+bm1) @ Wm2 + bm2
__global__ void mlp_kernel(const float* __restrict__ g,
                           const float* __restrict__ Wm1,
                           const float* __restrict__ bm1,
                           const float* __restrict__ Wm2,
                           const float* __restrict__ bm2,
                           float* __restrict__ out,
                           int n_graphs) {
    int wid = (blockIdx.x * blockDim.x + threadIdx.x) >> 6;
    int lane = threadIdx.x & 63;
    if (wid >= n_graphs) return;
    const float* gr = g + (long)wid * HID;
    float h0 = bm1[lane];
    float h1 = bm1[lane + 64];
    for (int k = 0; k < HID; ++k) {
        float gv = gr[k];
        h0 += gv * Wm1[k * MLP_HID + lane];
        h1 += gv * Wm1[k * MLP_HID + lane + 64];
    }
    float part = fmaxf(h0, 0.f) * Wm2[lane] + fmaxf(h1, 0.f) * Wm2[lane + 64];
    #pragma unroll
    for (int off = 32; off > 0; off >>= 1)
        part += __shfl_down(part, off, 64);
    if (lane == 0) out[wid] = part + bm2[0];
}

extern "C" void kernel_launch(void* const* d_in, const int* in_sizes, int n_in,
                              void* d_out, int out_size, void* d_ws, size_t ws_size,
                              hipStream_t stream) {
    const float* feats = (const float*)d_in[0];
    const int*   src   = (const int*)d_in[1];
    const int*   dst   = (const int*)d_in[2];
    const int*   gid   = (const int*)d_in[3];
    const float* W[3]  = {(const float*)d_in[4],  (const float*)d_in[8],  (const float*)d_in[12]};
    const float* b[3]  = {(const float*)d_in[5],  (const float*)d_in[9],  (const float*)d_in[13]};
    const float* R[3]  = {(const float*)d_in[6],  (const float*)d_in[10], (const float*)d_in[14]};
    const float* rb[3] = {(const float*)d_in[7],  (const float*)d_in[11], (const float*)d_in[15]};
    const float* Wm1 = (const float*)d_in[16];
    const float* bm1 = (const float*)d_in[17];
    const float* Wm2 = (const float*)d_in[18];
    const float* bm2 = (const float*)d_in[19];
    float* out = (float*)d_out;

    // workspace carve
    char* ws = (char*)d_ws;
    const size_t node_bf16 = (size_t)N_NODES * HID * sizeof(unsigned short);  // 12.8 MB
    unsigned short* xbufb     = (unsigned short*)(ws); ws += node_bf16;
    unsigned short* xwb       = (unsigned short*)(ws); ws += node_bf16;
    unsigned short* resb      = (unsigned short*)(ws); ws += node_bf16;
    float*          gbuf      = (float*)(ws);          ws += (size_t)N_GRAPHS * HID * sizeof(float);
    int*            cursor    = (int*)(ws);            ws += (size_t)NBUCKET * sizeof(int);
    int*            row_start = (int*)(ws);            ws += (size_t)N_NODES * sizeof(int);
    int*            row_deg   = (int*)(ws);            ws += (size_t)N_NODES * sizeof(int);
    int*            blockHist = (int*)(ws);            ws += (size_t)NBUCKET * NBLK * sizeof(int);  // 3.2 MB
    unsigned short* wtbuf     = (unsigned short*)(ws); ws += (size_t)(2 * SZ0 + 4 * SZ12) * sizeof(unsigned short);
    ws = (char*)(((size_t)ws + 255) & ~(size_t)255);
    unsigned*       pairs     = (unsigned*)(ws);       ws += (size_t)NBUCKET * BUCKET_CAP * sizeof(unsigned); // 25.6 MB

    // ---- one-time weight transpose/quantize + bucketed CSR build
    prep_wt_kernel<<<6, 256, 0, stream>>>(W[0], R[0], W[1], R[1], W[2], R[2], wtbuf);
    split_hist_kernel<<<NBLK, 256, 0, stream>>>(dst, blockHist);
    split_scan_kernel<<<NBUCKET, NBLK, 0, stream>>>(blockHist, cursor);
    split_scatter_kernel<<<NBLK, 256, 0, stream>>>(src, dst, blockHist, pairs);
    bucket_sort_kernel<<<NBUCKET, 256, 0, stream>>>(pairs, cursor, row_start, row_deg);

    const unsigned short* wt_l[3] = {wtbuf, wtbuf + 2 * SZ0, wtbuf + 2 * SZ0 + 2 * SZ12};

    for (int l = 0; l < 3; ++l) {
        {
            int blocks = (N_NODES + 63) / 64;     // 64 nodes per block
            if (l == 0)
                proj_mfma_kernel<IN_DIM, 96, STRIDE0, false><<<blocks, 256, 0, stream>>>(
                    (const void*)feats, wt_l[l], rb[l], xwb, resb, N_NODES);
            else
                proj_mfma_kernel<HID, 64, STRIDE12, true><<<blocks, 256, 0, stream>>>(
                    (const void*)xbufb, wt_l[l], rb[l], xwb, resb, N_NODES);
        }
        {
            int blocks = (N_NODES * 64 + 255) / 256;  // one wave per node
            gather_kernel<<<blocks, 256, 0, stream>>>((const uint2*)xwb, row_start, row_deg,
                                                      pairs, b[l], resb, xbufb, N_NODES);
        }
    }

    // pooling
    {
        int threads = N_GRAPHS * 64;
        pool_gather_kernel<<<(threads + 255) / 256, 256, 0, stream>>>(xbufb, gid, gbuf, N_GRAPHS);
    }
    // MLP
    {
        int threads = N_GRAPHS * 64;
        mlp_kernel<<<(threads + 255) / 256, 256, 0, stream>>>(gbuf, Wm1, bm1, Wm2, bm2, out, N_GRAPHS);
    }
}

// Round 12
// 350.117 us; speedup vs baseline: 15.1864x; 1.0752x over previous
//
#include <hip/hip_runtime.h>

#define N_NODES 100000
#define N_EDGES 3200000
#define N_GRAPHS 4096
#define IN_DIM 74
#define HID 64
#define MLP_HID 128

#define BKT_NODES 128                 // nodes per bucket
#define NBUCKET ((N_NODES + BKT_NODES - 1) / BKT_NODES)   // 782
#define BUCKET_CAP 8192               // edges capacity per bucket (mean ~4096)
#define NBLK 256                      // split blocks (long per-bucket runs = full 64B lines)
#define SPLIT_THREADS 1024            // fat blocks for occupancy (16 waves, 2 blocks/CU)
#define CHUNK ((N_EDGES + NBLK - 1) / NBLK)               // 12500

// prep'd weight layout sizes (bf16, transposed [feat][k], padded stride)
#define STRIDE0 104                   // layer0: KPAD=96, stride 104
#define STRIDE12 72                   // layers 1,2: KPAD=64, stride 72
#define SZ0 (64 * STRIDE0)
#define SZ12 (64 * STRIDE12)

typedef __attribute__((ext_vector_type(8))) short bf16x8;
typedef __attribute__((ext_vector_type(4))) float f32x4;

__device__ __forceinline__ unsigned short f32_to_bf16_rne(float f) {
    unsigned u = __float_as_uint(f);
    unsigned r = (u + 0x7FFFu + ((u >> 16) & 1u)) >> 16;
    return (unsigned short)r;
}
__device__ __forceinline__ float bf16lo_f(unsigned v) { return __uint_as_float(v << 16); }
__device__ __forceinline__ float bf16hi_f(unsigned v) { return __uint_as_float(v & 0xFFFF0000u); }

// ---- one-time weight prep: Wt[l][feat][k] = bf16(W_l[k][feat]), zero-padded.
__global__ void prep_wt_kernel(const float* __restrict__ W0, const float* __restrict__ R0,
                               const float* __restrict__ W1, const float* __restrict__ R1,
                               const float* __restrict__ W2, const float* __restrict__ R2,
                               unsigned short* __restrict__ wtbuf) {
    const float* srcs[6] = {W0, R0, W1, R1, W2, R2};
    int id = blockIdx.x;
    int l = id >> 1, isR = id & 1;
    const float* src = srcs[id];
    int IN = (l == 0) ? IN_DIM : HID;
    int STRIDE = (l == 0) ? STRIDE0 : STRIDE12;
    int base = (l == 0 ? 0 : 2 * SZ0 + (l - 1) * 2 * SZ12) + isR * (l == 0 ? SZ0 : SZ12);
    int total = 64 * STRIDE;
    for (int i = threadIdx.x; i < total; i += 256) {
        int n = i / STRIDE, k = i - n * STRIDE;
        wtbuf[base + i] = (k < IN) ? f32_to_bf16_rne(src[k * HID + n]) : 0;
    }
}

// ---- projection via MFMA: xw(bf16) = x@W ; res(bf16) = relu(x@R + rb).
template<int IN, int KPAD, int STRIDE, bool BF16IN>
__launch_bounds__(256)
__global__ void proj_mfma_kernel(const void* __restrict__ x,
                                 const unsigned short* __restrict__ wt_layer, // W then R
                                 const float* __restrict__ rb,
                                 unsigned short* __restrict__ xwb,
                                 unsigned short* __restrict__ resb,
                                 int n_nodes) {
    __shared__ __align__(16) unsigned short xs[64 * STRIDE];
    __shared__ __align__(16) unsigned short wt[64 * STRIDE];
    __shared__ __align__(16) unsigned short rt[64 * STRIDE];
    int n0 = blockIdx.x * 64;
    int tid = threadIdx.x;

    {
        const uint4* gw = reinterpret_cast<const uint4*>(wt_layer);
        const uint4* gr = reinterpret_cast<const uint4*>(wt_layer + 64 * STRIDE);
        uint4* sw = reinterpret_cast<uint4*>(wt);
        uint4* sr = reinterpret_cast<uint4*>(rt);
        const int cnt = 64 * STRIDE / 8;
        for (int i = tid; i < cnt; i += 256) { sw[i] = gw[i]; sr[i] = gr[i]; }
    }
    if (!BF16IN) {
        const float* xf = (const float*)x;
        for (int i = tid; i < 64 * STRIDE; i += 256) {
            int row = i / STRIDE, col = i - row * STRIDE;
            int n = n0 + row;
            float v = (col < IN && n < n_nodes) ? xf[(long)n * IN + col] : 0.f;
            xs[i] = f32_to_bf16_rne(v);
        }
    } else {
        const uint4* xb = (const uint4*)x;
        for (int i = tid; i < 64 * 8; i += 256) {
            int row = i >> 3, c8 = (i & 7) << 3;
            int n = n0 + row;
            uint4 v = make_uint4(0, 0, 0, 0);
            if (n < n_nodes) v = xb[(long)n * 8 + (i & 7)];
            *reinterpret_cast<uint4*>(&xs[row * STRIDE + c8]) = v;
        }
    }
    __syncthreads();

    int w = tid >> 6, lane = tid & 63;
    int nb = w * 16;
    int rc = lane & 15;        // A row / B col / D col
    int kg = lane >> 4;        // k-chunk of 8

    f32x4 accW[4], accR[4];
    #pragma unroll
    for (int fg = 0; fg < 4; ++fg) { accW[fg] = {0.f, 0.f, 0.f, 0.f}; accR[fg] = {0.f, 0.f, 0.f, 0.f}; }

    #pragma unroll
    for (int ks = 0; ks < KPAD / 32; ++ks) {
        int k0 = ks * 32 + kg * 8;
        bf16x8 a = *reinterpret_cast<const bf16x8*>(&xs[(nb + rc) * STRIDE + k0]);
        #pragma unroll
        for (int fg = 0; fg < 4; ++fg) {
            bf16x8 bw = *reinterpret_cast<const bf16x8*>(&wt[(fg * 16 + rc) * STRIDE + k0]);
            accW[fg] = __builtin_amdgcn_mfma_f32_16x16x32_bf16(a, bw, accW[fg], 0, 0, 0);
            bf16x8 br = *reinterpret_cast<const bf16x8*>(&rt[(fg * 16 + rc) * STRIDE + k0]);
            accR[fg] = __builtin_amdgcn_mfma_f32_16x16x32_bf16(a, br, accR[fg], 0, 0, 0);
        }
    }

    // D: col = lane&15, row = (lane>>4)*4 + reg
    #pragma unroll
    for (int fg = 0; fg < 4; ++fg) {
        int feat = fg * 16 + rc;
        float rbv = rb[feat];
        #pragma unroll
        for (int r = 0; r < 4; ++r) {
            int node = n0 + nb + kg * 4 + r;
            if (node < n_nodes) {
                long o = (long)node * HID + feat;
                xwb[o]  = f32_to_bf16_rne(accW[fg][r]);
                resb[o] = f32_to_bf16_rne(fmaxf(accR[fg][r] + rbv, 0.f));
            }
        }
    }
}

// ---- split pass 1: per-block LDS histogram of dst buckets (1024-thread blocks)
__launch_bounds__(SPLIT_THREADS)
__global__ void split_hist_kernel(const int* __restrict__ dst,
                                  int* __restrict__ blockHist /*[NBUCKET][NBLK]*/) {
    __shared__ int h[NBUCKET];
    int blk = blockIdx.x, tid = threadIdx.x;
    for (int i = tid; i < NBUCKET; i += SPLIT_THREADS) h[i] = 0;
    __syncthreads();
    int lo = blk * CHUNK;
    int hi = lo + CHUNK; if (hi > N_EDGES) hi = N_EDGES;
    for (int e = lo + tid; e < hi; e += SPLIT_THREADS)
        atomicAdd(&h[dst[e] >> 7], 1);
    __syncthreads();
    for (int i = tid; i < NBUCKET; i += SPLIT_THREADS)
        blockHist[i * NBLK + blk] = h[i];
}

// ---- split pass 2: per-bucket exclusive scan over the NBLK block counts.
__launch_bounds__(NBLK)
__global__ void split_scan_kernel(int* __restrict__ blockHist,
                                  int* __restrict__ cursor) {
    __shared__ int s[NBLK];
    int bkt = blockIdx.x, tid = threadIdx.x;
    int v = blockHist[bkt * NBLK + tid];
    s[tid] = v;
    __syncthreads();
    for (int off = 1; off < NBLK; off <<= 1) {
        int t = (tid >= off) ? s[tid - off] : 0;
        __syncthreads();
        s[tid] += t;
        __syncthreads();
    }
    blockHist[bkt * NBLK + tid] = bkt * BUCKET_CAP + s[tid] - v;   // exclusive
    if (tid == NBLK - 1) cursor[bkt] = bkt * BUCKET_CAP + s[tid]; // total end
}

// ---- split pass 3: scatter to exact positions (LDS cursors; 1024-thread blocks)
__launch_bounds__(SPLIT_THREADS)
__global__ void split_scatter_kernel(const int* __restrict__ src,
                                     const int* __restrict__ dst,
                                     const int* __restrict__ blockHist,
                                     unsigned* __restrict__ pairs) {
    __shared__ int cur[NBUCKET];
    int blk = blockIdx.x, tid = threadIdx.x;
    for (int i = tid; i < NBUCKET; i += SPLIT_THREADS)
        cur[i] = blockHist[i * NBLK + blk];
    __syncthreads();
    int lo = blk * CHUNK;
    int hi = lo + CHUNK; if (hi > N_EDGES) hi = N_EDGES;
    for (int e = lo + tid; e < hi; e += SPLIT_THREADS) {
        int d = dst[e];
        int b = d >> 7;
        int pos = atomicAdd(&cur[b], 1);
        pairs[pos] = (unsigned)src[e] | ((unsigned)(d & (BKT_NODES - 1)) << 17);
    }
}

// ---- per-bucket LDS counting sort -> src sorted by dst_local; row_start/row_deg
__launch_bounds__(256)
__global__ void bucket_sort_kernel(unsigned* __restrict__ pairs,
                                   const int* __restrict__ cursor,
                                   int* __restrict__ row_start,
                                   int* __restrict__ row_deg) {
    __shared__ unsigned stage[BUCKET_CAP];   // 32 KB
    __shared__ int hist[BKT_NODES];
    __shared__ int offs[BKT_NODES];
    __shared__ int cur[BKT_NODES];
    int bkt = blockIdx.x;
    int tid = threadIdx.x;
    int base = bkt * BUCKET_CAP;
    int cnt = cursor[bkt] - base;

    for (int i = tid; i < BKT_NODES; i += 256) hist[i] = 0;
    __syncthreads();
    for (int e = tid; e < cnt; e += 256) {
        unsigned p = pairs[base + e];
        stage[e] = p;
        atomicAdd(&hist[p >> 17], 1);
    }
    __syncthreads();
    if (tid < BKT_NODES) offs[tid] = hist[tid];
    __syncthreads();
    for (int s = 1; s < BKT_NODES; s <<= 1) {
        int v = (tid < BKT_NODES && tid >= s) ? offs[tid - s] : 0;
        __syncthreads();
        if (tid < BKT_NODES) offs[tid] += v;
        __syncthreads();
    }
    if (tid < BKT_NODES) {
        int ex = offs[tid] - hist[tid];
        cur[tid] = ex;
        int node = bkt * BKT_NODES + tid;
        if (node < N_NODES) {
            row_start[node] = base + ex;
            row_deg[node] = hist[tid];
        }
    }
    __syncthreads();
    for (int e = tid; e < cnt; e += 256) {
        unsigned p = stage[e];
        int pos = atomicAdd(&cur[p >> 17], 1);
        pairs[base + pos] = p & 0x1FFFF;   // store src only
    }
}

// ---- gather aggregation + epilogue over bf16 xw; res/xout bf16.
__global__ void gather_kernel(const uint2* __restrict__ xwq,   // 16 uint2 per node
                              const int* __restrict__ row_start,
                              const int* __restrict__ row_deg,
                              const unsigned* __restrict__ csr_src,
                              const float* __restrict__ b,
                              const unsigned short* __restrict__ resb,
                              unsigned short* __restrict__ xoutb,
                              int n_nodes) {
    int wid = (blockIdx.x * blockDim.x + threadIdx.x) >> 6;
    int lane = threadIdx.x & 63;
    if (wid >= n_nodes) return;
    int c = lane & 15;
    int q = lane >> 4;
    int start = row_start[wid];
    int end = start + row_deg[wid];
    float a0 = 0.f, a1 = 0.f, a2 = 0.f, a3 = 0.f;
    int e = start;
    for (; e + 16 <= end; e += 16) {
        unsigned s0 = csr_src[e + q];
        unsigned s1 = csr_src[e + q + 4];
        unsigned s2 = csr_src[e + q + 8];
        unsigned s3 = csr_src[e + q + 12];
        uint2 v0 = xwq[s0 * 16 + c];
        uint2 v1 = xwq[s1 * 16 + c];
        uint2 v2 = xwq[s2 * 16 + c];
        uint2 v3 = xwq[s3 * 16 + c];
        a0 += (bf16lo_f(v0.x) + bf16lo_f(v1.x)) + (bf16lo_f(v2.x) + bf16lo_f(v3.x));
        a1 += (bf16hi_f(v0.x) + bf16hi_f(v1.x)) + (bf16hi_f(v2.x) + bf16hi_f(v3.x));
        a2 += (bf16lo_f(v0.y) + bf16lo_f(v1.y)) + (bf16lo_f(v2.y) + bf16lo_f(v3.y));
        a3 += (bf16hi_f(v0.y) + bf16hi_f(v1.y)) + (bf16hi_f(v2.y) + bf16hi_f(v3.y));
    }
    for (; e + 4 <= end; e += 4) {
        unsigned s = csr_src[e + q];
        uint2 v = xwq[s * 16 + c];
        a0 += bf16lo_f(v.x); a1 += bf16hi_f(v.x);
        a2 += bf16lo_f(v.y); a3 += bf16hi_f(v.y);
    }
    if (e < end && q < end - e) {
        unsigned s = csr_src[e + q];
        uint2 v = xwq[s * 16 + c];
        a0 += bf16lo_f(v.x); a1 += bf16hi_f(v.x);
        a2 += bf16lo_f(v.y); a3 += bf16hi_f(v.y);
    }
    a0 += __shfl_xor(a0, 16, 64); a0 += __shfl_xor(a0, 32, 64);
    a1 += __shfl_xor(a1, 16, 64); a1 += __shfl_xor(a1, 32, 64);
    a2 += __shfl_xor(a2, 16, 64); a2 += __shfl_xor(a2, 32, 64);
    a3 += __shfl_xor(a3, 16, 64); a3 += __shfl_xor(a3, 32, 64);
    if (q == 0) {
        int f = c * 4;
        long o = (long)wid * HID + f;
        const float4 bv = *reinterpret_cast<const float4*>(&b[f]);
        uint2 rv = *reinterpret_cast<const uint2*>(&resb[o]);
        float w0 = fmaxf(a0 + bv.x, 0.f) + bf16lo_f(rv.x);
        float w1 = fmaxf(a1 + bv.y, 0.f) + bf16hi_f(rv.x);
        float w2 = fmaxf(a2 + bv.z, 0.f) + bf16lo_f(rv.y);
        float w3 = fmaxf(a3 + bv.w, 0.f) + bf16hi_f(rv.y);
        uint2 ov;
        ov.x = (unsigned)f32_to_bf16_rne(w0) | ((unsigned)f32_to_bf16_rne(w1) << 16);
        ov.y = (unsigned)f32_to_bf16_rne(w2) | ((unsigned)f32_to_bf16_rne(w3) << 16);
        *reinterpret_cast<uint2*>(&xoutb[o]) = ov;
    }
}

// ---- pooling gather over bf16 x: one wave/graph, binary search range
__global__ void pool_gather_kernel(const unsigned short* __restrict__ x,
                                   const int* __restrict__ gid,
                                   float* __restrict__ g,
                                   int n_graphs) {
    int wid = (blockIdx.x * blockDim.x + threadIdx.x) >> 6;
    int lane = threadIdx.x & 63;
    if (wid >= n_graphs) return;
    int lo = 0, hi = N_NODES;
    while (lo < hi) { int mid = (lo + hi) >> 1; if (gid[mid] < wid) lo = mid + 1; else hi = mid; }
    int start = lo;
    hi = N_NODES;
    while (lo < hi) { int mid = (lo + hi) >> 1; if (gid[mid] < wid + 1) lo = mid + 1; else hi = mid; }
    int end = lo;
    float acc = 0.f;
    for (int n = start; n < end; ++n)
        acc += __uint_as_float((unsigned)x[(long)n * HID + lane] << 16);
    g[(long)wid * HID + lane] = acc;
}

// ---- MLP: one wave per graph. out = relu(g@Wm1+bm1) @ Wm2 + bm2
__global__ void mlp_kernel(const float* __restrict__ g,
                           const float* __restrict__ Wm1,
                           const float* __restrict__ bm1,
                           const float* __restrict__ Wm2,
                           const float* __restrict__ bm2,
                           float* __restrict__ out,
                           int n_graphs) {
    int wid = (blockIdx.x * blockDim.x + threadIdx.x) >> 6;
    int lane = threadIdx.x & 63;
    if (wid >= n_graphs) return;
    const float* gr = g + (long)wid * HID;
    float h0 = bm1[lane];
    float h1 = bm1[lane + 64];
    for (int k = 0; k < HID; ++k) {
        float gv = gr[k];
        h0 += gv * Wm1[k * MLP_HID + lane];
        h1 += gv * Wm1[k * MLP_HID + lane + 64];
    }
    float part = fmaxf(h0, 0.f) * Wm2[lane] + fmaxf(h1, 0.f) * Wm2[lane + 64];
    #pragma unroll
    for (int off = 32; off > 0; off >>= 1)
        part += __shfl_down(part, off, 64);
    if (lane == 0) out[wid] = part + bm2[0];
}

extern "C" void kernel_launch(void* const* d_in, const int* in_sizes, int n_in,
                              void* d_out, int out_size, void* d_ws, size_t ws_size,
                              hipStream_t stream) {
    const float* feats = (const float*)d_in[0];
    const int*   src   = (const int*)d_in[1];
    const int*   dst   = (const int*)d_in[2];
    const int*   gid   = (const int*)d_in[3];
    const float* W[3]  = {(const float*)d_in[4],  (const float*)d_in[8],  (const float*)d_in[12]};
    const float* b[3]  = {(const float*)d_in[5],  (const float*)d_in[9],  (const float*)d_in[13]};
    const float* R[3]  = {(const float*)d_in[6],  (const float*)d_in[10], (const float*)d_in[14]};
    const float* rb[3] = {(const float*)d_in[7],  (const float*)d_in[11], (const float*)d_in[15]};
    const float* Wm1 = (const float*)d_in[16];
    const float* bm1 = (const float*)d_in[17];
    const float* Wm2 = (const float*)d_in[18];
    const float* bm2 = (const float*)d_in[19];
    float* out = (float*)d_out;

    // workspace carve
    char* ws = (char*)d_ws;
    const size_t node_bf16 = (size_t)N_NODES * HID * sizeof(unsigned short);  // 12.8 MB
    unsigned short* xbufb     = (unsigned short*)(ws); ws += node_bf16;
    unsigned short* xwb       = (unsigned short*)(ws); ws += node_bf16;
    unsigned short* resb      = (unsigned short*)(ws); ws += node_bf16;
    float*          gbuf      = (float*)(ws);          ws += (size_t)N_GRAPHS * HID * sizeof(float);
    int*            cursor    = (int*)(ws);            ws += (size_t)NBUCKET * sizeof(int);
    int*            row_start = (int*)(ws);            ws += (size_t)N_NODES * sizeof(int);
    int*            row_deg   = (int*)(ws);            ws += (size_t)N_NODES * sizeof(int);
    int*            blockHist = (int*)(ws);            ws += (size_t)NBUCKET * NBLK * sizeof(int);  // 800 KB
    unsigned short* wtbuf     = (unsigned short*)(ws); ws += (size_t)(2 * SZ0 + 4 * SZ12) * sizeof(unsigned short);
    ws = (char*)(((size_t)ws + 255) & ~(size_t)255);
    unsigned*       pairs     = (unsigned*)(ws);       ws += (size_t)NBUCKET * BUCKET_CAP * sizeof(unsigned); // 25.6 MB

    // ---- one-time weight transpose/quantize + bucketed CSR build
    prep_wt_kernel<<<6, 256, 0, stream>>>(W[0], R[0], W[1], R[1], W[2], R[2], wtbuf);
    split_hist_kernel<<<NBLK, SPLIT_THREADS, 0, stream>>>(dst, blockHist);
    split_scan_kernel<<<NBUCKET, NBLK, 0, stream>>>(blockHist, cursor);
    split_scatter_kernel<<<NBLK, SPLIT_THREADS, 0, stream>>>(src, dst, blockHist, pairs);
    bucket_sort_kernel<<<NBUCKET, 256, 0, stream>>>(pairs, cursor, row_start, row_deg);

    const unsigned short* wt_l[3] = {wtbuf, wtbuf + 2 * SZ0, wtbuf + 2 * SZ0 + 2 * SZ12};

    for (int l = 0; l < 3; ++l) {
        {
            int blocks = (N_NODES + 63) / 64;     // 64 nodes per block
            if (l == 0)
                proj_mfma_kernel<IN_DIM, 96, STRIDE0, false><<<blocks, 256, 0, stream>>>(
                    (const void*)feats, wt_l[l], rb[l], xwb, resb, N_NODES);
            else
                proj_mfma_kernel<HID, 64, STRIDE12, true><<<blocks, 256, 0, stream>>>(
                    (const void*)xbufb, wt_l[l], rb[l], xwb, resb, N_NODES);
        }
        {
            int blocks = (N_NODES * 64 + 255) / 256;  // one wave per node
            gather_kernel<<<blocks, 256, 0, stream>>>((const uint2*)xwb, row_start, row_deg,
                                                      pairs, b[l], resb, xbufb, N_NODES);
        }
    }

    // pooling
    {
        int threads = N_GRAPHS * 64;
        pool_gather_kernel<<<(threads + 255) / 256, 256, 0, stream>>>(xbufb, gid, gbuf, N_GRAPHS);
    }
    // MLP
    {
        int threads = N_GRAPHS * 64;
        mlp_kernel<<<(threads + 255) / 256, 256, 0, stream>>>(gbuf, Wm1, bm1, Wm2, bm2, out, N_GRAPHS);
    }
}

// Round 13
// 347.158 us; speedup vs baseline: 15.3158x; 1.0085x over previous
//
#include <hip/hip_runtime.h>

#define N_NODES 100000
#define N_EDGES 3200000
#define N_GRAPHS 4096
#define IN_DIM 74
#define HID 64
#define MLP_HID 128

#define BKT_NODES 128                 // nodes per bucket
#define NBUCKET ((N_NODES + BKT_NODES - 1) / BKT_NODES)   // 782
#define BUCKET_CAP 8192               // edges capacity per bucket (mean ~4096)
#define NBLK 256                      // split blocks (long per-bucket runs = full 64B lines)
#define SPLIT_THREADS 1024            // fat blocks for occupancy
#define CHUNK ((N_EDGES + NBLK - 1) / NBLK)               // 12500

// prep'd weight layout sizes (bf16, transposed [feat][k], padded stride)
#define STRIDE0 104                   // layer0: KPAD=96, stride 104
#define STRIDE12 72                   // layers 1,2: KPAD=64, stride 72
#define SZ0 (64 * STRIDE0)
#define SZ12 (64 * STRIDE12)

typedef __attribute__((ext_vector_type(8))) short bf16x8;
typedef __attribute__((ext_vector_type(4))) float f32x4;

__device__ __forceinline__ unsigned short f32_to_bf16_rne(float f) {
    unsigned u = __float_as_uint(f);
    unsigned r = (u + 0x7FFFu + ((u >> 16) & 1u)) >> 16;
    return (unsigned short)r;
}
__device__ __forceinline__ float bf16u_f(unsigned short u) {
    return __uint_as_float((unsigned)u << 16);
}

// ---- one-time weight prep: Wt[l][feat][k] = bf16(W_l[k][feat]), zero-padded.
__global__ void prep_wt_kernel(const float* __restrict__ W0, const float* __restrict__ R0,
                               const float* __restrict__ W1, const float* __restrict__ R1,
                               const float* __restrict__ W2, const float* __restrict__ R2,
                               unsigned short* __restrict__ wtbuf) {
    const float* srcs[6] = {W0, R0, W1, R1, W2, R2};
    int id = blockIdx.x;
    int l = id >> 1, isR = id & 1;
    const float* src = srcs[id];
    int IN = (l == 0) ? IN_DIM : HID;
    int STRIDE = (l == 0) ? STRIDE0 : STRIDE12;
    int base = (l == 0 ? 0 : 2 * SZ0 + (l - 1) * 2 * SZ12) + isR * (l == 0 ? SZ0 : SZ12);
    int total = 64 * STRIDE;
    for (int i = threadIdx.x; i < total; i += 256) {
        int n = i / STRIDE, k = i - n * STRIDE;
        wtbuf[base + i] = (k < IN) ? f32_to_bf16_rne(src[k * HID + n]) : 0;
    }
}

// ---- projection via MFMA: xq(i8, per-node scale) = x@W ; res(bf16) = relu(x@R+rb).
// xq row layout: dword c holds feats {c, c+16, c+32, c+48} as 4 signed bytes.
template<int IN, int KPAD, int STRIDE, bool BF16IN>
__launch_bounds__(256)
__global__ void proj_mfma_kernel(const void* __restrict__ x,
                                 const unsigned short* __restrict__ wt_layer, // W then R
                                 const float* __restrict__ rb,
                                 unsigned* __restrict__ xq,       // 16 dwords/node
                                 float* __restrict__ xscale,      // 1 f32/node
                                 unsigned short* __restrict__ resb,
                                 int n_nodes) {
    __shared__ __align__(16) unsigned short xs[64 * STRIDE];
    __shared__ __align__(16) unsigned short wt[64 * STRIDE];
    __shared__ __align__(16) unsigned short rt[64 * STRIDE];
    int n0 = blockIdx.x * 64;
    int tid = threadIdx.x;

    {
        const uint4* gw = reinterpret_cast<const uint4*>(wt_layer);
        const uint4* gr = reinterpret_cast<const uint4*>(wt_layer + 64 * STRIDE);
        uint4* sw = reinterpret_cast<uint4*>(wt);
        uint4* sr = reinterpret_cast<uint4*>(rt);
        const int cnt = 64 * STRIDE / 8;
        for (int i = tid; i < cnt; i += 256) { sw[i] = gw[i]; sr[i] = gr[i]; }
    }
    if (!BF16IN) {
        const float* xf = (const float*)x;
        for (int i = tid; i < 64 * STRIDE; i += 256) {
            int row = i / STRIDE, col = i - row * STRIDE;
            int n = n0 + row;
            float v = (col < IN && n < n_nodes) ? xf[(long)n * IN + col] : 0.f;
            xs[i] = f32_to_bf16_rne(v);
        }
    } else {
        const uint4* xb = (const uint4*)x;
        for (int i = tid; i < 64 * 8; i += 256) {
            int row = i >> 3, c8 = (i & 7) << 3;
            int n = n0 + row;
            uint4 v = make_uint4(0, 0, 0, 0);
            if (n < n_nodes) v = xb[(long)n * 8 + (i & 7)];
            *reinterpret_cast<uint4*>(&xs[row * STRIDE + c8]) = v;
        }
    }
    __syncthreads();

    int w = tid >> 6, lane = tid & 63;
    int nb = w * 16;
    int rc = lane & 15;        // A row / B col / D col
    int kg = lane >> 4;        // k-chunk of 8

    f32x4 accW[4], accR[4];
    #pragma unroll
    for (int fg = 0; fg < 4; ++fg) { accW[fg] = {0.f, 0.f, 0.f, 0.f}; accR[fg] = {0.f, 0.f, 0.f, 0.f}; }

    #pragma unroll
    for (int ks = 0; ks < KPAD / 32; ++ks) {
        int k0 = ks * 32 + kg * 8;
        bf16x8 a = *reinterpret_cast<const bf16x8*>(&xs[(nb + rc) * STRIDE + k0]);
        #pragma unroll
        for (int fg = 0; fg < 4; ++fg) {
            bf16x8 bw = *reinterpret_cast<const bf16x8*>(&wt[(fg * 16 + rc) * STRIDE + k0]);
            accW[fg] = __builtin_amdgcn_mfma_f32_16x16x32_bf16(a, bw, accW[fg], 0, 0, 0);
            bf16x8 br = *reinterpret_cast<const bf16x8*>(&rt[(fg * 16 + rc) * STRIDE + k0]);
            accR[fg] = __builtin_amdgcn_mfma_f32_16x16x32_bf16(a, br, accR[fg], 0, 0, 0);
        }
    }

    // D: col = lane&15, row = (lane>>4)*4 + reg. All 16 lanes of a quarter share
    // the same node for fixed r, so quarter-local shfl max gives the row max.
    #pragma unroll
    for (int r = 0; r < 4; ++r) {
        float m = fmaxf(fmaxf(fabsf(accW[0][r]), fabsf(accW[1][r])),
                        fmaxf(fabsf(accW[2][r]), fabsf(accW[3][r])));
        m = fmaxf(m, __shfl_xor(m, 1, 64));
        m = fmaxf(m, __shfl_xor(m, 2, 64));
        m = fmaxf(m, __shfl_xor(m, 4, 64));
        m = fmaxf(m, __shfl_xor(m, 8, 64));
        float inv = (m > 0.f) ? 127.f / m : 0.f;
        int node = n0 + nb + kg * 4 + r;
        if (node < n_nodes) {
            unsigned pack = 0;
            #pragma unroll
            for (int fg = 0; fg < 4; ++fg) {
                int qv = (int)rintf(accW[fg][r] * inv);
                pack |= ((unsigned)(qv & 0xFF)) << (8 * fg);
            }
            xq[(long)node * 16 + rc] = pack;
            if (rc == 0) xscale[node] = m * (1.f / 127.f);
        }
    }
    #pragma unroll
    for (int fg = 0; fg < 4; ++fg) {
        int feat = fg * 16 + rc;
        float rbv = rb[feat];
        #pragma unroll
        for (int r = 0; r < 4; ++r) {
            int node = n0 + nb + kg * 4 + r;
            if (node < n_nodes)
                resb[(long)node * HID + feat] = f32_to_bf16_rne(fmaxf(accR[fg][r] + rbv, 0.f));
        }
    }
}

// ---- split pass 1: per-block LDS histogram of dst buckets
__launch_bounds__(SPLIT_THREADS)
__global__ void split_hist_kernel(const int* __restrict__ dst,
                                  int* __restrict__ blockHist /*[NBUCKET][NBLK]*/) {
    __shared__ int h[NBUCKET];
    int blk = blockIdx.x, tid = threadIdx.x;
    for (int i = tid; i < NBUCKET; i += SPLIT_THREADS) h[i] = 0;
    __syncthreads();
    int lo = blk * CHUNK;
    int hi = lo + CHUNK; if (hi > N_EDGES) hi = N_EDGES;
    for (int e = lo + tid; e < hi; e += SPLIT_THREADS)
        atomicAdd(&h[dst[e] >> 7], 1);
    __syncthreads();
    for (int i = tid; i < NBUCKET; i += SPLIT_THREADS)
        blockHist[i * NBLK + blk] = h[i];
}

// ---- split pass 2: per-bucket exclusive scan over the NBLK block counts.
__launch_bounds__(NBLK)
__global__ void split_scan_kernel(int* __restrict__ blockHist,
                                  int* __restrict__ cursor) {
    __shared__ int s[NBLK];
    int bkt = blockIdx.x, tid = threadIdx.x;
    int v = blockHist[bkt * NBLK + tid];
    s[tid] = v;
    __syncthreads();
    for (int off = 1; off < NBLK; off <<= 1) {
        int t = (tid >= off) ? s[tid - off] : 0;
        __syncthreads();
        s[tid] += t;
        __syncthreads();
    }
    blockHist[bkt * NBLK + tid] = bkt * BUCKET_CAP + s[tid] - v;   // exclusive
    if (tid == NBLK - 1) cursor[bkt] = bkt * BUCKET_CAP + s[tid]; // total end
}

// ---- split pass 3: scatter to exact positions (LDS cursors)
__launch_bounds__(SPLIT_THREADS)
__global__ void split_scatter_kernel(const int* __restrict__ src,
                                     const int* __restrict__ dst,
                                     const int* __restrict__ blockHist,
                                     unsigned* __restrict__ pairs) {
    __shared__ int cur[NBUCKET];
    int blk = blockIdx.x, tid = threadIdx.x;
    for (int i = tid; i < NBUCKET; i += SPLIT_THREADS)
        cur[i] = blockHist[i * NBLK + blk];
    __syncthreads();
    int lo = blk * CHUNK;
    int hi = lo + CHUNK; if (hi > N_EDGES) hi = N_EDGES;
    for (int e = lo + tid; e < hi; e += SPLIT_THREADS) {
        int d = dst[e];
        int b = d >> 7;
        int pos = atomicAdd(&cur[b], 1);
        pairs[pos] = (unsigned)src[e] | ((unsigned)(d & (BKT_NODES - 1)) << 17);
    }
}

// ---- per-bucket LDS counting sort -> src sorted by dst_local; row_start/row_deg
__launch_bounds__(256)
__global__ void bucket_sort_kernel(unsigned* __restrict__ pairs,
                                   const int* __restrict__ cursor,
                                   int* __restrict__ row_start,
                                   int* __restrict__ row_deg) {
    __shared__ unsigned stage[BUCKET_CAP];   // 32 KB
    __shared__ int hist[BKT_NODES];
    __shared__ int offs[BKT_NODES];
    __shared__ int cur[BKT_NODES];
    int bkt = blockIdx.x;
    int tid = threadIdx.x;
    int base = bkt * BUCKET_CAP;
    int cnt = cursor[bkt] - base;

    for (int i = tid; i < BKT_NODES; i += 256) hist[i] = 0;
    __syncthreads();
    for (int e = tid; e < cnt; e += 256) {
        unsigned p = pairs[base + e];
        stage[e] = p;
        atomicAdd(&hist[p >> 17], 1);
    }
    __syncthreads();
    if (tid < BKT_NODES) offs[tid] = hist[tid];
    __syncthreads();
    for (int s = 1; s < BKT_NODES; s <<= 1) {
        int v = (tid < BKT_NODES && tid >= s) ? offs[tid - s] : 0;
        __syncthreads();
        if (tid < BKT_NODES) offs[tid] += v;
        __syncthreads();
    }
    if (tid < BKT_NODES) {
        int ex = offs[tid] - hist[tid];
        cur[tid] = ex;
        int node = bkt * BKT_NODES + tid;
        if (node < N_NODES) {
            row_start[node] = base + ex;
            row_deg[node] = hist[tid];
        }
    }
    __syncthreads();
    for (int e = tid; e < cnt; e += 256) {
        unsigned p = stage[e];
        int pos = atomicAdd(&cur[p >> 17], 1);
        pairs[base + pos] = p & 0x1FFFF;   // store src only
    }
}

// ---- gather aggregation + epilogue over i8 xq (per-node scale); res/xout bf16.
// One wave per node; 4 edges per step (quarter-wave each); lane reads one dword
// = feats {c, c+16, c+32, c+48}; f32 accumulate; shfl_xor(16,32) merges quarters.
__global__ void gather_kernel(const unsigned* __restrict__ xq,   // 16 dwords/node
                              const float* __restrict__ xscale,
                              const int* __restrict__ row_start,
                              const int* __restrict__ row_deg,
                              const unsigned* __restrict__ csr_src,
                              const float* __restrict__ b,
                              const unsigned short* __restrict__ resb,
                              unsigned short* __restrict__ xoutb,
                              int n_nodes) {
    int wid = (blockIdx.x * blockDim.x + threadIdx.x) >> 6;
    int lane = threadIdx.x & 63;
    if (wid >= n_nodes) return;
    int c = lane & 15;
    int q = lane >> 4;
    int start = row_start[wid];
    int end = start + row_deg[wid];
    float a0 = 0.f, a1 = 0.f, a2 = 0.f, a3 = 0.f;
    int e = start;
    for (; e + 16 <= end; e += 16) {
        unsigned s0 = csr_src[e + q];
        unsigned s1 = csr_src[e + q + 4];
        unsigned s2 = csr_src[e + q + 8];
        unsigned s3 = csr_src[e + q + 12];
        unsigned v0 = xq[s0 * 16 + c]; float c0 = xscale[s0];
        unsigned v1 = xq[s1 * 16 + c]; float c1 = xscale[s1];
        unsigned v2 = xq[s2 * 16 + c]; float c2 = xscale[s2];
        unsigned v3 = xq[s3 * 16 + c]; float c3 = xscale[s3];
        a0 = fmaf((float)((int)(v0 << 24) >> 24), c0, a0);
        a1 = fmaf((float)((int)(v0 << 16) >> 24), c0, a1);
        a2 = fmaf((float)((int)(v0 <<  8) >> 24), c0, a2);
        a3 = fmaf((float)((int) v0        >> 24), c0, a3);
        a0 = fmaf((float)((int)(v1 << 24) >> 24), c1, a0);
        a1 = fmaf((float)((int)(v1 << 16) >> 24), c1, a1);
        a2 = fmaf((float)((int)(v1 <<  8) >> 24), c1, a2);
        a3 = fmaf((float)((int) v1        >> 24), c1, a3);
        a0 = fmaf((float)((int)(v2 << 24) >> 24), c2, a0);
        a1 = fmaf((float)((int)(v2 << 16) >> 24), c2, a1);
        a2 = fmaf((float)((int)(v2 <<  8) >> 24), c2, a2);
        a3 = fmaf((float)((int) v2        >> 24), c2, a3);
        a0 = fmaf((float)((int)(v3 << 24) >> 24), c3, a0);
        a1 = fmaf((float)((int)(v3 << 16) >> 24), c3, a1);
        a2 = fmaf((float)((int)(v3 <<  8) >> 24), c3, a2);
        a3 = fmaf((float)((int) v3        >> 24), c3, a3);
    }
    for (; e + 4 <= end; e += 4) {
        unsigned s = csr_src[e + q];
        unsigned v = xq[s * 16 + c]; float cs = xscale[s];
        a0 = fmaf((float)((int)(v << 24) >> 24), cs, a0);
        a1 = fmaf((float)((int)(v << 16) >> 24), cs, a1);
        a2 = fmaf((float)((int)(v <<  8) >> 24), cs, a2);
        a3 = fmaf((float)((int) v        >> 24), cs, a3);
    }
    if (e < end && q < end - e) {
        unsigned s = csr_src[e + q];
        unsigned v = xq[s * 16 + c]; float cs = xscale[s];
        a0 = fmaf((float)((int)(v << 24) >> 24), cs, a0);
        a1 = fmaf((float)((int)(v << 16) >> 24), cs, a1);
        a2 = fmaf((float)((int)(v <<  8) >> 24), cs, a2);
        a3 = fmaf((float)((int) v        >> 24), cs, a3);
    }
    a0 += __shfl_xor(a0, 16, 64); a0 += __shfl_xor(a0, 32, 64);
    a1 += __shfl_xor(a1, 16, 64); a1 += __shfl_xor(a1, 32, 64);
    a2 += __shfl_xor(a2, 16, 64); a2 += __shfl_xor(a2, 32, 64);
    a3 += __shfl_xor(a3, 16, 64); a3 += __shfl_xor(a3, 32, 64);
    if (q == 0) {
        long o = (long)wid * HID;
        float w0 = fmaxf(a0 + b[c],      0.f) + bf16u_f(resb[o + c]);
        float w1 = fmaxf(a1 + b[c + 16], 0.f) + bf16u_f(resb[o + c + 16]);
        float w2 = fmaxf(a2 + b[c + 32], 0.f) + bf16u_f(resb[o + c + 32]);
        float w3 = fmaxf(a3 + b[c + 48], 0.f) + bf16u_f(resb[o + c + 48]);
        xoutb[o + c]      = f32_to_bf16_rne(w0);
        xoutb[o + c + 16] = f32_to_bf16_rne(w1);
        xoutb[o + c + 32] = f32_to_bf16_rne(w2);
        xoutb[o + c + 48] = f32_to_bf16_rne(w3);
    }
}

// ---- pooling gather over bf16 x: one wave/graph, binary search range
__global__ void pool_gather_kernel(const unsigned short* __restrict__ x,
                                   const int* __restrict__ gid,
                                   float* __restrict__ g,
                                   int n_graphs) {
    int wid = (blockIdx.x * blockDim.x + threadIdx.x) >> 6;
    int lane = threadIdx.x & 63;
    if (wid >= n_graphs) return;
    int lo = 0, hi = N_NODES;
    while (lo < hi) { int mid = (lo + hi) >> 1; if (gid[mid] < wid) lo = mid + 1; else hi = mid; }
    int start = lo;
    hi = N_NODES;
    while (lo < hi) { int mid = (lo + hi) >> 1; if (gid[mid] < wid + 1) lo = mid + 1; else hi = mid; }
    int end = lo;
    float acc = 0.f;
    for (int n = start; n < end; ++n)
        acc += bf16u_f(x[(long)n * HID + lane]);
    g[(long)wid * HID + lane] = acc;
}

// ---- MLP: one wave per graph. out = relu(g@Wm1+bm1) @ Wm2 + bm2
__global__ void mlp_kernel(const float* __restrict__ g,
                           const float* __restrict__ Wm1,
                           const float* __restrict__ bm1,
                           const float* __restrict__ Wm2,
                           const float* __restrict__ bm2,
                           float* __restrict__ out,
                           int n_graphs) {
    int wid = (blockIdx.x * blockDim.x + threadIdx.x) >> 6;
    int lane = threadIdx.x & 63;
    if (wid >= n_graphs) return;
    const float* gr = g + (long)wid * HID;
    float h0 = bm1[lane];
    float h1 = bm1[lane + 64];
    for (int k = 0; k < HID; ++k) {
        float gv = gr[k];
        h0 += gv * Wm1[k * MLP_HID + lane];
        h1 += gv * Wm1[k * MLP_HID + lane + 64];
    }
    float part = fmaxf(h0, 0.f) * Wm2[lane] + fmaxf(h1, 0.f) * Wm2[lane + 64];
    #pragma unroll
    for (int off = 32; off > 0; off >>= 1)
        part += __shfl_down(part, off, 64);
    if (lane == 0) out[wid] = part + bm2[0];
}

extern "C" void kernel_launch(void* const* d_in, const int* in_sizes, int n_in,
                              void* d_out, int out_size, void* d_ws, size_t ws_size,
                              hipStream_t stream) {
    const float* feats = (const float*)d_in[0];
    const int*   src   = (const int*)d_in[1];
    const int*   dst   = (const int*)d_in[2];
    const int*   gid   = (const int*)d_in[3];
    const float* W[3]  = {(const float*)d_in[4],  (const float*)d_in[8],  (const float*)d_in[12]};
    const float* b[3]  = {(const float*)d_in[5],  (const float*)d_in[9],  (const float*)d_in[13]};
    const float* R[3]  = {(const float*)d_in[6],  (const float*)d_in[10], (const float*)d_in[14]};
    const float* rb[3] = {(const float*)d_in[7],  (const float*)d_in[11], (const float*)d_in[15]};
    const float* Wm1 = (const float*)d_in[16];
    const float* bm1 = (const float*)d_in[17];
    const float* Wm2 = (const float*)d_in[18];
    const float* bm2 = (const float*)d_in[19];
    float* out = (float*)d_out;

    // workspace carve
    char* ws = (char*)d_ws;
    const size_t node_bf16 = (size_t)N_NODES * HID * sizeof(unsigned short);  // 12.8 MB
    unsigned short* xbufb     = (unsigned short*)(ws); ws += node_bf16;
    unsigned*       xq        = (unsigned*)(ws);       ws += (size_t)N_NODES * 16 * sizeof(unsigned); // 6.4 MB
    float*          xscale    = (float*)(ws);          ws += (size_t)N_NODES * sizeof(float);         // 400 KB
    unsigned short* resb      = (unsigned short*)(ws); ws += node_bf16;
    float*          gbuf      = (float*)(ws);          ws += (size_t)N_GRAPHS * HID * sizeof(float);
    int*            cursor    = (int*)(ws);            ws += (size_t)NBUCKET * sizeof(int);
    int*            row_start = (int*)(ws);            ws += (size_t)N_NODES * sizeof(int);
    int*            row_deg   = (int*)(ws);            ws += (size_t)N_NODES * sizeof(int);
    int*            blockHist = (int*)(ws);            ws += (size_t)NBUCKET * NBLK * sizeof(int);  // 800 KB
    unsigned short* wtbuf     = (unsigned short*)(ws); ws += (size_t)(2 * SZ0 + 4 * SZ12) * sizeof(unsigned short);
    ws = (char*)(((size_t)ws + 255) & ~(size_t)255);
    unsigned*       pairs     = (unsigned*)(ws);       ws += (size_t)NBUCKET * BUCKET_CAP * sizeof(unsigned); // 25.6 MB

    // ---- one-time weight transpose/quantize + bucketed CSR build
    prep_wt_kernel<<<6, 256, 0, stream>>>(W[0], R[0], W[1], R[1], W[2], R[2], wtbuf);
    split_hist_kernel<<<NBLK, SPLIT_THREADS, 0, stream>>>(dst, blockHist);
    split_scan_kernel<<<NBUCKET, NBLK, 0, stream>>>(blockHist, cursor);
    split_scatter_kernel<<<NBLK, SPLIT_THREADS, 0, stream>>>(src, dst, blockHist, pairs);
    bucket_sort_kernel<<<NBUCKET, 256, 0, stream>>>(pairs, cursor, row_start, row_deg);

    const unsigned short* wt_l[3] = {wtbuf, wtbuf + 2 * SZ0, wtbuf + 2 * SZ0 + 2 * SZ12};

    for (int l = 0; l < 3; ++l) {
        {
            int blocks = (N_NODES + 63) / 64;     // 64 nodes per block
            if (l == 0)
                proj_mfma_kernel<IN_DIM, 96, STRIDE0, false><<<blocks, 256, 0, stream>>>(
                    (const void*)feats, wt_l[l], rb[l], xq, xscale, resb, N_NODES);
            else
                proj_mfma_kernel<HID, 64, STRIDE12, true><<<blocks, 256, 0, stream>>>(
                    (const void*)xbufb, wt_l[l], rb[l], xq, xscale, resb, N_NODES);
        }
        {
            int blocks = (N_NODES * 64 + 255) / 256;  // one wave per node
            gather_kernel<<<blocks, 256, 0, stream>>>(xq, xscale, row_start, row_deg,
                                                      pairs, b[l], resb, xbufb, N_NODES);
        }
    }

    // pooling
    {
        int threads = N_GRAPHS * 64;
        pool_gather_kernel<<<(threads + 255) / 256, 256, 0, stream>>>(xbufb, gid, gbuf, N_GRAPHS);
    }
    // MLP
    {
        int threads = N_GRAPHS * 64;
        mlp_kernel<<<(threads + 255) / 256, 256, 0, stream>>>(gbuf, Wm1, bm1, Wm2, bm2, out, N_GRAPHS);
    }
}

// Round 14
// 342.339 us; speedup vs baseline: 15.5314x; 1.0141x over previous
//
#include <hip/hip_runtime.h>

#define N_NODES 100000
#define N_EDGES 3200000
#define N_GRAPHS 4096
#define IN_DIM 74
#define HID 64
#define MLP_HID 128

#define BKT_NODES 128                 // nodes per bucket
#define NBUCKET ((N_NODES + BKT_NODES - 1) / BKT_NODES)   // 782
#define BUCKET_CAP 8192               // edges capacity per bucket (mean ~4096)
#define NBLK 256                      // split blocks (long per-bucket runs)
#define SPLIT_THREADS 1024            // fat blocks for occupancy
#define CHUNK ((N_EDGES + NBLK - 1) / NBLK)               // 12500 (N_EDGES = NBLK*CHUNK exactly)

// prep'd weight layout sizes (bf16, transposed [feat][k], padded stride)
#define STRIDE0 104                   // layer0: KPAD=96, stride 104
#define STRIDE12 72                   // layers 1,2: KPAD=64, stride 72
#define SZ0 (64 * STRIDE0)
#define SZ12 (64 * STRIDE12)

typedef __attribute__((ext_vector_type(8))) short bf16x8;
typedef __attribute__((ext_vector_type(4))) float f32x4;

__device__ __forceinline__ unsigned short f32_to_bf16_rne(float f) {
    unsigned u = __float_as_uint(f);
    unsigned r = (u + 0x7FFFu + ((u >> 16) & 1u)) >> 16;
    return (unsigned short)r;
}
__device__ __forceinline__ float bf16u_f(unsigned short u) {
    return __uint_as_float((unsigned)u << 16);
}

// accumulate 8 int8 feats (one uint2) scaled by s into a0..a7
#define ACC8(v, s) do { \
    a0 = fmaf((float)((int)((v).x << 24) >> 24), (s), a0); \
    a1 = fmaf((float)((int)((v).x << 16) >> 24), (s), a1); \
    a2 = fmaf((float)((int)((v).x <<  8) >> 24), (s), a2); \
    a3 = fmaf((float)((int)(v).x        >> 24), (s), a3); \
    a4 = fmaf((float)((int)((v).y << 24) >> 24), (s), a4); \
    a5 = fmaf((float)((int)((v).y << 16) >> 24), (s), a5); \
    a6 = fmaf((float)((int)((v).y <<  8) >> 24), (s), a6); \
    a7 = fmaf((float)((int)(v).y        >> 24), (s), a7); \
} while (0)

// ---- one-time weight prep: Wt[l][feat][k] = bf16(W_l[k][feat]), zero-padded.
__global__ void prep_wt_kernel(const float* __restrict__ W0, const float* __restrict__ R0,
                               const float* __restrict__ W1, const float* __restrict__ R1,
                               const float* __restrict__ W2, const float* __restrict__ R2,
                               unsigned short* __restrict__ wtbuf) {
    const float* srcs[6] = {W0, R0, W1, R1, W2, R2};
    int id = blockIdx.x;
    int l = id >> 1, isR = id & 1;
    const float* src = srcs[id];
    int IN = (l == 0) ? IN_DIM : HID;
    int STRIDE = (l == 0) ? STRIDE0 : STRIDE12;
    int base = (l == 0 ? 0 : 2 * SZ0 + (l - 1) * 2 * SZ12) + isR * (l == 0 ? SZ0 : SZ12);
    int total = 64 * STRIDE;
    for (int i = threadIdx.x; i < total; i += 256) {
        int n = i / STRIDE, k = i - n * STRIDE;
        wtbuf[base + i] = (k < IN) ? f32_to_bf16_rne(src[k * HID + n]) : 0;
    }
}

// ---- projection via MFMA: xq(i8, per-node scale) = x@W ; res(bf16) = relu(x@R+rb).
// xq row layout: dword c holds feats {c, c+16, c+32, c+48} as 4 signed bytes.
template<int IN, int KPAD, int STRIDE, bool BF16IN>
__launch_bounds__(256)
__global__ void proj_mfma_kernel(const void* __restrict__ x,
                                 const unsigned short* __restrict__ wt_layer, // W then R
                                 const float* __restrict__ rb,
                                 unsigned* __restrict__ xq,       // 16 dwords/node
                                 float* __restrict__ xscale,      // 1 f32/node
                                 unsigned short* __restrict__ resb,
                                 int n_nodes) {
    __shared__ __align__(16) unsigned short xs[64 * STRIDE];
    __shared__ __align__(16) unsigned short wt[64 * STRIDE];
    __shared__ __align__(16) unsigned short rt[64 * STRIDE];
    int n0 = blockIdx.x * 64;
    int tid = threadIdx.x;

    {
        const uint4* gw = reinterpret_cast<const uint4*>(wt_layer);
        const uint4* gr = reinterpret_cast<const uint4*>(wt_layer + 64 * STRIDE);
        uint4* sw = reinterpret_cast<uint4*>(wt);
        uint4* sr = reinterpret_cast<uint4*>(rt);
        const int cnt = 64 * STRIDE / 8;
        for (int i = tid; i < cnt; i += 256) { sw[i] = gw[i]; sr[i] = gr[i]; }
    }
    if (!BF16IN) {
        const float* xf = (const float*)x;
        for (int i = tid; i < 64 * STRIDE; i += 256) {
            int row = i / STRIDE, col = i - row * STRIDE;
            int n = n0 + row;
            float v = (col < IN && n < n_nodes) ? xf[(long)n * IN + col] : 0.f;
            xs[i] = f32_to_bf16_rne(v);
        }
    } else {
        const uint4* xb = (const uint4*)x;
        for (int i = tid; i < 64 * 8; i += 256) {
            int row = i >> 3, c8 = (i & 7) << 3;
            int n = n0 + row;
            uint4 v = make_uint4(0, 0, 0, 0);
            if (n < n_nodes) v = xb[(long)n * 8 + (i & 7)];
            *reinterpret_cast<uint4*>(&xs[row * STRIDE + c8]) = v;
        }
    }
    __syncthreads();

    int w = tid >> 6, lane = tid & 63;
    int nb = w * 16;
    int rc = lane & 15;        // A row / B col / D col
    int kg = lane >> 4;        // k-chunk of 8

    f32x4 accW[4], accR[4];
    #pragma unroll
    for (int fg = 0; fg < 4; ++fg) { accW[fg] = {0.f, 0.f, 0.f, 0.f}; accR[fg] = {0.f, 0.f, 0.f, 0.f}; }

    #pragma unroll
    for (int ks = 0; ks < KPAD / 32; ++ks) {
        int k0 = ks * 32 + kg * 8;
        bf16x8 a = *reinterpret_cast<const bf16x8*>(&xs[(nb + rc) * STRIDE + k0]);
        #pragma unroll
        for (int fg = 0; fg < 4; ++fg) {
            bf16x8 bw = *reinterpret_cast<const bf16x8*>(&wt[(fg * 16 + rc) * STRIDE + k0]);
            accW[fg] = __builtin_amdgcn_mfma_f32_16x16x32_bf16(a, bw, accW[fg], 0, 0, 0);
            bf16x8 br = *reinterpret_cast<const bf16x8*>(&rt[(fg * 16 + rc) * STRIDE + k0]);
            accR[fg] = __builtin_amdgcn_mfma_f32_16x16x32_bf16(a, br, accR[fg], 0, 0, 0);
        }
    }

    // D: col = lane&15, row = (lane>>4)*4 + reg; quarter shares the node.
    #pragma unroll
    for (int r = 0; r < 4; ++r) {
        float m = fmaxf(fmaxf(fabsf(accW[0][r]), fabsf(accW[1][r])),
                        fmaxf(fabsf(accW[2][r]), fabsf(accW[3][r])));
        m = fmaxf(m, __shfl_xor(m, 1, 64));
        m = fmaxf(m, __shfl_xor(m, 2, 64));
        m = fmaxf(m, __shfl_xor(m, 4, 64));
        m = fmaxf(m, __shfl_xor(m, 8, 64));
        float inv = (m > 0.f) ? 127.f / m : 0.f;
        int node = n0 + nb + kg * 4 + r;
        if (node < n_nodes) {
            unsigned pack = 0;
            #pragma unroll
            for (int fg = 0; fg < 4; ++fg) {
                int qv = (int)rintf(accW[fg][r] * inv);
                pack |= ((unsigned)(qv & 0xFF)) << (8 * fg);
            }
            xq[(long)node * 16 + rc] = pack;
            if (rc == 0) xscale[node] = m * (1.f / 127.f);
        }
    }
    #pragma unroll
    for (int fg = 0; fg < 4; ++fg) {
        int feat = fg * 16 + rc;
        float rbv = rb[feat];
        #pragma unroll
        for (int r = 0; r < 4; ++r) {
            int node = n0 + nb + kg * 4 + r;
            if (node < n_nodes)
                resb[(long)node * HID + feat] = f32_to_bf16_rne(fmaxf(accR[fg][r] + rbv, 0.f));
        }
    }
}

// ---- split pass 1: per-block LDS histogram of dst buckets (int4 loads)
__launch_bounds__(SPLIT_THREADS)
__global__ void split_hist_kernel(const int* __restrict__ dst,
                                  int* __restrict__ blockHist /*[NBUCKET][NBLK]*/) {
    __shared__ int h[NBUCKET];
    int blk = blockIdx.x, tid = threadIdx.x;
    for (int i = tid; i < NBUCKET; i += SPLIT_THREADS) h[i] = 0;
    __syncthreads();
    int lo = blk * CHUNK;                      // CHUNK % 4 == 0, 16B-aligned
    for (int e = lo + tid * 4; e < lo + CHUNK; e += SPLIT_THREADS * 4) {
        int4 d4 = *reinterpret_cast<const int4*>(&dst[e]);
        atomicAdd(&h[d4.x >> 7], 1);
        atomicAdd(&h[d4.y >> 7], 1);
        atomicAdd(&h[d4.z >> 7], 1);
        atomicAdd(&h[d4.w >> 7], 1);
    }
    __syncthreads();
    for (int i = tid; i < NBUCKET; i += SPLIT_THREADS)
        blockHist[i * NBLK + blk] = h[i];
}

// ---- split pass 2: per-bucket exclusive scan over the NBLK block counts.
__launch_bounds__(NBLK)
__global__ void split_scan_kernel(int* __restrict__ blockHist,
                                  int* __restrict__ cursor) {
    __shared__ int s[NBLK];
    int bkt = blockIdx.x, tid = threadIdx.x;
    int v = blockHist[bkt * NBLK + tid];
    s[tid] = v;
    __syncthreads();
    for (int off = 1; off < NBLK; off <<= 1) {
        int t = (tid >= off) ? s[tid - off] : 0;
        __syncthreads();
        s[tid] += t;
        __syncthreads();
    }
    blockHist[bkt * NBLK + tid] = bkt * BUCKET_CAP + s[tid] - v;   // exclusive
    if (tid == NBLK - 1) cursor[bkt] = bkt * BUCKET_CAP + s[tid]; // total end
}

// ---- split pass 3: scatter to exact positions (LDS cursors; int4 loads)
__launch_bounds__(SPLIT_THREADS)
__global__ void split_scatter_kernel(const int* __restrict__ src,
                                     const int* __restrict__ dst,
                                     const int* __restrict__ blockHist,
                                     unsigned* __restrict__ pairs) {
    __shared__ int cur[NBUCKET];
    int blk = blockIdx.x, tid = threadIdx.x;
    for (int i = tid; i < NBUCKET; i += SPLIT_THREADS)
        cur[i] = blockHist[i * NBLK + blk];
    __syncthreads();
    int lo = blk * CHUNK;
    for (int e = lo + tid * 4; e < lo + CHUNK; e += SPLIT_THREADS * 4) {
        int4 d4 = *reinterpret_cast<const int4*>(&dst[e]);
        int4 s4 = *reinterpret_cast<const int4*>(&src[e]);
        int p0 = atomicAdd(&cur[d4.x >> 7], 1);
        pairs[p0] = (unsigned)s4.x | ((unsigned)(d4.x & (BKT_NODES - 1)) << 17);
        int p1 = atomicAdd(&cur[d4.y >> 7], 1);
        pairs[p1] = (unsigned)s4.y | ((unsigned)(d4.y & (BKT_NODES - 1)) << 17);
        int p2 = atomicAdd(&cur[d4.z >> 7], 1);
        pairs[p2] = (unsigned)s4.z | ((unsigned)(d4.z & (BKT_NODES - 1)) << 17);
        int p3 = atomicAdd(&cur[d4.w >> 7], 1);
        pairs[p3] = (unsigned)s4.w | ((unsigned)(d4.w & (BKT_NODES - 1)) << 17);
    }
}

// ---- per-bucket LDS counting sort -> src sorted by dst_local; row_start/row_deg
__launch_bounds__(256)
__global__ void bucket_sort_kernel(unsigned* __restrict__ pairs,
                                   const int* __restrict__ cursor,
                                   int* __restrict__ row_start,
                                   int* __restrict__ row_deg) {
    __shared__ unsigned stage[BUCKET_CAP];   // 32 KB
    __shared__ int hist[BKT_NODES];
    __shared__ int offs[BKT_NODES];
    __shared__ int cur[BKT_NODES];
    int bkt = blockIdx.x;
    int tid = threadIdx.x;
    int base = bkt * BUCKET_CAP;
    int cnt = cursor[bkt] - base;

    for (int i = tid; i < BKT_NODES; i += 256) hist[i] = 0;
    __syncthreads();
    for (int e = tid; e < cnt; e += 256) {
        unsigned p = pairs[base + e];
        stage[e] = p;
        atomicAdd(&hist[p >> 17], 1);
    }
    __syncthreads();
    if (tid < BKT_NODES) offs[tid] = hist[tid];
    __syncthreads();
    for (int s = 1; s < BKT_NODES; s <<= 1) {
        int v = (tid < BKT_NODES && tid >= s) ? offs[tid - s] : 0;
        __syncthreads();
        if (tid < BKT_NODES) offs[tid] += v;
        __syncthreads();
    }
    if (tid < BKT_NODES) {
        int ex = offs[tid] - hist[tid];
        cur[tid] = ex;
        int node = bkt * BKT_NODES + tid;
        if (node < N_NODES) {
            row_start[node] = base + ex;
            row_deg[node] = hist[tid];
        }
    }
    __syncthreads();
    for (int e = tid; e < cnt; e += 256) {
        unsigned p = stage[e];
        int pos = atomicAdd(&cur[p >> 17], 1);
        pairs[base + pos] = p & 0x1FFFF;   // store src only
    }
}

// ---- gather aggregation + epilogue over i8 xq; 8 edges per step.
// Eighth-wave per edge: 8 lanes x uint2 cover one 64B row. f32 accumulate;
// shfl_xor(8,16,32) merges the 8 groups.
__global__ void gather_kernel(const uint2* __restrict__ xq2,   // 8 uint2 per node
                              const float* __restrict__ xscale,
                              const int* __restrict__ row_start,
                              const int* __restrict__ row_deg,
                              const unsigned* __restrict__ csr_src,
                              const float* __restrict__ b,
                              const unsigned short* __restrict__ resb,
                              unsigned short* __restrict__ xoutb,
                              int n_nodes) {
    int wid = (blockIdx.x * blockDim.x + threadIdx.x) >> 6;
    int lane = threadIdx.x & 63;
    if (wid >= n_nodes) return;
    int g = lane >> 3;        // edge slot 0..7
    int c2 = lane & 7;        // uint2 index within row
    int start = row_start[wid];
    int end = start + row_deg[wid];
    float a0 = 0.f, a1 = 0.f, a2 = 0.f, a3 = 0.f;
    float a4 = 0.f, a5 = 0.f, a6 = 0.f, a7 = 0.f;
    int e = start;
    for (; e + 16 <= end; e += 16) {
        unsigned s0 = csr_src[e + g];
        unsigned s1 = csr_src[e + 8 + g];
        uint2 v0 = xq2[s0 * 8 + c2]; float c0 = xscale[s0];
        uint2 v1 = xq2[s1 * 8 + c2]; float c1 = xscale[s1];
        ACC8(v0, c0);
        ACC8(v1, c1);
    }
    for (; e + 8 <= end; e += 8) {
        unsigned s = csr_src[e + g];
        uint2 v = xq2[s * 8 + c2]; float cs = xscale[s];
        ACC8(v, cs);
    }
    if (e < end && g < end - e) {
        unsigned s = csr_src[e + g];
        uint2 v = xq2[s * 8 + c2]; float cs = xscale[s];
        ACC8(v, cs);
    }
    a0 += __shfl_xor(a0, 8, 64); a0 += __shfl_xor(a0, 16, 64); a0 += __shfl_xor(a0, 32, 64);
    a1 += __shfl_xor(a1, 8, 64); a1 += __shfl_xor(a1, 16, 64); a1 += __shfl_xor(a1, 32, 64);
    a2 += __shfl_xor(a2, 8, 64); a2 += __shfl_xor(a2, 16, 64); a2 += __shfl_xor(a2, 32, 64);
    a3 += __shfl_xor(a3, 8, 64); a3 += __shfl_xor(a3, 16, 64); a3 += __shfl_xor(a3, 32, 64);
    a4 += __shfl_xor(a4, 8, 64); a4 += __shfl_xor(a4, 16, 64); a4 += __shfl_xor(a4, 32, 64);
    a5 += __shfl_xor(a5, 8, 64); a5 += __shfl_xor(a5, 16, 64); a5 += __shfl_xor(a5, 32, 64);
    a6 += __shfl_xor(a6, 8, 64); a6 += __shfl_xor(a6, 16, 64); a6 += __shfl_xor(a6, 32, 64);
    a7 += __shfl_xor(a7, 8, 64); a7 += __shfl_xor(a7, 16, 64); a7 += __shfl_xor(a7, 32, 64);
    if (g == 0) {
        // dword 2*c2 -> feats {2c2, +16, +32, +48} = a0..a3
        // dword 2*c2+1 -> feats {2c2+1, +16, +32, +48} = a4..a7
        long o = (long)wid * HID;
        int f = 2 * c2;
        #pragma unroll
        for (int blk4 = 0; blk4 < 4; ++blk4) {
            int ff = f + blk4 * 16;
            float lo_a = (blk4 == 0) ? a0 : (blk4 == 1) ? a1 : (blk4 == 2) ? a2 : a3;
            float hi_a = (blk4 == 0) ? a4 : (blk4 == 1) ? a5 : (blk4 == 2) ? a6 : a7;
            float2 bv = *reinterpret_cast<const float2*>(&b[ff]);
            unsigned rv = *reinterpret_cast<const unsigned*>(&resb[o + ff]);
            float w0 = fmaxf(lo_a + bv.x, 0.f) + __uint_as_float(rv << 16);
            float w1 = fmaxf(hi_a + bv.y, 0.f) + __uint_as_float(rv & 0xFFFF0000u);
            unsigned ov = (unsigned)f32_to_bf16_rne(w0) | ((unsigned)f32_to_bf16_rne(w1) << 16);
            *reinterpret_cast<unsigned*>(&xoutb[o + ff]) = ov;
        }
    }
}

// ---- pooling gather over bf16 x: one wave/graph, binary search range
__global__ void pool_gather_kernel(const unsigned short* __restrict__ x,
                                   const int* __restrict__ gid,
                                   float* __restrict__ g,
                                   int n_graphs) {
    int wid = (blockIdx.x * blockDim.x + threadIdx.x) >> 6;
    int lane = threadIdx.x & 63;
    if (wid >= n_graphs) return;
    int lo = 0, hi = N_NODES;
    while (lo < hi) { int mid = (lo + hi) >> 1; if (gid[mid] < wid) lo = mid + 1; else hi = mid; }
    int start = lo;
    hi = N_NODES;
    while (lo < hi) { int mid = (lo + hi) >> 1; if (gid[mid] < wid + 1) lo = mid + 1; else hi = mid; }
    int end = lo;
    float acc = 0.f;
    for (int n = start; n < end; ++n)
        acc += bf16u_f(x[(long)n * HID + lane]);
    g[(long)wid * HID + lane] = acc;
}

// ---- MLP: one wave per graph. out = relu(g@Wm1+bm1) @ Wm2 + bm2
__global__ void mlp_kernel(const float* __restrict__ g,
                           const float* __restrict__ Wm1,
                           const float* __restrict__ bm1,
                           const float* __restrict__ Wm2,
                           const float* __restrict__ bm2,
                           float* __restrict__ out,
                           int n_graphs) {
    int wid = (blockIdx.x * blockDim.x + threadIdx.x) >> 6;
    int lane = threadIdx.x & 63;
    if (wid >= n_graphs) return;
    const float* gr = g + (long)wid * HID;
    float h0 = bm1[lane];
    float h1 = bm1[lane + 64];
    for (int k = 0; k < HID; ++k) {
        float gv = gr[k];
        h0 += gv * Wm1[k * MLP_HID + lane];
        h1 += gv * Wm1[k * MLP_HID + lane + 64];
    }
    float part = fmaxf(h0, 0.f) * Wm2[lane] + fmaxf(h1, 0.f) * Wm2[lane + 64];
    #pragma unroll
    for (int off = 32; off > 0; off >>= 1)
        part += __shfl_down(part, off, 64);
    if (lane == 0) out[wid] = part + bm2[0];
}

extern "C" void kernel_launch(void* const* d_in, const int* in_sizes, int n_in,
                              void* d_out, int out_size, void* d_ws, size_t ws_size,
                              hipStream_t stream) {
    const float* feats = (const float*)d_in[0];
    const int*   src   = (const int*)d_in[1];
    const int*   dst   = (const int*)d_in[2];
    const int*   gid   = (const int*)d_in[3];
    const float* W[3]  = {(const float*)d_in[4],  (const float*)d_in[8],  (const float*)d_in[12]};
    const float* b[3]  = {(const float*)d_in[5],  (const float*)d_in[9],  (const float*)d_in[13]};
    const float* R[3]  = {(const float*)d_in[6],  (const float*)d_in[10], (const float*)d_in[14]};
    const float* rb[3] = {(const float*)d_in[7],  (const float*)d_in[11], (const float*)d_in[15]};
    const float* Wm1 = (const float*)d_in[16];
    const float* bm1 = (const float*)d_in[17];
    const float* Wm2 = (const float*)d_in[18];
    const float* bm2 = (const float*)d_in[19];
    float* out = (float*)d_out;

    // workspace carve
    char* ws = (char*)d_ws;
    const size_t node_bf16 = (size_t)N_NODES * HID * sizeof(unsigned short);  // 12.8 MB
    unsigned short* xbufb     = (unsigned short*)(ws); ws += node_bf16;
    unsigned*       xq        = (unsigned*)(ws);       ws += (size_t)N_NODES * 16 * sizeof(unsigned); // 6.4 MB
    float*          xscale    = (float*)(ws);          ws += (size_t)N_NODES * sizeof(float);         // 400 KB
    unsigned short* resb      = (unsigned short*)(ws); ws += node_bf16;
    float*          gbuf      = (float*)(ws);          ws += (size_t)N_GRAPHS * HID * sizeof(float);
    int*            cursor    = (int*)(ws);            ws += (size_t)NBUCKET * sizeof(int);
    int*            row_start = (int*)(ws);            ws += (size_t)N_NODES * sizeof(int);
    int*            row_deg   = (int*)(ws);            ws += (size_t)N_NODES * sizeof(int);
    int*            blockHist = (int*)(ws);            ws += (size_t)NBUCKET * NBLK * sizeof(int);  // 800 KB
    unsigned short* wtbuf     = (unsigned short*)(ws); ws += (size_t)(2 * SZ0 + 4 * SZ12) * sizeof(unsigned short);
    ws = (char*)(((size_t)ws + 255) & ~(size_t)255);
    unsigned*       pairs     = (unsigned*)(ws);       ws += (size_t)NBUCKET * BUCKET_CAP * sizeof(unsigned); // 25.6 MB

    // ---- one-time weight transpose/quantize + bucketed CSR build
    prep_wt_kernel<<<6, 256, 0, stream>>>(W[0], R[0], W[1], R[1], W[2], R[2], wtbuf);
    split_hist_kernel<<<NBLK, SPLIT_THREADS, 0, stream>>>(dst, blockHist);
    split_scan_kernel<<<NBUCKET, NBLK, 0, stream>>>(blockHist, cursor);
    split_scatter_kernel<<<NBLK, SPLIT_THREADS, 0, stream>>>(src, dst, blockHist, pairs);
    bucket_sort_kernel<<<NBUCKET, 256, 0, stream>>>(pairs, cursor, row_start, row_deg);

    const unsigned short* wt_l[3] = {wtbuf, wtbuf + 2 * SZ0, wtbuf + 2 * SZ0 + 2 * SZ12};

    for (int l = 0; l < 3; ++l) {
        {
            int blocks = (N_NODES + 63) / 64;     // 64 nodes per block
            if (l == 0)
                proj_mfma_kernel<IN_DIM, 96, STRIDE0, false><<<blocks, 256, 0, stream>>>(
                    (const void*)feats, wt_l[l], rb[l], xq, xscale, resb, N_NODES);
            else
                proj_mfma_kernel<HID, 64, STRIDE12, true><<<blocks, 256, 0, stream>>>(
                    (const void*)xbufb, wt_l[l], rb[l], xq, xscale, resb, N_NODES);
        }
        {
            int blocks = (N_NODES * 64 + 255) / 256;  // one wave per node
            gather_kernel<<<blocks, 256, 0, stream>>>((const uint2*)xq, xscale, row_start, row_deg,
                                                      pairs, b[l], resb, xbufb, N_NODES);
        }
    }

    // pooling
    {
        int threads = N_GRAPHS * 64;
        pool_gather_kernel<<<(threads + 255) / 256, 256, 0, stream>>>(xbufb, gid, gbuf, N_GRAPHS);
    }
    // MLP
    {
        int threads = N_GRAPHS * 64;
        mlp_kernel<<<(threads + 255) / 256, 256, 0, stream>>>(gbuf, Wm1, bm1, Wm2, bm2, out, N_GRAPHS);
    }
}